// Round 1
// baseline (406.956 us; speedup 1.0000x reference)
//
#include <hip/hip_runtime.h>
#include <math.h>

// Problem dims (fixed by reference)
#define BB 8
#define TT 2048
#define DD 512
#define SD 256
#define OD 64
#define CHUNK 32
#define NC 64          // TT/CHUNK
#define CB 64          // binding-scan chunk
#define NCB 32         // TT/CB
#define MM (BB*TT)     // 16384

// ---------------------------------------------------------------------------
// Generic fp32 GEMM: C[M,N] = act(A[M,K]@B[K,N] + bias[N]) (+ addsrc[M,N]) (+= C if accum)
// Tile 64x64, TK=16, 256 threads, 4x4 per thread. M,N %64==0, K %16==0.
// ---------------------------------------------------------------------------
__global__ __launch_bounds__(256) void gemm_f32(
    const float* __restrict__ A, const float* __restrict__ B,
    const float* __restrict__ bias, const float* __restrict__ addsrc,
    float* __restrict__ C, int M, int N, int K, int act, int accum)
{
    __shared__ float As[16][68];
    __shared__ float Bs[16][68];
    const int bm = blockIdx.y * 64;
    const int bn = blockIdx.x * 64;
    const int tid = threadIdx.x;
    const int tx = tid & 15, ty = tid >> 4;
    const int arow = tid >> 2, acol = (tid & 3) << 2;   // A tile: 64 rows x 16 k
    const int brow = tid >> 4, bcol = (tid & 15) << 2;  // B tile: 16 k x 64 cols
    const float* Ap = A + (size_t)(bm + arow) * K + acol;
    const float* Bp = B + (size_t)brow * N + bn + bcol;
    float acc[4][4] = {};
    for (int k0 = 0; k0 < K; k0 += 16) {
        float4 av = *(const float4*)(Ap + k0);
        float4 bv = *(const float4*)(Bp + (size_t)k0 * N);
        __syncthreads();
        As[acol + 0][arow] = av.x;
        As[acol + 1][arow] = av.y;
        As[acol + 2][arow] = av.z;
        As[acol + 3][arow] = av.w;
        *(float4*)&Bs[brow][bcol] = bv;
        __syncthreads();
        #pragma unroll
        for (int kk = 0; kk < 16; ++kk) {
            float4 a4 = *(const float4*)&As[kk][ty << 2];
            float4 b4 = *(const float4*)&Bs[kk][tx << 2];
            float ar[4] = {a4.x, a4.y, a4.z, a4.w};
            float br[4] = {b4.x, b4.y, b4.z, b4.w};
            #pragma unroll
            for (int r = 0; r < 4; ++r)
                #pragma unroll
                for (int c2 = 0; c2 < 4; ++c2)
                    acc[r][c2] = fmaf(ar[r], br[c2], acc[r][c2]);
        }
    }
    #pragma unroll
    for (int r = 0; r < 4; ++r) {
        int row = bm + (ty << 2) + r;
        #pragma unroll
        for (int c2 = 0; c2 < 4; ++c2) {
            int col = bn + (tx << 2) + c2;
            float val = acc[r][c2] + bias[col];
            if (addsrc) val += addsrc[(size_t)row * N + col];
            if (act == 1) val = 1.f / (1.f + expf(-val));
            size_t oi = (size_t)row * N + col;
            if (accum) val += C[oi];
            C[oi] = val;
        }
    }
}

// ---------------------------------------------------------------------------
// Gated scan pass 1: per (b, chunk, sd) compute within-chunk cum_a / cum_wb
// exactly mirroring the reference clamps. 131072 threads, 32 serial steps.
// ---------------------------------------------------------------------------
__global__ __launch_bounds__(256) void scan_pass1(
    const float* __restrict__ g, const float* __restrict__ ilin,
    float* __restrict__ ca, float* __restrict__ cwb,
    float* __restrict__ ca_last, float* __restrict__ wb_last)
{
    int idx = blockIdx.x * 256 + threadIdx.x;        // 8*64*256 = 131072
    int sd = idx & 255;
    int c  = (idx >> 8) & 63;
    int b  = idx >> 14;
    size_t base = ((size_t)(b * TT + c * CHUNK)) * SD + sd;
    float prod = 1.f, wb = 0.f;
    for (int i = 0; i < CHUNK; ++i) {
        size_t off = base + (size_t)i * SD;
        float graw = g[off];
        float a = fmaxf(graw, 1e-6f);
        prod *= a;                                    // == exp(cumsum(log(max(a,1e-6))))
        float drive = (1.f - graw) * ilin[off];
        wb += drive / fmaxf(prod, 1e-8f);
        ca[off] = prod;
        cwb[off] = wb;
    }
    int cidx = (b * NC + c) * SD + sd;
    ca_last[cidx] = prod;
    wb_last[cidx] = wb;
}

// Pass 2: inter-chunk carry. h emitted BEFORE each chunk (matches lax.scan emit).
__global__ __launch_bounds__(256) void scan_pass2(
    const float* __restrict__ ca_last, const float* __restrict__ wb_last,
    float* __restrict__ h_prev)
{
    int idx = blockIdx.x * 256 + threadIdx.x;        // 8*256 = 2048
    int sd = idx & 255;
    int b  = idx >> 8;
    float h = 0.f;
    for (int c = 0; c < NC; ++c) {
        int o = (b * NC + c) * SD + sd;
        h_prev[o] = h;
        h = ca_last[o] * (h + wb_last[o]);
    }
}

// Pass 3: states = cum_a * (h_prev + cum_wb)  (elementwise)
__global__ __launch_bounds__(256) void scan_pass3(
    const float* __restrict__ ca, const float* __restrict__ cwb,
    const float* __restrict__ h_prev, float* __restrict__ states)
{
    size_t idx = (size_t)blockIdx.x * 256 + threadIdx.x;   // 16384*256
    int sd = idx & 255;
    int t  = (int)((idx >> 8) & 2047);
    int b  = (int)(idx >> 19);
    int c  = t >> 5;
    states[idx] = ca[idx] * (h_prev[((size_t)(b * NC + c)) * SD + sd] + cwb[idx]);
}

// ---------------------------------------------------------------------------
// Binding scan (outer-product linear attention with per-row decay), chunked.
// P1 per (b,chunk): A=tril(Q K^T); o_intra = dec_i^t * (A @ (dec_i^-s v));
//                   dS = dec_i^63 * ((dec_i^-m v)^T K)
// ---------------------------------------------------------------------------
__global__ __launch_bounds__(256) void bind_p1(
    const float* __restrict__ v, const float* __restrict__ k, const float* __restrict__ q,
    const float* __restrict__ op_decay, float* __restrict__ o, float* __restrict__ dS)
{
    __shared__ float Qs[64][64];   // reused as V' after A is built
    __shared__ float Ks[64][64];
    __shared__ float Am[64][64];
    __shared__ float l2d[64];
    const int bc = blockIdx.x;     // b*NCB + c
    const int b = bc >> 5, c = bc & 31;
    const size_t base = ((size_t)b * TT + (size_t)c * CB) * OD;
    const int tid = threadIdx.x;
    if (tid < 64) {
        float dec = 1.f / (1.f + expf(-op_decay[tid]));
        l2d[tid] = log2f(dec);
    }
    const int lr = tid >> 4;            // 0..15
    const int lc = (tid & 15) << 2;     // 0..60
    #pragma unroll
    for (int rr = 0; rr < 4; ++rr) {
        int row = lr + rr * 16;
        *(float4*)&Qs[row][lc] = *(const float4*)&q[base + row * OD + lc];
        *(float4*)&Ks[row][lc] = *(const float4*)&k[base + row * OD + lc];
    }
    __syncthreads();
    const int tx = tid & 15, ty = tid >> 4;
    // A[t][s] = sum_d Q[t][d]*K[s][d]
    float a_acc[4][4] = {};
    for (int d = 0; d < 64; ++d) {
        float qv[4], kv[4];
        #pragma unroll
        for (int r = 0; r < 4; ++r) qv[r] = Qs[(ty << 2) + r][d];
        #pragma unroll
        for (int s = 0; s < 4; ++s) kv[s] = Ks[(tx << 2) + s][d];
        #pragma unroll
        for (int r = 0; r < 4; ++r)
            #pragma unroll
            for (int s = 0; s < 4; ++s)
                a_acc[r][s] = fmaf(qv[r], kv[s], a_acc[r][s]);
    }
    #pragma unroll
    for (int r = 0; r < 4; ++r)
        #pragma unroll
        for (int s = 0; s < 4; ++s) {
            int t = (ty << 2) + r, ss = (tx << 2) + s;
            Am[t][ss] = (ss <= t) ? a_acc[r][s] : 0.f;
        }
    __syncthreads();   // all Qs reads done -> safe to overwrite with V'
    #pragma unroll
    for (int rr = 0; rr < 4; ++rr) {
        int row = lr + rr * 16;         // m
        float4 vv = *(const float4*)&v[base + row * OD + lc];
        float vals[4] = {vv.x, vv.y, vv.z, vv.w};
        #pragma unroll
        for (int j = 0; j < 4; ++j)
            Qs[row][lc + j] = exp2f(-(float)row * l2d[lc + j]) * vals[j];
    }
    __syncthreads();
    // o_intra[t][i] = dec_i^t * sum_s Am[t][s]*Vp[s][i]
    {
        float p[4][4] = {};
        for (int s = 0; s < 64; ++s) {
            float av[4];
            #pragma unroll
            for (int r = 0; r < 4; ++r) av[r] = Am[(ty << 2) + r][s];
            float4 v4 = *(const float4*)&Qs[s][tx << 2];
            float vp[4] = {v4.x, v4.y, v4.z, v4.w};
            #pragma unroll
            for (int r = 0; r < 4; ++r)
                #pragma unroll
                for (int i2 = 0; i2 < 4; ++i2)
                    p[r][i2] = fmaf(av[r], vp[i2], p[r][i2]);
        }
        #pragma unroll
        for (int r = 0; r < 4; ++r) {
            int t = (ty << 2) + r;
            #pragma unroll
            for (int i2 = 0; i2 < 4; ++i2) {
                int i = (tx << 2) + i2;
                o[base + t * OD + i] = exp2f((float)t * l2d[i]) * p[r][i2];
            }
        }
    }
    // dS[i][j] = dec_i^63 * sum_m Vp[m][i]*K[m][j]
    {
        float sacc[4][4] = {};
        for (int m = 0; m < 64; ++m) {
            float vp[4];
            #pragma unroll
            for (int r = 0; r < 4; ++r) vp[r] = Qs[m][(ty << 2) + r];
            float4 k4 = *(const float4*)&Ks[m][tx << 2];
            float kv[4] = {k4.x, k4.y, k4.z, k4.w};
            #pragma unroll
            for (int r = 0; r < 4; ++r)
                #pragma unroll
                for (int j = 0; j < 4; ++j)
                    sacc[r][j] = fmaf(vp[r], kv[j], sacc[r][j]);
        }
        float* dSb = dS + (size_t)bc * 4096;
        #pragma unroll
        for (int r = 0; r < 4; ++r) {
            int i = (ty << 2) + r;
            float scale = exp2f(63.f * l2d[i]);
            #pragma unroll
            for (int j2 = 0; j2 < 4; ++j2)
                dSb[i * 64 + (tx << 2) + j2] = scale * sacc[r][j2];
        }
    }
}

// P2: propagate chunk-start states. thread = (b,i,j), 32 serial chunks.
__global__ __launch_bounds__(256) void bind_p2(
    const float* __restrict__ dS, const float* __restrict__ op_decay,
    float* __restrict__ Sstart)
{
    int idx = blockIdx.x * 256 + threadIdx.x;   // 8*64*64 = 32768
    int j = idx & 63, i = (idx >> 6) & 63, b = idx >> 12;
    float dec = 1.f / (1.f + expf(-op_decay[i]));
    float d64 = exp2f(64.f * log2f(dec));
    float S = 0.f;
    for (int c = 0; c < NCB; ++c) {
        size_t o = (((size_t)b * NCB + c) * 4096) + i * 64 + j;
        Sstart[o] = S;
        S = d64 * S + dS[o];
    }
}

// P3: o += dec_i^(l+1) * (Q @ Sstart^T)
__global__ __launch_bounds__(256) void bind_p3(
    const float* __restrict__ q, const float* __restrict__ Sstart,
    const float* __restrict__ op_decay, float* __restrict__ o)
{
    __shared__ float Qs[64][64];
    __shared__ float Ss[64][64];
    __shared__ float l2d[64];
    const int bc = blockIdx.x;
    const int b = bc >> 5, c = bc & 31;
    const size_t base = ((size_t)b * TT + (size_t)c * CB) * OD;
    const int tid = threadIdx.x;
    if (tid < 64) {
        float dec = 1.f / (1.f + expf(-op_decay[tid]));
        l2d[tid] = log2f(dec);
    }
    const int lr = tid >> 4;
    const int lc = (tid & 15) << 2;
    const float* Sb = Sstart + (size_t)bc * 4096;
    #pragma unroll
    for (int rr = 0; rr < 4; ++rr) {
        int row = lr + rr * 16;
        *(float4*)&Qs[row][lc] = *(const float4*)&q[base + row * OD + lc];
        *(float4*)&Ss[row][lc] = *(const float4*)&Sb[row * 64 + lc];
    }
    __syncthreads();
    const int tx = tid & 15, ty = tid >> 4;
    float acc[4][4] = {};
    for (int j = 0; j < 64; ++j) {
        float qv[4], sv[4];
        #pragma unroll
        for (int r = 0; r < 4; ++r) qv[r] = Qs[(ty << 2) + r][j];
        #pragma unroll
        for (int i2 = 0; i2 < 4; ++i2) sv[i2] = Ss[(tx << 2) + i2][j];
        #pragma unroll
        for (int r = 0; r < 4; ++r)
            #pragma unroll
            for (int i2 = 0; i2 < 4; ++i2)
                acc[r][i2] = fmaf(qv[r], sv[i2], acc[r][i2]);
    }
    #pragma unroll
    for (int r = 0; r < 4; ++r) {
        int l = (ty << 2) + r;
        #pragma unroll
        for (int i2 = 0; i2 < 4; ++i2) {
            int i = (tx << 2) + i2;
            size_t oi = base + l * OD + i;
            o[oi] += exp2f((float)(l + 1) * l2d[i]) * acc[r][i2];
        }
    }
}

// ---------------------------------------------------------------------------
// In-place LayerNorm over last dim (512), one block per row.
// ---------------------------------------------------------------------------
__global__ __launch_bounds__(256) void ln_kernel(
    float* __restrict__ y, const float* __restrict__ lng, const float* __restrict__ lnb)
{
    const int row = blockIdx.x;
    float* yr = y + (size_t)row * DD;
    const int tid = threadIdx.x;
    float2 v2 = *(float2*)&yr[tid * 2];
    float s = v2.x + v2.y;
    float s2 = v2.x * v2.x + v2.y * v2.y;
    #pragma unroll
    for (int off = 32; off > 0; off >>= 1) {
        s  += __shfl_down(s, off);
        s2 += __shfl_down(s2, off);
    }
    __shared__ float ps[4], ps2[4];
    int lane = tid & 63, wid = tid >> 6;
    if (lane == 0) { ps[wid] = s; ps2[wid] = s2; }
    __syncthreads();
    float tot  = ps[0] + ps[1] + ps[2] + ps[3];
    float tot2 = ps2[0] + ps2[1] + ps2[2] + ps2[3];
    float mu = tot * (1.f / 512.f);
    float var = tot2 * (1.f / 512.f) - mu * mu;
    float rstd = rsqrtf(var + 1e-5f);
    int d0 = tid * 2;
    yr[d0]     = (v2.x - mu) * rstd * lng[d0]     + lnb[d0];
    yr[d0 + 1] = (v2.y - mu) * rstd * lng[d0 + 1] + lnb[d0 + 1];
}

// ---------------------------------------------------------------------------
extern "C" void kernel_launch(void* const* d_in, const int* in_sizes, int n_in,
                              void* d_out, int out_size, void* d_ws, size_t ws_size,
                              hipStream_t stream)
{
    const float* x       = (const float*)d_in[0];
    const float* gate_W  = (const float*)d_in[1];
    const float* gate_b  = (const float*)d_in[2];
    const float* in_W    = (const float*)d_in[3];
    const float* in_b    = (const float*)d_in[4];
    const float* out_W   = (const float*)d_in[5];
    const float* out_b   = (const float*)d_in[6];
    const float* opv_W   = (const float*)d_in[7];
    const float* opv_b   = (const float*)d_in[8];
    const float* opk_W   = (const float*)d_in[9];
    const float* opk_b   = (const float*)d_in[10];
    const float* opq_W   = (const float*)d_in[11];
    const float* opq_b   = (const float*)d_in[12];
    const float* op_dec  = (const float*)d_in[13];
    const float* opout_W = (const float*)d_in[14];
    const float* opout_b = (const float*)d_in[15];
    const float* ln_g    = (const float*)d_in[16];
    const float* ln_b    = (const float*)d_in[17];
    float* y = (float*)d_out;
    float* ws = (float*)d_ws;

    // workspace layout (floats)
    const size_t SZ_BIG = (size_t)MM * SD;     // 4,194,304
    const size_t SZ_OD  = (size_t)MM * OD;     // 1,048,576
    const size_t SZ_SUM = (size_t)BB * NC * SD;// 131,072
    const size_t SZ_DS  = (size_t)BB * NCB * 64 * 64; // 1,048,576
    float* g_buf   = ws;                 // gates (post-sigmoid)
    float* ilin    = g_buf + SZ_BIG;
    float* ca      = ilin + SZ_BIG;
    float* cwb     = ca + SZ_BIG;
    float* states  = cwb + SZ_BIG;
    float* vlin    = states + SZ_BIG;
    float* klin    = vlin + SZ_OD;
    float* qlin    = klin + SZ_OD;
    float* ca_last = qlin + SZ_OD;
    float* wb_last = ca_last + SZ_SUM;
    float* h_prev  = wb_last + SZ_SUM;
    float* dS      = h_prev + SZ_SUM;
    float* Sstart  = dS + SZ_DS;
    float* obind   = Sstart + SZ_DS;

    // 1-5: projections
    hipLaunchKernelGGL(gemm_f32, dim3(SD/64, MM/64), dim3(256), 0, stream,
                       x, gate_W, gate_b, (const float*)nullptr, g_buf, MM, SD, DD, 1, 0);
    hipLaunchKernelGGL(gemm_f32, dim3(SD/64, MM/64), dim3(256), 0, stream,
                       x, in_W, in_b, (const float*)nullptr, ilin, MM, SD, DD, 0, 0);
    hipLaunchKernelGGL(gemm_f32, dim3(OD/64, MM/64), dim3(256), 0, stream,
                       x, opv_W, opv_b, (const float*)nullptr, vlin, MM, OD, DD, 0, 0);
    hipLaunchKernelGGL(gemm_f32, dim3(OD/64, MM/64), dim3(256), 0, stream,
                       x, opk_W, opk_b, (const float*)nullptr, klin, MM, OD, DD, 0, 0);
    hipLaunchKernelGGL(gemm_f32, dim3(OD/64, MM/64), dim3(256), 0, stream,
                       x, opq_W, opq_b, (const float*)nullptr, qlin, MM, OD, DD, 0, 0);
    // 6-8: gated chunked scan
    hipLaunchKernelGGL(scan_pass1, dim3(BB*NC*SD/256), dim3(256), 0, stream,
                       g_buf, ilin, ca, cwb, ca_last, wb_last);
    hipLaunchKernelGGL(scan_pass2, dim3(BB*SD/256), dim3(256), 0, stream,
                       ca_last, wb_last, h_prev);
    hipLaunchKernelGGL(scan_pass3, dim3((unsigned)(SZ_BIG/256)), dim3(256), 0, stream,
                       ca, cwb, h_prev, states);
    // 9: y = x + states@out_W + out_b
    hipLaunchKernelGGL(gemm_f32, dim3(DD/64, MM/64), dim3(256), 0, stream,
                       states, out_W, out_b, x, y, MM, DD, SD, 0, 0);
    // 10-12: binding scan
    hipLaunchKernelGGL(bind_p1, dim3(BB*NCB), dim3(256), 0, stream,
                       vlin, klin, qlin, op_dec, obind, dS);
    hipLaunchKernelGGL(bind_p2, dim3(BB*64*64/256), dim3(256), 0, stream,
                       dS, op_dec, Sstart);
    hipLaunchKernelGGL(bind_p3, dim3(BB*NCB), dim3(256), 0, stream,
                       qlin, Sstart, op_dec, obind);
    // 13: y += obind@opout_W + opout_b
    hipLaunchKernelGGL(gemm_f32, dim3(DD/64, MM/64), dim3(256), 0, stream,
                       obind, opout_W, opout_b, (const float*)nullptr, y, MM, DD, OD, 0, 1);
    // 14: LayerNorm in place
    hipLaunchKernelGGL(ln_kernel, dim3(MM), dim3(256), 0, stream, y, ln_g, ln_b);
}

// Round 2
// 188.037 us; speedup vs baseline: 2.1642x; 2.1642x over previous
//
#include <hip/hip_runtime.h>
#include <hip/hip_bf16.h>
#include <math.h>

#define BB 8
#define TT 2048
#define DD 512
#define SD 256
#define OD 64
#define CHUNK 32
#define NC 64          // TT/CHUNK
#define CB 64          // binding-scan chunk
#define NCB 32         // TT/CB
#define MM (BB*TT)     // 16384

typedef __attribute__((ext_vector_type(8))) short bf16x8_t;
typedef __attribute__((ext_vector_type(4))) float f32x4;

// ---------------------------------------------------------------------------
// fp32 -> bf16 conversion of x
// ---------------------------------------------------------------------------
__global__ __launch_bounds__(256) void conv_x(
    const float* __restrict__ x, __hip_bfloat16* __restrict__ xb)
{
    size_t i = ((size_t)blockIdx.x * 256 + threadIdx.x) * 8;
    float4 v0 = *(const float4*)&x[i];
    float4 v1 = *(const float4*)&x[i + 4];
    alignas(16) __hip_bfloat16 h[8] = {
        __float2bfloat16(v0.x), __float2bfloat16(v0.y),
        __float2bfloat16(v0.z), __float2bfloat16(v0.w),
        __float2bfloat16(v1.x), __float2bfloat16(v1.y),
        __float2bfloat16(v1.z), __float2bfloat16(v1.w)};
    *(float4*)&xb[i] = *(float4*)h;
}

// ---------------------------------------------------------------------------
// Weight conversion: transpose to [N][K] bf16, concat gate|in and v|k|q.
// ---------------------------------------------------------------------------
__global__ __launch_bounds__(256) void conv_weights(
    const float* __restrict__ gate_W, const float* __restrict__ gate_b,
    const float* __restrict__ in_W,   const float* __restrict__ in_b,
    const float* __restrict__ opv_W,  const float* __restrict__ opk_W,
    const float* __restrict__ opq_W,
    const float* __restrict__ opv_b,  const float* __restrict__ opk_b,
    const float* __restrict__ opq_b,
    const float* __restrict__ out_W,  const float* __restrict__ opout_W,
    __hip_bfloat16* __restrict__ Wgi,   __hip_bfloat16* __restrict__ Wvkq,
    __hip_bfloat16* __restrict__ Wout,  __hip_bfloat16* __restrict__ Wopout,
    float* __restrict__ bias_gi, float* __restrict__ bias_vkq)
{
    int idx = blockIdx.x * 256 + threadIdx.x;
    if (idx < 262144) {                       // Wgi_t [512][512]
        int n = idx >> 9, k = idx & 511;
        float v = (n < 256) ? gate_W[k * 256 + n] : in_W[k * 256 + (n - 256)];
        Wgi[idx] = __float2bfloat16(v);
        return;
    }
    idx -= 262144;
    if (idx < 98304) {                        // Wvkq_t [192][512]
        int n = idx >> 9, k = idx & 511;
        int h = n >> 6, j = n & 63;
        const float* W = (h == 0) ? opv_W : (h == 1) ? opk_W : opq_W;
        Wvkq[(size_t)n * 512 + k] = __float2bfloat16(W[k * 64 + j]);
        return;
    }
    idx -= 98304;
    if (idx < 131072) {                       // Wout_t [512][256]
        int n = idx >> 8, k = idx & 255;
        Wout[idx] = __float2bfloat16(out_W[k * 512 + n]);
        return;
    }
    idx -= 131072;
    if (idx < 32768) {                        // Wopout_t [512][64]
        int n = idx >> 6, k = idx & 63;
        Wopout[idx] = __float2bfloat16(opout_W[k * 512 + n]);
        return;
    }
    idx -= 32768;
    if (idx < 512) { bias_gi[idx] = (idx < 256) ? gate_b[idx] : in_b[idx - 256]; return; }
    idx -= 512;
    if (idx < 192) {
        int h = idx >> 6, j = idx & 63;
        bias_vkq[idx] = (h == 0) ? opv_b[j] : (h == 1) ? opk_b[j] : opq_b[j];
    }
}

// ---------------------------------------------------------------------------
// bf16 MFMA GEMM: out = A[M,K] @ Wt[N,K]^T + bias, with epilogue options.
// BM=128, BK=32, 4 waves (2x2), wave tile 64xWN. XOR granule swizzle on LDS.
// ---------------------------------------------------------------------------
template<int BN>
__global__ __launch_bounds__(256) void gemm_bf16(
    const __hip_bfloat16* __restrict__ A,
    const __hip_bfloat16* __restrict__ Bt,
    const float* __restrict__ bias,
    const float* __restrict__ addsrc,       // [M,N] fp32 or null
    float* __restrict__ outF,               // fp32 out (or null)
    __hip_bfloat16* __restrict__ outB,      // bf16 out (or null)
    int M, int N, int K, int sigCols, int accum)
{
    constexpr int BM = 128, BK = 32;
    constexpr int WN = (BN == 128) ? 64 : 32;
    constexpr int NFC = WN / 16;
    __shared__ alignas(16) __hip_bfloat16 As[BM * BK];
    __shared__ alignas(16) __hip_bfloat16 Bs[BN * BK];
    const int tid = threadIdx.x;
    const int lane = tid & 63, wid = tid >> 6;
    const int wr = wid >> 1, wc = wid & 1;
    const int bm = blockIdx.y * BM, bn = blockIdx.x * BN;

    // A staging: thread -> row=tid>>1, granules 2*(tid&1), 2*(tid&1)+1
    const int arow = tid >> 1, ag0 = (tid & 1) * 2;
    const int sA = (arow >> 1) & 3;
    const __hip_bfloat16* Ag = A + (size_t)(bm + arow) * K + ag0 * 8;
    __hip_bfloat16* Aw0 = &As[arow * 32 + ((ag0 ^ sA) * 8)];
    __hip_bfloat16* Aw1 = &As[arow * 32 + (((ag0 + 1) ^ sA) * 8)];

    // B staging
    constexpr bool BW2 = (BN == 128);
    const int brow = BW2 ? (tid >> 1) : (tid >> 2);
    const int bg0  = BW2 ? ((tid & 1) * 2) : (tid & 3);
    const int sB = (brow >> 1) & 3;
    const __hip_bfloat16* Bg = Bt + (size_t)(bn + brow) * K + bg0 * 8;
    __hip_bfloat16* Bw0 = &Bs[brow * 32 + ((bg0 ^ sB) * 8)];
    __hip_bfloat16* Bw1 = &Bs[brow * 32 + (((bg0 + 1) ^ sB) * 8)];

    f32x4 acc[4][NFC] = {};

    for (int k0 = 0; k0 < K; k0 += BK) {
        float4 a0 = *(const float4*)(Ag + k0);
        float4 a1 = *(const float4*)(Ag + k0 + 8);
        float4 b0 = *(const float4*)(Bg + k0);
        float4 b1;
        if constexpr (BW2) b1 = *(const float4*)(Bg + k0 + 8);
        __syncthreads();
        *(float4*)Aw0 = a0;
        *(float4*)Aw1 = a1;
        *(float4*)Bw0 = b0;
        if constexpr (BW2) *(float4*)Bw1 = b1;
        __syncthreads();
        bf16x8_t af[4], bfr[NFC];
        #pragma unroll
        for (int mi = 0; mi < 4; ++mi) {
            int row = wr * 64 + mi * 16 + (lane & 15);
            int gp = (lane >> 4) ^ ((row >> 1) & 3);
            af[mi] = *(const bf16x8_t*)&As[row * 32 + gp * 8];
        }
        #pragma unroll
        for (int nj = 0; nj < NFC; ++nj) {
            int row = wc * WN + nj * 16 + (lane & 15);
            int gp = (lane >> 4) ^ ((row >> 1) & 3);
            bfr[nj] = *(const bf16x8_t*)&Bs[row * 32 + gp * 8];
        }
        #pragma unroll
        for (int mi = 0; mi < 4; ++mi)
            #pragma unroll
            for (int nj = 0; nj < NFC; ++nj)
                acc[mi][nj] = __builtin_amdgcn_mfma_f32_16x16x32_bf16(
                    af[mi], bfr[nj], acc[mi][nj], 0, 0, 0);
    }

    #pragma unroll
    for (int mi = 0; mi < 4; ++mi) {
        #pragma unroll
        for (int nj = 0; nj < NFC; ++nj) {
            int col = bn + wc * WN + nj * 16 + (lane & 15);
            int r0 = bm + wr * 64 + mi * 16 + (lane >> 4) * 4;
            float bv = bias[col];
            #pragma unroll
            for (int e = 0; e < 4; ++e) {
                int row = r0 + e;
                size_t oi = (size_t)row * N + col;
                float val = acc[mi][nj][e] + bv;
                if (addsrc) val += addsrc[oi];
                if (col < sigCols) val = 1.f / (1.f + expf(-val));
                if (outF) outF[oi] = accum ? (outF[oi] + val) : val;
                else      outB[oi] = __float2bfloat16(val);
            }
        }
    }
}

// ---------------------------------------------------------------------------
// Gated scan. gi layout: [M][512], cols 0-255 = sigmoid(gate), 256-511 = in.
// ---------------------------------------------------------------------------
__global__ __launch_bounds__(256) void scan_pass1(
    const float* __restrict__ gi,
    float* __restrict__ ca_last, float* __restrict__ wb_last)
{
    int idx = blockIdx.x * 256 + threadIdx.x;        // 131072
    int sd = idx & 255;
    int c  = (idx >> 8) & 63;
    int b  = idx >> 14;
    size_t base = ((size_t)(b * TT + c * CHUNK)) * 512;
    float prod = 1.f, wb = 0.f;
    for (int i = 0; i < CHUNK; ++i) {
        size_t off = base + (size_t)i * 512;
        float g  = gi[off + sd];
        float il = gi[off + 256 + sd];
        float a = fmaxf(g, 1e-6f);
        prod *= a;
        wb += (1.f - g) * il / fmaxf(prod, 1e-8f);
    }
    int cidx = (b * NC + c) * SD + sd;
    ca_last[cidx] = prod;
    wb_last[cidx] = wb;
}

__global__ __launch_bounds__(256) void scan_pass2(
    const float* __restrict__ ca_last, const float* __restrict__ wb_last,
    float* __restrict__ h_prev)
{
    int idx = blockIdx.x * 256 + threadIdx.x;        // 2048
    int sd = idx & 255;
    int b  = idx >> 8;
    float h = 0.f;
    for (int c = 0; c < NC; ++c) {
        int o = (b * NC + c) * SD + sd;
        h_prev[o] = h;
        h = ca_last[o] * (h + wb_last[o]);
    }
}

// recompute cum within chunk, emit states as bf16
__global__ __launch_bounds__(256) void scan_pass3(
    const float* __restrict__ gi, const float* __restrict__ h_prev,
    __hip_bfloat16* __restrict__ states)
{
    int idx = blockIdx.x * 256 + threadIdx.x;        // 131072
    int sd = idx & 255;
    int c  = (idx >> 8) & 63;
    int b  = idx >> 14;
    size_t base = ((size_t)(b * TT + c * CHUNK)) * 512;
    size_t obase = ((size_t)(b * TT + c * CHUNK)) * 256 + sd;
    float h = h_prev[(b * NC + c) * SD + sd];
    float prod = 1.f, wb = 0.f;
    for (int i = 0; i < CHUNK; ++i) {
        size_t off = base + (size_t)i * 512;
        float g  = gi[off + sd];
        float il = gi[off + 256 + sd];
        float a = fmaxf(g, 1e-6f);
        prod *= a;
        wb += (1.f - g) * il / fmaxf(prod, 1e-8f);
        states[obase + (size_t)i * 256] = __float2bfloat16(prod * (h + wb));
    }
}

// ---------------------------------------------------------------------------
// Binding scan. vkq layout: [M][192], v=0-63, k=64-127, q=128-191 (fp32).
// ---------------------------------------------------------------------------
__global__ __launch_bounds__(256) void bind_p1(
    const float* __restrict__ vkq, const float* __restrict__ op_decay,
    float* __restrict__ o, float* __restrict__ dS)
{
    __shared__ float Qs[64][64];   // reused as V' after A is built
    __shared__ float Ks[64][64];
    __shared__ float Am[64][64];
    __shared__ float l2d[64];
    const int bc = blockIdx.x;     // b*NCB + c
    const int b = bc >> 5, c = bc & 31;
    const size_t base = ((size_t)b * TT + (size_t)c * CB) * 192;
    const size_t obase = ((size_t)b * TT + (size_t)c * CB) * OD;
    const int tid = threadIdx.x;
    if (tid < 64) {
        float dec = 1.f / (1.f + expf(-op_decay[tid]));
        l2d[tid] = log2f(dec);
    }
    const int lr = tid >> 4;
    const int lc = (tid & 15) << 2;
    #pragma unroll
    for (int rr = 0; rr < 4; ++rr) {
        int row = lr + rr * 16;
        *(float4*)&Qs[row][lc] = *(const float4*)&vkq[base + row * 192 + 128 + lc];
        *(float4*)&Ks[row][lc] = *(const float4*)&vkq[base + row * 192 + 64 + lc];
    }
    __syncthreads();
    const int tx = tid & 15, ty = tid >> 4;
    float a_acc[4][4] = {};
    for (int d = 0; d < 64; ++d) {
        float qv[4], kv[4];
        #pragma unroll
        for (int r = 0; r < 4; ++r) qv[r] = Qs[(ty << 2) + r][d];
        #pragma unroll
        for (int s = 0; s < 4; ++s) kv[s] = Ks[(tx << 2) + s][d];
        #pragma unroll
        for (int r = 0; r < 4; ++r)
            #pragma unroll
            for (int s = 0; s < 4; ++s)
                a_acc[r][s] = fmaf(qv[r], kv[s], a_acc[r][s]);
    }
    #pragma unroll
    for (int r = 0; r < 4; ++r)
        #pragma unroll
        for (int s = 0; s < 4; ++s) {
            int t = (ty << 2) + r, ss = (tx << 2) + s;
            Am[t][ss] = (ss <= t) ? a_acc[r][s] : 0.f;
        }
    __syncthreads();
    #pragma unroll
    for (int rr = 0; rr < 4; ++rr) {
        int row = lr + rr * 16;
        float4 vv = *(const float4*)&vkq[base + row * 192 + lc];
        float vals[4] = {vv.x, vv.y, vv.z, vv.w};
        #pragma unroll
        for (int j = 0; j < 4; ++j)
            Qs[row][lc + j] = exp2f(-(float)row * l2d[lc + j]) * vals[j];
    }
    __syncthreads();
    {
        float p[4][4] = {};
        for (int s = 0; s < 64; ++s) {
            float av[4];
            #pragma unroll
            for (int r = 0; r < 4; ++r) av[r] = Am[(ty << 2) + r][s];
            float4 v4 = *(const float4*)&Qs[s][tx << 2];
            float vp[4] = {v4.x, v4.y, v4.z, v4.w};
            #pragma unroll
            for (int r = 0; r < 4; ++r)
                #pragma unroll
                for (int i2 = 0; i2 < 4; ++i2)
                    p[r][i2] = fmaf(av[r], vp[i2], p[r][i2]);
        }
        #pragma unroll
        for (int r = 0; r < 4; ++r) {
            int t = (ty << 2) + r;
            #pragma unroll
            for (int i2 = 0; i2 < 4; ++i2) {
                int i = (tx << 2) + i2;
                o[obase + t * OD + i] = exp2f((float)t * l2d[i]) * p[r][i2];
            }
        }
    }
    {
        float sacc[4][4] = {};
        for (int m = 0; m < 64; ++m) {
            float vp[4];
            #pragma unroll
            for (int r = 0; r < 4; ++r) vp[r] = Qs[m][(ty << 2) + r];
            float4 k4 = *(const float4*)&Ks[m][tx << 2];
            float kv[4] = {k4.x, k4.y, k4.z, k4.w};
            #pragma unroll
            for (int r = 0; r < 4; ++r)
                #pragma unroll
                for (int j = 0; j < 4; ++j)
                    sacc[r][j] = fmaf(vp[r], kv[j], sacc[r][j]);
        }
        float* dSb = dS + (size_t)bc * 4096;
        #pragma unroll
        for (int r = 0; r < 4; ++r) {
            int i = (ty << 2) + r;
            float scale = exp2f(63.f * l2d[i]);
            #pragma unroll
            for (int j2 = 0; j2 < 4; ++j2)
                dSb[i * 64 + (tx << 2) + j2] = scale * sacc[r][j2];
        }
    }
}

__global__ __launch_bounds__(256) void bind_p2(
    const float* __restrict__ dS, const float* __restrict__ op_decay,
    float* __restrict__ Sstart)
{
    int idx = blockIdx.x * 256 + threadIdx.x;   // 32768
    int j = idx & 63, i = (idx >> 6) & 63, b = idx >> 12;
    float dec = 1.f / (1.f + expf(-op_decay[i]));
    float d64 = exp2f(64.f * log2f(dec));
    float S = 0.f;
    for (int c = 0; c < NCB; ++c) {
        size_t o = (((size_t)b * NCB + c) * 4096) + i * 64 + j;
        Sstart[o] = S;
        S = d64 * S + dS[o];
    }
}

// o_final(bf16) = o_intra + dec^(l+1) * (Q @ Sstart^T)
__global__ __launch_bounds__(256) void bind_p3(
    const float* __restrict__ vkq, const float* __restrict__ Sstart,
    const float* __restrict__ op_decay, const float* __restrict__ o,
    __hip_bfloat16* __restrict__ ob16)
{
    __shared__ float Qs[64][64];
    __shared__ float Ss[64][64];
    __shared__ float l2d[64];
    const int bc = blockIdx.x;
    const int b = bc >> 5, c = bc & 31;
    const size_t base = ((size_t)b * TT + (size_t)c * CB) * 192;
    const size_t obase = ((size_t)b * TT + (size_t)c * CB) * OD;
    const int tid = threadIdx.x;
    if (tid < 64) {
        float dec = 1.f / (1.f + expf(-op_decay[tid]));
        l2d[tid] = log2f(dec);
    }
    const int lr = tid >> 4;
    const int lc = (tid & 15) << 2;
    const float* Sb = Sstart + (size_t)bc * 4096;
    #pragma unroll
    for (int rr = 0; rr < 4; ++rr) {
        int row = lr + rr * 16;
        *(float4*)&Qs[row][lc] = *(const float4*)&vkq[base + row * 192 + 128 + lc];
        *(float4*)&Ss[row][lc] = *(const float4*)&Sb[row * 64 + lc];
    }
    __syncthreads();
    const int tx = tid & 15, ty = tid >> 4;
    float acc[4][4] = {};
    for (int j = 0; j < 64; ++j) {
        float qv[4], sv[4];
        #pragma unroll
        for (int r = 0; r < 4; ++r) qv[r] = Qs[(ty << 2) + r][j];
        #pragma unroll
        for (int i2 = 0; i2 < 4; ++i2) sv[i2] = Ss[(tx << 2) + i2][j];
        #pragma unroll
        for (int r = 0; r < 4; ++r)
            #pragma unroll
            for (int i2 = 0; i2 < 4; ++i2)
                acc[r][i2] = fmaf(qv[r], sv[i2], acc[r][i2]);
    }
    #pragma unroll
    for (int r = 0; r < 4; ++r) {
        int l = (ty << 2) + r;
        #pragma unroll
        for (int i2 = 0; i2 < 4; ++i2) {
            int i = (tx << 2) + i2;
            size_t oi = obase + l * OD + i;
            float val = o[oi] + exp2f((float)(l + 1) * l2d[i]) * acc[r][i2];
            ob16[oi] = __float2bfloat16(val);
        }
    }
}

// ---------------------------------------------------------------------------
// In-place LayerNorm over last dim (512).
// ---------------------------------------------------------------------------
__global__ __launch_bounds__(256) void ln_kernel(
    float* __restrict__ y, const float* __restrict__ lng, const float* __restrict__ lnb)
{
    const int row = blockIdx.x;
    float* yr = y + (size_t)row * DD;
    const int tid = threadIdx.x;
    float2 v2 = *(float2*)&yr[tid * 2];
    float s = v2.x + v2.y;
    float s2 = v2.x * v2.x + v2.y * v2.y;
    #pragma unroll
    for (int off = 32; off > 0; off >>= 1) {
        s  += __shfl_down(s, off);
        s2 += __shfl_down(s2, off);
    }
    __shared__ float ps[4], ps2[4];
    int lane = tid & 63, wid = tid >> 6;
    if (lane == 0) { ps[wid] = s; ps2[wid] = s2; }
    __syncthreads();
    float tot  = ps[0] + ps[1] + ps[2] + ps[3];
    float tot2 = ps2[0] + ps2[1] + ps2[2] + ps2[3];
    float mu = tot * (1.f / 512.f);
    float var = tot2 * (1.f / 512.f) - mu * mu;
    float rstd = rsqrtf(var + 1e-5f);
    int d0 = tid * 2;
    yr[d0]     = (v2.x - mu) * rstd * lng[d0]     + lnb[d0];
    yr[d0 + 1] = (v2.y - mu) * rstd * lng[d0 + 1] + lnb[d0 + 1];
}

// ---------------------------------------------------------------------------
extern "C" void kernel_launch(void* const* d_in, const int* in_sizes, int n_in,
                              void* d_out, int out_size, void* d_ws, size_t ws_size,
                              hipStream_t stream)
{
    const float* x       = (const float*)d_in[0];
    const float* gate_W  = (const float*)d_in[1];
    const float* gate_b  = (const float*)d_in[2];
    const float* in_W    = (const float*)d_in[3];
    const float* in_b    = (const float*)d_in[4];
    const float* out_W   = (const float*)d_in[5];
    const float* out_b   = (const float*)d_in[6];
    const float* opv_W   = (const float*)d_in[7];
    const float* opv_b   = (const float*)d_in[8];
    const float* opk_W   = (const float*)d_in[9];
    const float* opk_b   = (const float*)d_in[10];
    const float* opq_W   = (const float*)d_in[11];
    const float* opq_b   = (const float*)d_in[12];
    const float* op_dec  = (const float*)d_in[13];
    const float* opout_W = (const float*)d_in[14];
    const float* opout_b = (const float*)d_in[15];
    const float* ln_g    = (const float*)d_in[16];
    const float* ln_b    = (const float*)d_in[17];
    float* y = (float*)d_out;

    char* w = (char*)d_ws;
    auto alloc = [&](size_t bytes) { char* p = w; w += (bytes + 255) & ~(size_t)255; return p; };
    float* gi        = (float*)alloc((size_t)MM * 512 * 4);
    float* vkq       = (float*)alloc((size_t)MM * 192 * 4);
    float* o_intra   = (float*)alloc((size_t)MM * 64 * 4);
    float* ca_last   = (float*)alloc((size_t)BB * NC * SD * 4);
    float* wb_last   = (float*)alloc((size_t)BB * NC * SD * 4);
    float* h_prev    = (float*)alloc((size_t)BB * NC * SD * 4);
    float* dS        = (float*)alloc((size_t)BB * NCB * 4096 * 4);
    float* Sstart    = (float*)alloc((size_t)BB * NCB * 4096 * 4);
    float* bias_gi   = (float*)alloc(512 * 4);
    float* bias_vkq  = (float*)alloc(192 * 4);
    __hip_bfloat16* xb       = (__hip_bfloat16*)alloc((size_t)MM * 512 * 2);
    __hip_bfloat16* states16 = (__hip_bfloat16*)alloc((size_t)MM * 256 * 2);
    __hip_bfloat16* ob16     = (__hip_bfloat16*)alloc((size_t)MM * 64 * 2);
    __hip_bfloat16* Wgi      = (__hip_bfloat16*)alloc((size_t)512 * 512 * 2);
    __hip_bfloat16* Wvkq     = (__hip_bfloat16*)alloc((size_t)192 * 512 * 2);
    __hip_bfloat16* Wout     = (__hip_bfloat16*)alloc((size_t)512 * 256 * 2);
    __hip_bfloat16* Wopout   = (__hip_bfloat16*)alloc((size_t)512 * 64 * 2);

    // conversions
    hipLaunchKernelGGL(conv_x, dim3(MM * 512 / 8 / 256), dim3(256), 0, stream, x, xb);
    hipLaunchKernelGGL(conv_weights, dim3((524992 + 255) / 256), dim3(256), 0, stream,
                       gate_W, gate_b, in_W, in_b, opv_W, opk_W, opq_W,
                       opv_b, opk_b, opq_b, out_W, opout_W,
                       Wgi, Wvkq, Wout, Wopout, bias_gi, bias_vkq);
    // gate|in projection: gi[M][512], sigmoid on cols<256
    hipLaunchKernelGGL((gemm_bf16<128>), dim3(4, MM / 128), dim3(256), 0, stream,
                       xb, Wgi, bias_gi, (const float*)nullptr, gi, (__hip_bfloat16*)nullptr,
                       MM, 512, 512, 256, 0);
    // v|k|q projection: vkq[M][192]
    hipLaunchKernelGGL((gemm_bf16<64>), dim3(3, MM / 128), dim3(256), 0, stream,
                       xb, Wvkq, bias_vkq, (const float*)nullptr, vkq, (__hip_bfloat16*)nullptr,
                       MM, 192, 512, 0, 0);
    // gated chunked scan
    hipLaunchKernelGGL(scan_pass1, dim3(BB * NC * SD / 256), dim3(256), 0, stream,
                       gi, ca_last, wb_last);
    hipLaunchKernelGGL(scan_pass2, dim3(BB * SD / 256), dim3(256), 0, stream,
                       ca_last, wb_last, h_prev);
    hipLaunchKernelGGL(scan_pass3, dim3(BB * NC * SD / 256), dim3(256), 0, stream,
                       gi, h_prev, states16);
    // y = x + states @ out_W + out_b
    hipLaunchKernelGGL((gemm_bf16<128>), dim3(4, MM / 128), dim3(256), 0, stream,
                       states16, Wout, out_b, x, y, (__hip_bfloat16*)nullptr,
                       MM, 512, 256, 0, 0);
    // binding scan
    hipLaunchKernelGGL(bind_p1, dim3(BB * NCB), dim3(256), 0, stream,
                       vkq, op_dec, o_intra, dS);
    hipLaunchKernelGGL(bind_p2, dim3(BB * 64 * 64 / 256), dim3(256), 0, stream,
                       dS, op_dec, Sstart);
    hipLaunchKernelGGL(bind_p3, dim3(BB * NCB), dim3(256), 0, stream,
                       vkq, Sstart, op_dec, o_intra, ob16);
    // y += ob16 @ opout_W + opout_b
    hipLaunchKernelGGL((gemm_bf16<128>), dim3(4, MM / 128), dim3(256), 0, stream,
                       ob16, Wopout, opout_b, (const float*)nullptr, y, (__hip_bfloat16*)nullptr,
                       MM, 512, 64, 0, 1);
    // LayerNorm in place
    hipLaunchKernelGGL(ln_kernel, dim3(MM), dim3(256), 0, stream, y, ln_g, ln_b);
}

// Round 3
// 149.737 us; speedup vs baseline: 2.7178x; 1.2558x over previous
//
#include <hip/hip_runtime.h>
#include <hip/hip_bf16.h>
#include <math.h>

#define BB 8
#define TT 2048
#define DD 512
#define SD 256
#define OD 64
#define CHUNK 32
#define NC 64          // TT/CHUNK
#define CB 64          // binding-scan chunk
#define NCB 32         // TT/CB
#define MM (BB*TT)     // 16384

typedef __attribute__((ext_vector_type(8))) short bf16x8_t;
typedef __attribute__((ext_vector_type(4))) float f32x4;

// async global->LDS, 16B per lane. LDS dest must be wave-uniform base (+lane*16 by HW).
__device__ __forceinline__ void gload_lds16(const void* gsrc, void* ldst) {
    __builtin_amdgcn_global_load_lds(
        (const __attribute__((address_space(1))) unsigned int*)gsrc,
        (__attribute__((address_space(3))) unsigned int*)ldst,
        16, 0, 0);
}

// ---------------------------------------------------------------------------
// fp32 -> bf16 conversion of x
// ---------------------------------------------------------------------------
__global__ __launch_bounds__(256) void conv_x(
    const float* __restrict__ x, __hip_bfloat16* __restrict__ xb)
{
    size_t i = ((size_t)blockIdx.x * 256 + threadIdx.x) * 8;
    float4 v0 = *(const float4*)&x[i];
    float4 v1 = *(const float4*)&x[i + 4];
    alignas(16) __hip_bfloat16 h[8] = {
        __float2bfloat16(v0.x), __float2bfloat16(v0.y),
        __float2bfloat16(v0.z), __float2bfloat16(v0.w),
        __float2bfloat16(v1.x), __float2bfloat16(v1.y),
        __float2bfloat16(v1.z), __float2bfloat16(v1.w)};
    *(float4*)&xb[i] = *(float4*)h;
}

// ---------------------------------------------------------------------------
// Weight conversion: Wcat[768][512] bf16 = [gate|in|v|k|q|pad64]^T,
// Wout[512][256] bf16 = out_W^T, bias_cat[768].
// ---------------------------------------------------------------------------
__global__ __launch_bounds__(256) void conv_weights(
    const float* __restrict__ gate_W, const float* __restrict__ gate_b,
    const float* __restrict__ in_W,   const float* __restrict__ in_b,
    const float* __restrict__ opv_W,  const float* __restrict__ opk_W,
    const float* __restrict__ opq_W,
    const float* __restrict__ opv_b,  const float* __restrict__ opk_b,
    const float* __restrict__ opq_b,
    const float* __restrict__ out_W,
    __hip_bfloat16* __restrict__ Wcat, __hip_bfloat16* __restrict__ Wout,
    float* __restrict__ bias_cat)
{
    int idx = blockIdx.x * 256 + threadIdx.x;
    if (idx < 393216) {                       // Wcat [768][512]
        int n = idx >> 9, k = idx & 511;
        float v;
        if (n < 256)       v = gate_W[k * 256 + n];
        else if (n < 512)  v = in_W[k * 256 + (n - 256)];
        else if (n < 704) {
            int h = (n - 512) >> 6, j = (n - 512) & 63;
            const float* W = (h == 0) ? opv_W : (h == 1) ? opk_W : opq_W;
            v = W[k * 64 + j];
        } else v = 0.f;
        Wcat[idx] = __float2bfloat16(v);
        return;
    }
    idx -= 393216;
    if (idx < 131072) {                       // Wout [512][256]
        int n = idx >> 8, k = idx & 255;
        Wout[idx] = __float2bfloat16(out_W[k * 512 + n]);
        return;
    }
    idx -= 131072;
    if (idx < 768) {
        float v;
        if (idx < 256)      v = gate_b[idx];
        else if (idx < 512) v = in_b[idx - 256];
        else if (idx < 704) {
            int h = (idx - 512) >> 6, j = (idx - 512) & 63;
            v = (h == 0) ? opv_b[j] : (h == 1) ? opk_b[j] : opq_b[j];
        } else v = 0.f;
        bias_cat[idx] = v;
    }
}

// ---------------------------------------------------------------------------
// bf16 MFMA GEMM, m97-style: 128x128 tile, BK=32, global_load_lds(16B) into
// double-buffered LDS, granule XOR swizzle via pre-swizzled SOURCE + swizzled
// READ (linear LDS dest). 4 waves (2x2), wave tile 64x64, 16 MFMA/k-step.
// Output routing: cols <n0 -> out0 (sigmoid on <sigCols, +addsrc), else out1.
// ---------------------------------------------------------------------------
__global__ __launch_bounds__(256) void gemm_bf16(
    const __hip_bfloat16* __restrict__ A,
    const __hip_bfloat16* __restrict__ Bt,
    const float* __restrict__ bias,
    const float* __restrict__ addsrc,       // [M][n0] fp32 or null
    float* __restrict__ out0,
    float* __restrict__ out1,               // stride N-n0 (may be null if n0==N)
    int M, int N, int K, int n0, int sigCols)
{
    constexpr int BM = 128, BK = 32;
    __shared__ alignas(16) __hip_bfloat16 As[2][BM * BK];   // 8KB each
    __shared__ alignas(16) __hip_bfloat16 Bs[2][BM * BK];
    const int tid = threadIdx.x;
    const int lane = tid & 63, wid = tid >> 6;
    const int wr = wid >> 1, wc = wid & 1;
    const int bm = blockIdx.y * BM, bn = blockIdx.x * BM;
    const int l15 = lane & 15, hgr = lane >> 4;

    // staging: granule g = s*256+tid; row=g>>2, slot=g&3 holds src granule slot^((row>>1)&3)
    const __hip_bfloat16* srcA[2];
    const __hip_bfloat16* srcB[2];
    int ldsOff[2];
    #pragma unroll
    for (int s = 0; s < 2; ++s) {
        int g = s * 256 + tid;
        int row = g >> 2, slot = g & 3;
        int sgc = slot ^ ((row >> 1) & 3);
        srcA[s] = A  + (size_t)(bm + row) * K + sgc * 8;
        srcB[s] = Bt + (size_t)(bn + row) * K + sgc * 8;
        ldsOff[s] = (s * 256 + (tid & ~63)) * 16;   // bytes, wave-uniform
    }
    // fragment read offsets (bytes)
    int offA[4], offB[4];
    #pragma unroll
    for (int mi = 0; mi < 4; ++mi) {
        int r = wr * 64 + mi * 16 + l15;
        offA[mi] = r * 64 + (hgr ^ ((r >> 1) & 3)) * 16;
    }
    #pragma unroll
    for (int nj = 0; nj < 4; ++nj) {
        int r = wc * 64 + nj * 16 + l15;
        offB[nj] = r * 64 + (hgr ^ ((r >> 1) & 3)) * 16;
    }

    f32x4 acc[4][4] = {};
    const int nk = K / BK;

    // prologue: stage k-step 0 into buf 0
    #pragma unroll
    for (int s = 0; s < 2; ++s) gload_lds16(srcA[s], (char*)&As[0][0] + ldsOff[s]);
    #pragma unroll
    for (int s = 0; s < 2; ++s) gload_lds16(srcB[s], (char*)&Bs[0][0] + ldsOff[s]);
    __syncthreads();

    int cur = 0;
    for (int t = 0; t < nk; ++t) {
        if (t + 1 < nk) {
            int k0 = (t + 1) * BK;
            #pragma unroll
            for (int s = 0; s < 2; ++s) gload_lds16(srcA[s] + k0, (char*)&As[cur ^ 1][0] + ldsOff[s]);
            #pragma unroll
            for (int s = 0; s < 2; ++s) gload_lds16(srcB[s] + k0, (char*)&Bs[cur ^ 1][0] + ldsOff[s]);
        }
        bf16x8_t af[4], bfr[4];
        #pragma unroll
        for (int mi = 0; mi < 4; ++mi)
            af[mi] = *(const bf16x8_t*)((const char*)&As[cur][0] + offA[mi]);
        #pragma unroll
        for (int nj = 0; nj < 4; ++nj)
            bfr[nj] = *(const bf16x8_t*)((const char*)&Bs[cur][0] + offB[nj]);
        #pragma unroll
        for (int mi = 0; mi < 4; ++mi)
            #pragma unroll
            for (int nj = 0; nj < 4; ++nj)
                acc[mi][nj] = __builtin_amdgcn_mfma_f32_16x16x32_bf16(
                    af[mi], bfr[nj], acc[mi][nj], 0, 0, 0);
        __syncthreads();   // drains vmcnt+lgkmcnt: next buffer staged, cur reusable
        cur ^= 1;
    }

    const int n1 = N - n0;
    #pragma unroll
    for (int mi = 0; mi < 4; ++mi) {
        #pragma unroll
        for (int nj = 0; nj < 4; ++nj) {
            int col = bn + wc * 64 + nj * 16 + l15;
            int r0 = bm + wr * 64 + mi * 16 + hgr * 4;
            float bv = bias[col];
            #pragma unroll
            for (int e = 0; e < 4; ++e) {
                int row = r0 + e;
                float val = acc[mi][nj][e] + bv;
                if (col < n0) {
                    size_t oi = (size_t)row * n0 + col;
                    if (addsrc) val += addsrc[oi];
                    if (col < sigCols) val = 1.f / (1.f + expf(-val));
                    out0[oi] = val;
                } else {
                    out1[(size_t)row * n1 + (col - n0)] = val;
                }
            }
        }
    }
}

// ---------------------------------------------------------------------------
// Gated scan. gi layout: [M][512], cols 0-255 = sigmoid(gate), 256-511 = in.
// ---------------------------------------------------------------------------
__global__ __launch_bounds__(256) void scan_pass1(
    const float* __restrict__ gi,
    float* __restrict__ ca_last, float* __restrict__ wb_last)
{
    int idx = blockIdx.x * 256 + threadIdx.x;        // 131072
    int sd = idx & 255;
    int c  = (idx >> 8) & 63;
    int b  = idx >> 14;
    size_t base = ((size_t)(b * TT + c * CHUNK)) * 512;
    float prod = 1.f, wb = 0.f;
    for (int i = 0; i < CHUNK; ++i) {
        size_t off = base + (size_t)i * 512;
        float g  = gi[off + sd];
        float il = gi[off + 256 + sd];
        float a = fmaxf(g, 1e-6f);
        prod *= a;
        wb += (1.f - g) * il / fmaxf(prod, 1e-8f);
    }
    int cidx = (b * NC + c) * SD + sd;
    ca_last[cidx] = prod;
    wb_last[cidx] = wb;
}

__global__ __launch_bounds__(256) void scan_pass2(
    const float* __restrict__ ca_last, const float* __restrict__ wb_last,
    float* __restrict__ h_prev)
{
    int idx = blockIdx.x * 256 + threadIdx.x;        // 2048
    int sd = idx & 255;
    int b  = idx >> 8;
    float h = 0.f;
    for (int c = 0; c < NC; ++c) {
        int o = (b * NC + c) * SD + sd;
        h_prev[o] = h;
        h = ca_last[o] * (h + wb_last[o]);
    }
}

__global__ __launch_bounds__(256) void scan_pass3(
    const float* __restrict__ gi, const float* __restrict__ h_prev,
    __hip_bfloat16* __restrict__ states)
{
    int idx = blockIdx.x * 256 + threadIdx.x;        // 131072
    int sd = idx & 255;
    int c  = (idx >> 8) & 63;
    int b  = idx >> 14;
    size_t base = ((size_t)(b * TT + c * CHUNK)) * 512;
    size_t obase = ((size_t)(b * TT + c * CHUNK)) * 256 + sd;
    float h = h_prev[(b * NC + c) * SD + sd];
    float prod = 1.f, wb = 0.f;
    for (int i = 0; i < CHUNK; ++i) {
        size_t off = base + (size_t)i * 512;
        float g  = gi[off + sd];
        float il = gi[off + 256 + sd];
        float a = fmaxf(g, 1e-6f);
        prod *= a;
        wb += (1.f - g) * il / fmaxf(prod, 1e-8f);
        states[obase + (size_t)i * 256] = __float2bfloat16(prod * (h + wb));
    }
}

// ---------------------------------------------------------------------------
// Binding scan. vkq layout: [M][256], v=0-63, k=64-127, q=128-191 (fp32).
// LDS layouts chosen so every inner-loop read is broadcast or 2-way:
//   B1 = Qt[d][t] then Vp[m][i] ; B2 = Kt[d][t] then Krow[m][j] ; B3 = Amt[s][t]
// all with row stride 68 floats (16B aligned).
// ---------------------------------------------------------------------------
#define LST 68
__global__ __launch_bounds__(256) void bind_p1(
    const float* __restrict__ vkq, const float* __restrict__ op_decay,
    float* __restrict__ o, float* __restrict__ dS)
{
    __shared__ float B1[64 * LST];
    __shared__ float B2[64 * LST];
    __shared__ float B3[64 * LST];
    __shared__ float l2d[64];
    const int bc = blockIdx.x;     // b*NCB + c
    const int b = bc >> 5, c = bc & 31;
    const size_t base = ((size_t)b * TT + (size_t)c * CB) * 256;
    const size_t obase = ((size_t)b * TT + (size_t)c * CB) * OD;
    const int tid = threadIdx.x;
    if (tid < 64) l2d[tid] = log2f(1.f / (1.f + expf(-op_decay[tid])));
    const int lr = tid >> 4, lc = (tid & 15) << 2;
    // load Qt, Kt (transposed [d][t])
    #pragma unroll
    for (int rr = 0; rr < 4; ++rr) {
        int t = lr + rr * 16;
        float4 qv = *(const float4*)&vkq[base + t * 256 + 128 + lc];
        float4 kv = *(const float4*)&vkq[base + t * 256 + 64 + lc];
        float q4[4] = {qv.x, qv.y, qv.z, qv.w};
        float k4[4] = {kv.x, kv.y, kv.z, kv.w};
        #pragma unroll
        for (int j = 0; j < 4; ++j) {
            B1[(lc + j) * LST + t] = q4[j];
            B2[(lc + j) * LST + t] = k4[j];
        }
    }
    __syncthreads();
    const int tx = tid & 15, ty = tid >> 4;   // 16x16 thread grid, 4x4 tiles
    // Phase A: A[t][s] = sum_d Qt[d][t]*Kt[d][s]; store masked transpose Amt[s][t]
    {
        float a_acc[4][4] = {};
        for (int d = 0; d < 64; ++d) {
            float4 q4 = *(const float4*)&B1[d * LST + 4 * ty];
            float4 k4 = *(const float4*)&B2[d * LST + 4 * tx];
            float qr[4] = {q4.x, q4.y, q4.z, q4.w};
            float kr[4] = {k4.x, k4.y, k4.z, k4.w};
            #pragma unroll
            for (int r = 0; r < 4; ++r)
                #pragma unroll
                for (int s = 0; s < 4; ++s)
                    a_acc[r][s] = fmaf(qr[r], kr[s], a_acc[r][s]);
        }
        __syncthreads();   // Qt/Kt reads done (B1/B2 reused below; B3 write now)
        #pragma unroll
        for (int s = 0; s < 4; ++s) {
            int ss = 4 * tx + s;
            float w[4];
            #pragma unroll
            for (int r = 0; r < 4; ++r)
                w[r] = (ss <= 4 * ty + r) ? a_acc[r][s] : 0.f;
            *(float4*)&B3[ss * LST + 4 * ty] = *(float4*)w;
        }
    }
    // load Vp[m][i] (decay-rescaled) over B1, Krow[m][j] over B2
    #pragma unroll
    for (int rr = 0; rr < 4; ++rr) {
        int m = lr + rr * 16;
        float4 vv = *(const float4*)&vkq[base + m * 256 + 0 + lc];
        float4 kv = *(const float4*)&vkq[base + m * 256 + 64 + lc];
        float v4[4] = {vv.x, vv.y, vv.z, vv.w};
        #pragma unroll
        for (int j = 0; j < 4; ++j)
            v4[j] *= exp2f(-(float)m * l2d[lc + j]);
        *(float4*)&B1[m * LST + lc] = *(float4*)v4;
        *(float4*)&B2[m * LST + lc] = kv;
    }
    __syncthreads();
    // Phase B: o[t][i] = 2^(t*l2d[i]) * sum_s Amt[s][t]*Vp[s][i]
    {
        float p[4][4] = {};
        for (int s = 0; s < 64; ++s) {
            float4 a4 = *(const float4*)&B3[s * LST + 4 * ty];
            float4 v4 = *(const float4*)&B1[s * LST + 4 * tx];
            float ar[4] = {a4.x, a4.y, a4.z, a4.w};
            float vr[4] = {v4.x, v4.y, v4.z, v4.w};
            #pragma unroll
            for (int r = 0; r < 4; ++r)
                #pragma unroll
                for (int i2 = 0; i2 < 4; ++i2)
                    p[r][i2] = fmaf(ar[r], vr[i2], p[r][i2]);
        }
        #pragma unroll
        for (int r = 0; r < 4; ++r) {
            int t = 4 * ty + r;
            float w[4];
            #pragma unroll
            for (int i2 = 0; i2 < 4; ++i2)
                w[i2] = exp2f((float)t * l2d[4 * tx + i2]) * p[r][i2];
            *(float4*)&o[obase + t * OD + 4 * tx] = *(float4*)w;
        }
    }
    // Phase C: dS[i][j] = 2^(63*l2d[i]) * sum_m Vp[m][i]*Krow[m][j]
    {
        float sacc[4][4] = {};
        for (int m = 0; m < 64; ++m) {
            float4 v4 = *(const float4*)&B1[m * LST + 4 * ty];
            float4 k4 = *(const float4*)&B2[m * LST + 4 * tx];
            float vr[4] = {v4.x, v4.y, v4.z, v4.w};
            float kr[4] = {k4.x, k4.y, k4.z, k4.w};
            #pragma unroll
            for (int r = 0; r < 4; ++r)
                #pragma unroll
                for (int j = 0; j < 4; ++j)
                    sacc[r][j] = fmaf(vr[r], kr[j], sacc[r][j]);
        }
        float* dSb = dS + (size_t)bc * 4096;
        #pragma unroll
        for (int r = 0; r < 4; ++r) {
            int i = 4 * ty + r;
            float scale = exp2f(63.f * l2d[i]);
            float w[4];
            #pragma unroll
            for (int j2 = 0; j2 < 4; ++j2)
                w[j2] = scale * sacc[r][j2];
            *(float4*)&dSb[i * 64 + 4 * tx] = *(float4*)w;
        }
    }
}

__global__ __launch_bounds__(256) void bind_p2(
    const float* __restrict__ dS, const float* __restrict__ op_decay,
    float* __restrict__ Sstart)
{
    int idx = blockIdx.x * 256 + threadIdx.x;   // 32768
    int j = idx & 63, i = (idx >> 6) & 63, b = idx >> 12;
    float dec = 1.f / (1.f + expf(-op_decay[i]));
    float d64 = exp2f(64.f * log2f(dec));
    float S = 0.f;
    for (int c = 0; c < NCB; ++c) {
        size_t o = (((size_t)b * NCB + c) * 4096) + i * 64 + j;
        Sstart[o] = S;
        S = d64 * S + dS[o];
    }
}

// in-place: o += dec_i^(l+1) * (Q @ Sstart^T)
__global__ __launch_bounds__(256) void bind_p3(
    const float* __restrict__ vkq, const float* __restrict__ Sstart,
    const float* __restrict__ op_decay, float* __restrict__ o)
{
    __shared__ float B1[64 * LST];   // Qt[j][t]
    __shared__ float B2[64 * LST];   // St[j][i]
    __shared__ float l2d[64];
    const int bc = blockIdx.x;
    const int b = bc >> 5, c = bc & 31;
    const size_t base = ((size_t)b * TT + (size_t)c * CB) * 256;
    const size_t obase = ((size_t)b * TT + (size_t)c * CB) * OD;
    const int tid = threadIdx.x;
    if (tid < 64) l2d[tid] = log2f(1.f / (1.f + expf(-op_decay[tid])));
    const int lr = tid >> 4, lc = (tid & 15) << 2;
    const float* Sb = Sstart + (size_t)bc * 4096;
    #pragma unroll
    for (int rr = 0; rr < 4; ++rr) {
        int t = lr + rr * 16;
        float4 qv = *(const float4*)&vkq[base + t * 256 + 128 + lc];
        float4 sv = *(const float4*)&Sb[t * 64 + lc];   // row i=t, cols j
        float q4[4] = {qv.x, qv.y, qv.z, qv.w};
        float s4[4] = {sv.x, sv.y, sv.z, sv.w};
        #pragma unroll
        for (int j = 0; j < 4; ++j) {
            B1[(lc + j) * LST + t] = q4[j];
            B2[(lc + j) * LST + t] = s4[j];   // St[j][i=t]
        }
    }
    __syncthreads();
    const int tx = tid & 15, ty = tid >> 4;
    float acc[4][4] = {};
    for (int j = 0; j < 64; ++j) {
        float4 q4 = *(const float4*)&B1[j * LST + 4 * ty];
        float4 s4 = *(const float4*)&B2[j * LST + 4 * tx];
        float qr[4] = {q4.x, q4.y, q4.z, q4.w};
        float sr[4] = {s4.x, s4.y, s4.z, s4.w};
        #pragma unroll
        for (int r = 0; r < 4; ++r)
            #pragma unroll
            for (int i2 = 0; i2 < 4; ++i2)
                acc[r][i2] = fmaf(qr[r], sr[i2], acc[r][i2]);
    }
    #pragma unroll
    for (int r = 0; r < 4; ++r) {
        int l = 4 * ty + r;
        #pragma unroll
        for (int i2 = 0; i2 < 4; ++i2) {
            int i = 4 * tx + i2;
            size_t oi = obase + l * OD + i;
            o[oi] += exp2f((float)(l + 1) * l2d[i]) * acc[r][i2];
        }
    }
}

// ---------------------------------------------------------------------------
// Fused: y_out = LN( y_partial + ob@opout_W + opout_b ) * ln_g + ln_b
// 16 rows per block; W kept fp32 (L2-resident), matvec on VALU.
// ---------------------------------------------------------------------------
__global__ __launch_bounds__(256) void bindout_ln(
    const float* __restrict__ ob,      // [M][64]
    const float* __restrict__ Wop,     // [64][512] fp32 (original layout)
    const float* __restrict__ opb,     // [512]
    const float* __restrict__ ypart,   // [M][512] (== yout, in-place per-row)
    const float* __restrict__ lng, const float* __restrict__ lnb,
    float* __restrict__ yout)
{
    constexpr int ROWS = 16;
    __shared__ float obs[ROWS * 64];       // 4KB
    __shared__ float yt[ROWS][512];        // 32KB
    const int r0 = blockIdx.x * ROWS;
    const int tid = threadIdx.x;
    {
        int i = tid * 4;
        *(float4*)&obs[i] = *(const float4*)&ob[(size_t)r0 * 64 + i];
    }
    __syncthreads();
    const int c0 = tid * 2;
    float2 acc[ROWS];
    #pragma unroll
    for (int r = 0; r < ROWS; ++r) acc[r] = make_float2(0.f, 0.f);
    for (int k = 0; k < 64; ++k) {
        float2 wv = *(const float2*)&Wop[k * 512 + c0];
        #pragma unroll
        for (int r = 0; r < ROWS; ++r) {
            float obv = obs[r * 64 + k];
            acc[r].x = fmaf(obv, wv.x, acc[r].x);
            acc[r].y = fmaf(obv, wv.y, acc[r].y);
        }
    }
    float bx = opb[c0], by = opb[c0 + 1];
    #pragma unroll
    for (int r = 0; r < ROWS; ++r) {
        float2 yp = *(const float2*)&ypart[((size_t)(r0 + r)) * 512 + c0];
        yt[r][c0]     = acc[r].x + bx + yp.x;
        yt[r][c0 + 1] = acc[r].y + by + yp.y;
    }
    __syncthreads();
    const int lane = tid & 63, w = tid >> 6;
    #pragma unroll
    for (int rr = 0; rr < 4; ++rr) {
        int r = w * 4 + rr;
        float vals[8];
        float s = 0.f, s2 = 0.f;
        #pragma unroll
        for (int e = 0; e < 8; ++e) {
            float v = yt[r][lane * 8 + e];
            vals[e] = v; s += v; s2 += v * v;
        }
        #pragma unroll
        for (int off = 32; off > 0; off >>= 1) {
            s  += __shfl_down(s, off);
            s2 += __shfl_down(s2, off);
        }
        s = __shfl(s, 0); s2 = __shfl(s2, 0);
        float mu = s * (1.f / 512.f);
        float var = s2 * (1.f / 512.f) - mu * mu;
        float rstd = rsqrtf(var + 1e-5f);
        #pragma unroll
        for (int e = 0; e < 8; ++e) {
            int d = lane * 8 + e;
            yout[((size_t)(r0 + r)) * 512 + d] = (vals[e] - mu) * rstd * lng[d] + lnb[d];
        }
    }
}

// ---------------------------------------------------------------------------
extern "C" void kernel_launch(void* const* d_in, const int* in_sizes, int n_in,
                              void* d_out, int out_size, void* d_ws, size_t ws_size,
                              hipStream_t stream)
{
    const float* x       = (const float*)d_in[0];
    const float* gate_W  = (const float*)d_in[1];
    const float* gate_b  = (const float*)d_in[2];
    const float* in_W    = (const float*)d_in[3];
    const float* in_b    = (const float*)d_in[4];
    const float* out_W   = (const float*)d_in[5];
    const float* out_b   = (const float*)d_in[6];
    const float* opv_W   = (const float*)d_in[7];
    const float* opv_b   = (const float*)d_in[8];
    const float* opk_W   = (const float*)d_in[9];
    const float* opk_b   = (const float*)d_in[10];
    const float* opq_W   = (const float*)d_in[11];
    const float* opq_b   = (const float*)d_in[12];
    const float* op_dec  = (const float*)d_in[13];
    const float* opout_W = (const float*)d_in[14];
    const float* opout_b = (const float*)d_in[15];
    const float* ln_g    = (const float*)d_in[16];
    const float* ln_b    = (const float*)d_in[17];
    float* y = (float*)d_out;

    char* w = (char*)d_ws;
    auto alloc = [&](size_t bytes) { char* p = w; w += (bytes + 255) & ~(size_t)255; return p; };
    float* gi        = (float*)alloc((size_t)MM * 512 * 4);
    float* vkq       = (float*)alloc((size_t)MM * 256 * 4);
    float* obind     = (float*)alloc((size_t)MM * 64 * 4);
    float* ca_last   = (float*)alloc((size_t)BB * NC * SD * 4);
    float* wb_last   = (float*)alloc((size_t)BB * NC * SD * 4);
    float* h_prev    = (float*)alloc((size_t)BB * NC * SD * 4);
    float* dS        = (float*)alloc((size_t)BB * NCB * 4096 * 4);
    float* Sstart    = (float*)alloc((size_t)BB * NCB * 4096 * 4);
    float* bias_cat  = (float*)alloc(768 * 4);
    __hip_bfloat16* xb       = (__hip_bfloat16*)alloc((size_t)MM * 512 * 2);
    __hip_bfloat16* states16 = (__hip_bfloat16*)alloc((size_t)MM * 256 * 2);
    __hip_bfloat16* Wcat     = (__hip_bfloat16*)alloc((size_t)768 * 512 * 2);
    __hip_bfloat16* Wout     = (__hip_bfloat16*)alloc((size_t)512 * 256 * 2);

    hipLaunchKernelGGL(conv_x, dim3(MM * 512 / 8 / 256), dim3(256), 0, stream, x, xb);
    hipLaunchKernelGGL(conv_weights, dim3((393216 + 131072 + 768 + 255) / 256), dim3(256), 0, stream,
                       gate_W, gate_b, in_W, in_b, opv_W, opk_W, opq_W,
                       opv_b, opk_b, opq_b, out_W, Wcat, Wout, bias_cat);
    // fused projection: [gi | vkq] = xb @ Wcat^T + bias  (sigmoid on cols<256)
    hipLaunchKernelGGL(gemm_bf16, dim3(6, MM / 128), dim3(256), 0, stream,
                       xb, Wcat, bias_cat, (const float*)nullptr, gi, vkq,
                       MM, 768, 512, 512, 256);
    // gated chunked scan
    hipLaunchKernelGGL(scan_pass1, dim3(BB * NC * SD / 256), dim3(256), 0, stream,
                       gi, ca_last, wb_last);
    hipLaunchKernelGGL(scan_pass2, dim3(BB * SD / 256), dim3(256), 0, stream,
                       ca_last, wb_last, h_prev);
    hipLaunchKernelGGL(scan_pass3, dim3(BB * NC * SD / 256), dim3(256), 0, stream,
                       gi, h_prev, states16);
    // y_partial = x + states @ out_W + out_b
    hipLaunchKernelGGL(gemm_bf16, dim3(4, MM / 128), dim3(256), 0, stream,
                       states16, Wout, out_b, x, y, (float*)nullptr,
                       MM, 512, 256, 512, 0);
    // binding scan
    hipLaunchKernelGGL(bind_p1, dim3(BB * NCB), dim3(256), 0, stream,
                       vkq, op_dec, obind, dS);
    hipLaunchKernelGGL(bind_p2, dim3(BB * 64 * 64 / 256), dim3(256), 0, stream,
                       dS, op_dec, Sstart);
    hipLaunchKernelGGL(bind_p3, dim3(BB * NCB), dim3(256), 0, stream,
                       vkq, Sstart, op_dec, obind);
    // fused bind-out GEMM + residual + LayerNorm (in-place on y)
    hipLaunchKernelGGL(bindout_ln, dim3(MM / 16), dim3(256), 0, stream,
                       obind, opout_W, opout_b, y, ln_g, ln_b, y);
}

// Round 4
// 129.994 us; speedup vs baseline: 3.1306x; 1.1519x over previous
//
#include <hip/hip_runtime.h>
#include <hip/hip_bf16.h>
#include <math.h>

#define BB 8
#define TT 2048
#define DD 512
#define SD 256
#define OD 64
#define CHUNK 32
#define NC 64          // TT/CHUNK
#define CB 64          // binding-scan chunk
#define NCB 32         // TT/CB
#define MM (BB*TT)     // 16384
#define KCAT 320       // states(256) | obind(64)

typedef __attribute__((ext_vector_type(8))) short bf16x8_t;
typedef __attribute__((ext_vector_type(4))) float f32x4;

// async global->LDS, 16B per lane. LDS dest must be wave-uniform base (+lane*16 by HW).
__device__ __forceinline__ void gload_lds16(const void* gsrc, void* ldst) {
    __builtin_amdgcn_global_load_lds(
        (const __attribute__((address_space(1))) unsigned int*)gsrc,
        (__attribute__((address_space(3))) unsigned int*)ldst,
        16, 0, 0);
}

// ---------------------------------------------------------------------------
// conv_all: x->bf16 (blocks < 4096) and all weight prep (remaining blocks).
// Wcat[768][512] = [gate|in|v|k|q|pad]^T bf16; Wcomb[512][320] = [out_W^T | opout_W^T];
// bias_cat[768]; bias_comb[512] = out_b + opout_b.
// ---------------------------------------------------------------------------
__global__ __launch_bounds__(256) void conv_all(
    const float* __restrict__ x,
    const float* __restrict__ gate_W, const float* __restrict__ gate_b,
    const float* __restrict__ in_W,   const float* __restrict__ in_b,
    const float* __restrict__ opv_W,  const float* __restrict__ opk_W,
    const float* __restrict__ opq_W,
    const float* __restrict__ opv_b,  const float* __restrict__ opk_b,
    const float* __restrict__ opq_b,
    const float* __restrict__ out_W,  const float* __restrict__ out_b,
    const float* __restrict__ opout_W, const float* __restrict__ opout_b,
    __hip_bfloat16* __restrict__ xb,
    __hip_bfloat16* __restrict__ Wcat,  __hip_bfloat16* __restrict__ Wcomb,
    float* __restrict__ bias_cat, float* __restrict__ bias_comb)
{
    const int bid = blockIdx.x;
    if (bid < 4096) {
        size_t i = ((size_t)bid * 256 + threadIdx.x) * 8;
        float4 v0 = *(const float4*)&x[i];
        float4 v1 = *(const float4*)&x[i + 4];
        alignas(16) __hip_bfloat16 h[8] = {
            __float2bfloat16(v0.x), __float2bfloat16(v0.y),
            __float2bfloat16(v0.z), __float2bfloat16(v0.w),
            __float2bfloat16(v1.x), __float2bfloat16(v1.y),
            __float2bfloat16(v1.z), __float2bfloat16(v1.w)};
        *(float4*)&xb[i] = *(float4*)h;
        return;
    }
    int idx = (bid - 4096) * 256 + threadIdx.x;
    if (idx < 393216) {                       // Wcat [768][512]
        int n = idx >> 9, k = idx & 511;
        float v;
        if (n < 256)       v = gate_W[k * 256 + n];
        else if (n < 512)  v = in_W[k * 256 + (n - 256)];
        else if (n < 704) {
            int h = (n - 512) >> 6, j = (n - 512) & 63;
            const float* W = (h == 0) ? opv_W : (h == 1) ? opk_W : opq_W;
            v = W[k * 64 + j];
        } else v = 0.f;
        Wcat[idx] = __float2bfloat16(v);
        return;
    }
    idx -= 393216;
    if (idx < 163840) {                       // Wcomb [512][320]
        int n = idx / KCAT, k = idx % KCAT;
        float v = (k < 256) ? out_W[k * 512 + n] : opout_W[(k - 256) * 512 + n];
        Wcomb[idx] = __float2bfloat16(v);
        return;
    }
    idx -= 163840;
    if (idx < 768) {
        float v;
        if (idx < 256)      v = gate_b[idx];
        else if (idx < 512) v = in_b[idx - 256];
        else if (idx < 704) {
            int h = (idx - 512) >> 6, j = (idx - 512) & 63;
            v = (h == 0) ? opv_b[j] : (h == 1) ? opk_b[j] : opq_b[j];
        } else v = 0.f;
        bias_cat[idx] = v;
        return;
    }
    idx -= 768;
    if (idx < 512) bias_comb[idx] = out_b[idx] + opout_b[idx];
}

// ---------------------------------------------------------------------------
// bf16 MFMA GEMM, m97-style: 128x128 tile, BK=32, global_load_lds(16B) into
// double-buffered LDS, granule XOR swizzle via pre-swizzled SOURCE + swizzled
// READ (linear LDS dest). 4 waves (2x2), wave tile 64x64, 16 MFMA/k-step.
// Output routing: cols <n0 -> out0 (sigmoid on <sigCols, +addsrc), else out1.
// ---------------------------------------------------------------------------
__global__ __launch_bounds__(256) void gemm_bf16(
    const __hip_bfloat16* __restrict__ A,
    const __hip_bfloat16* __restrict__ Bt,
    const float* __restrict__ bias,
    const float* __restrict__ addsrc,       // [M][n0] fp32 or null
    float* __restrict__ out0,
    float* __restrict__ out1,               // stride N-n0 (may be null if n0==N)
    int M, int N, int K, int n0, int sigCols)
{
    constexpr int BM = 128, BK = 32;
    __shared__ alignas(16) __hip_bfloat16 As[2][BM * BK];   // 8KB each
    __shared__ alignas(16) __hip_bfloat16 Bs[2][BM * BK];
    const int tid = threadIdx.x;
    const int lane = tid & 63, wid = tid >> 6;
    const int wr = wid >> 1, wc = wid & 1;
    const int bm = blockIdx.y * BM, bn = blockIdx.x * BM;
    const int l15 = lane & 15, hgr = lane >> 4;

    const __hip_bfloat16* srcA[2];
    const __hip_bfloat16* srcB[2];
    int ldsOff[2];
    #pragma unroll
    for (int s = 0; s < 2; ++s) {
        int g = s * 256 + tid;
        int row = g >> 2, slot = g & 3;
        int sgc = slot ^ ((row >> 1) & 3);
        srcA[s] = A  + (size_t)(bm + row) * K + sgc * 8;
        srcB[s] = Bt + (size_t)(bn + row) * K + sgc * 8;
        ldsOff[s] = (s * 256 + (tid & ~63)) * 16;   // bytes, wave-uniform
    }
    int offA[4], offB[4];
    #pragma unroll
    for (int mi = 0; mi < 4; ++mi) {
        int r = wr * 64 + mi * 16 + l15;
        offA[mi] = r * 64 + (hgr ^ ((r >> 1) & 3)) * 16;
    }
    #pragma unroll
    for (int nj = 0; nj < 4; ++nj) {
        int r = wc * 64 + nj * 16 + l15;
        offB[nj] = r * 64 + (hgr ^ ((r >> 1) & 3)) * 16;
    }

    f32x4 acc[4][4] = {};
    const int nk = K / BK;

    #pragma unroll
    for (int s = 0; s < 2; ++s) gload_lds16(srcA[s], (char*)&As[0][0] + ldsOff[s]);
    #pragma unroll
    for (int s = 0; s < 2; ++s) gload_lds16(srcB[s], (char*)&Bs[0][0] + ldsOff[s]);
    __syncthreads();

    int cur = 0;
    for (int t = 0; t < nk; ++t) {
        if (t + 1 < nk) {
            int k0 = (t + 1) * BK;
            #pragma unroll
            for (int s = 0; s < 2; ++s) gload_lds16(srcA[s] + k0, (char*)&As[cur ^ 1][0] + ldsOff[s]);
            #pragma unroll
            for (int s = 0; s < 2; ++s) gload_lds16(srcB[s] + k0, (char*)&Bs[cur ^ 1][0] + ldsOff[s]);
        }
        bf16x8_t af[4], bfr[4];
        #pragma unroll
        for (int mi = 0; mi < 4; ++mi)
            af[mi] = *(const bf16x8_t*)((const char*)&As[cur][0] + offA[mi]);
        #pragma unroll
        for (int nj = 0; nj < 4; ++nj)
            bfr[nj] = *(const bf16x8_t*)((const char*)&Bs[cur][0] + offB[nj]);
        #pragma unroll
        for (int mi = 0; mi < 4; ++mi)
            #pragma unroll
            for (int nj = 0; nj < 4; ++nj)
                acc[mi][nj] = __builtin_amdgcn_mfma_f32_16x16x32_bf16(
                    af[mi], bfr[nj], acc[mi][nj], 0, 0, 0);
        __syncthreads();
        cur ^= 1;
    }

    const int n1 = N - n0;
    #pragma unroll
    for (int mi = 0; mi < 4; ++mi) {
        #pragma unroll
        for (int nj = 0; nj < 4; ++nj) {
            int col = bn + wc * 64 + nj * 16 + l15;
            int r0 = bm + wr * 64 + mi * 16 + hgr * 4;
            float bv = bias[col];
            #pragma unroll
            for (int e = 0; e < 4; ++e) {
                int row = r0 + e;
                float val = acc[mi][nj][e] + bv;
                if (col < n0) {
                    size_t oi = (size_t)row * n0 + col;
                    if (addsrc) val += addsrc[oi];
                    if (col < sigCols) val = 1.f / (1.f + expf(-val));
                    out0[oi] = val;
                } else {
                    out1[(size_t)row * n1 + (col - n0)] = val;
                }
            }
        }
    }
}

// ---------------------------------------------------------------------------
// Device bodies for scan / bind phases (merged dispatch wrappers below).
// gi layout: [M][512], cols 0-255 = sigmoid(gate), 256-511 = in.
// vkq layout: [M][256], v=0-63, k=64-127, q=128-191 (fp32).
// ---------------------------------------------------------------------------
__device__ void scan_pass1_body(int blk,
    const float* __restrict__ gi,
    float* __restrict__ ca_last, float* __restrict__ wb_last)
{
    int idx = blk * 256 + threadIdx.x;        // 131072
    int sd = idx & 255;
    int c  = (idx >> 8) & 63;
    int b  = idx >> 14;
    size_t base = ((size_t)(b * TT + c * CHUNK)) * 512;
    float prod = 1.f, wb = 0.f;
    for (int i = 0; i < CHUNK; ++i) {
        size_t off = base + (size_t)i * 512;
        float g  = gi[off + sd];
        float il = gi[off + 256 + sd];
        float a = fmaxf(g, 1e-6f);
        prod *= a;
        wb += (1.f - g) * il / fmaxf(prod, 1e-8f);
    }
    int cidx = (b * NC + c) * SD + sd;
    ca_last[cidx] = prod;
    wb_last[cidx] = wb;
}

// writes states bf16 into cat[row][0..255], stride KCAT
__device__ void scan_pass3_body(int blk,
    const float* __restrict__ gi, const float* __restrict__ h_prev,
    __hip_bfloat16* __restrict__ cat)
{
    int idx = blk * 256 + threadIdx.x;        // 131072
    int sd = idx & 255;
    int c  = (idx >> 8) & 63;
    int b  = idx >> 14;
    size_t base = ((size_t)(b * TT + c * CHUNK)) * 512;
    size_t obase = ((size_t)(b * TT + c * CHUNK)) * KCAT + sd;
    float h = h_prev[(b * NC + c) * SD + sd];
    float prod = 1.f, wb = 0.f;
    for (int i = 0; i < CHUNK; ++i) {
        size_t off = base + (size_t)i * 512;
        float g  = gi[off + sd];
        float il = gi[off + 256 + sd];
        float a = fmaxf(g, 1e-6f);
        prod *= a;
        wb += (1.f - g) * il / fmaxf(prod, 1e-8f);
        cat[obase + (size_t)i * KCAT] = __float2bfloat16(prod * (h + wb));
    }
}

#define LST 68
__device__ void bind_p1_body(int bc,
    const float* __restrict__ vkq, const float* __restrict__ op_decay,
    float* __restrict__ o, float* __restrict__ dS,
    float* B1, float* B2, float* B3, float* l2d)
{
    const int b = bc >> 5, c = bc & 31;
    const size_t base = ((size_t)b * TT + (size_t)c * CB) * 256;
    const size_t obase = ((size_t)b * TT + (size_t)c * CB) * OD;
    const int tid = threadIdx.x;
    if (tid < 64) l2d[tid] = log2f(1.f / (1.f + expf(-op_decay[tid])));
    const int lr = tid >> 4, lc = (tid & 15) << 2;
    #pragma unroll
    for (int rr = 0; rr < 4; ++rr) {
        int t = lr + rr * 16;
        float4 qv = *(const float4*)&vkq[base + t * 256 + 128 + lc];
        float4 kv = *(const float4*)&vkq[base + t * 256 + 64 + lc];
        float q4[4] = {qv.x, qv.y, qv.z, qv.w};
        float k4[4] = {kv.x, kv.y, kv.z, kv.w};
        #pragma unroll
        for (int j = 0; j < 4; ++j) {
            B1[(lc + j) * LST + t] = q4[j];
            B2[(lc + j) * LST + t] = k4[j];
        }
    }
    __syncthreads();
    const int tx = tid & 15, ty = tid >> 4;
    {
        float a_acc[4][4] = {};
        for (int d = 0; d < 64; ++d) {
            float4 q4 = *(const float4*)&B1[d * LST + 4 * ty];
            float4 k4 = *(const float4*)&B2[d * LST + 4 * tx];
            float qr[4] = {q4.x, q4.y, q4.z, q4.w};
            float kr[4] = {k4.x, k4.y, k4.z, k4.w};
            #pragma unroll
            for (int r = 0; r < 4; ++r)
                #pragma unroll
                for (int s = 0; s < 4; ++s)
                    a_acc[r][s] = fmaf(qr[r], kr[s], a_acc[r][s]);
        }
        __syncthreads();
        #pragma unroll
        for (int s = 0; s < 4; ++s) {
            int ss = 4 * tx + s;
            float w[4];
            #pragma unroll
            for (int r = 0; r < 4; ++r)
                w[r] = (ss <= 4 * ty + r) ? a_acc[r][s] : 0.f;
            *(float4*)&B3[ss * LST + 4 * ty] = *(float4*)w;
        }
    }
    #pragma unroll
    for (int rr = 0; rr < 4; ++rr) {
        int m = lr + rr * 16;
        float4 vv = *(const float4*)&vkq[base + m * 256 + 0 + lc];
        float4 kv = *(const float4*)&vkq[base + m * 256 + 64 + lc];
        float v4[4] = {vv.x, vv.y, vv.z, vv.w};
        #pragma unroll
        for (int j = 0; j < 4; ++j)
            v4[j] *= exp2f(-(float)m * l2d[lc + j]);
        *(float4*)&B1[m * LST + lc] = *(float4*)v4;
        *(float4*)&B2[m * LST + lc] = kv;
    }
    __syncthreads();
    {
        float p[4][4] = {};
        for (int s = 0; s < 64; ++s) {
            float4 a4 = *(const float4*)&B3[s * LST + 4 * ty];
            float4 v4 = *(const float4*)&B1[s * LST + 4 * tx];
            float ar[4] = {a4.x, a4.y, a4.z, a4.w};
            float vr[4] = {v4.x, v4.y, v4.z, v4.w};
            #pragma unroll
            for (int r = 0; r < 4; ++r)
                #pragma unroll
                for (int i2 = 0; i2 < 4; ++i2)
                    p[r][i2] = fmaf(ar[r], vr[i2], p[r][i2]);
        }
        #pragma unroll
        for (int r = 0; r < 4; ++r) {
            int t = 4 * ty + r;
            float w[4];
            #pragma unroll
            for (int i2 = 0; i2 < 4; ++i2)
                w[i2] = exp2f((float)t * l2d[4 * tx + i2]) * p[r][i2];
            *(float4*)&o[obase + t * OD + 4 * tx] = *(float4*)w;
        }
    }
    {
        float sacc[4][4] = {};
        for (int m = 0; m < 64; ++m) {
            float4 v4 = *(const float4*)&B1[m * LST + 4 * ty];
            float4 k4 = *(const float4*)&B2[m * LST + 4 * tx];
            float vr[4] = {v4.x, v4.y, v4.z, v4.w};
            float kr[4] = {k4.x, k4.y, k4.z, k4.w};
            #pragma unroll
            for (int r = 0; r < 4; ++r)
                #pragma unroll
                for (int j = 0; j < 4; ++j)
                    sacc[r][j] = fmaf(vr[r], kr[j], sacc[r][j]);
        }
        float* dSb = dS + (size_t)bc * 4096;
        #pragma unroll
        for (int r = 0; r < 4; ++r) {
            int i = 4 * ty + r;
            float scale = exp2f(63.f * l2d[i]);
            float w[4];
            #pragma unroll
            for (int j2 = 0; j2 < 4; ++j2)
                w[j2] = scale * sacc[r][j2];
            *(float4*)&dSb[i * 64 + 4 * tx] = *(float4*)w;
        }
    }
}

// o_final(bf16 into cat[row][256+i]) = o_intra + dec^(l+1) * (Q @ Sstart^T)
__device__ void bind_p3_body(int bc,
    const float* __restrict__ vkq, const float* __restrict__ Sstart,
    const float* __restrict__ op_decay, const float* __restrict__ o,
    __hip_bfloat16* __restrict__ cat,
    float* B1, float* B2, float* l2d)
{
    const int b = bc >> 5, c = bc & 31;
    const size_t base = ((size_t)b * TT + (size_t)c * CB) * 256;
    const size_t obase = ((size_t)b * TT + (size_t)c * CB) * OD;
    const size_t cbase = ((size_t)b * TT + (size_t)c * CB) * KCAT + 256;
    const int tid = threadIdx.x;
    if (tid < 64) l2d[tid] = log2f(1.f / (1.f + expf(-op_decay[tid])));
    const int lr = tid >> 4, lc = (tid & 15) << 2;
    const float* Sb = Sstart + (size_t)bc * 4096;
    #pragma unroll
    for (int rr = 0; rr < 4; ++rr) {
        int t = lr + rr * 16;
        float4 qv = *(const float4*)&vkq[base + t * 256 + 128 + lc];
        float4 sv = *(const float4*)&Sb[t * 64 + lc];
        float q4[4] = {qv.x, qv.y, qv.z, qv.w};
        float s4[4] = {sv.x, sv.y, sv.z, sv.w};
        #pragma unroll
        for (int j = 0; j < 4; ++j) {
            B1[(lc + j) * LST + t] = q4[j];
            B2[(lc + j) * LST + t] = s4[j];
        }
    }
    __syncthreads();
    const int tx = tid & 15, ty = tid >> 4;
    float acc[4][4] = {};
    for (int j = 0; j < 64; ++j) {
        float4 q4 = *(const float4*)&B1[j * LST + 4 * ty];
        float4 s4 = *(const float4*)&B2[j * LST + 4 * tx];
        float qr[4] = {q4.x, q4.y, q4.z, q4.w};
        float sr[4] = {s4.x, s4.y, s4.z, s4.w};
        #pragma unroll
        for (int r = 0; r < 4; ++r)
            #pragma unroll
            for (int i2 = 0; i2 < 4; ++i2)
                acc[r][i2] = fmaf(qr[r], sr[i2], acc[r][i2]);
    }
    #pragma unroll
    for (int r = 0; r < 4; ++r) {
        int l = 4 * ty + r;
        alignas(8) __hip_bfloat16 w[4];
        #pragma unroll
        for (int i2 = 0; i2 < 4; ++i2) {
            int i = 4 * tx + i2;
            float val = o[obase + l * OD + i] + exp2f((float)(l + 1) * l2d[i]) * acc[r][i2];
            w[i2] = __float2bfloat16(val);
        }
        *(float2*)&cat[cbase + l * KCAT + 4 * tx] = *(float2*)w;
    }
}

// ---------------------------------------------------------------------------
// fused1: blocks 0-255 -> bind_p1, blocks 256-767 -> scan_pass1
// ---------------------------------------------------------------------------
__global__ __launch_bounds__(256) void fused1(
    const float* __restrict__ gi, const float* __restrict__ vkq,
    const float* __restrict__ op_decay,
    float* __restrict__ ca_last, float* __restrict__ wb_last,
    float* __restrict__ o_intra, float* __restrict__ dS)
{
    __shared__ float B1[64 * LST];
    __shared__ float B2[64 * LST];
    __shared__ float B3[64 * LST];
    __shared__ float l2d[64];
    const int bid = blockIdx.x;
    if (bid < 256) bind_p1_body(bid, vkq, op_decay, o_intra, dS, B1, B2, B3, l2d);
    else           scan_pass1_body(bid - 256, gi, ca_last, wb_last);
}

// ---------------------------------------------------------------------------
// fused2: blocks 0-127 -> bind_p2 carry scan; blocks 128-135 -> scan_pass2
// ---------------------------------------------------------------------------
__global__ __launch_bounds__(256) void fused2(
    const float* __restrict__ dS, const float* __restrict__ op_decay,
    float* __restrict__ Sstart,
    const float* __restrict__ ca_last, const float* __restrict__ wb_last,
    float* __restrict__ h_prev)
{
    const int bid = blockIdx.x;
    if (bid < 128) {
        int idx = bid * 256 + threadIdx.x;   // 32768
        int j = idx & 63, i = (idx >> 6) & 63, b = idx >> 12;
        float dec = 1.f / (1.f + expf(-op_decay[i]));
        float d64 = exp2f(64.f * log2f(dec));
        float S = 0.f;
        for (int c = 0; c < NCB; ++c) {
            size_t o = (((size_t)b * NCB + c) * 4096) + i * 64 + j;
            Sstart[o] = S;
            S = d64 * S + dS[o];
        }
    } else {
        int idx = (bid - 128) * 256 + threadIdx.x;   // 2048
        int sd = idx & 255;
        int b  = idx >> 8;
        float h = 0.f;
        for (int c = 0; c < NC; ++c) {
            int o = (b * NC + c) * SD + sd;
            h_prev[o] = h;
            h = ca_last[o] * (h + wb_last[o]);
        }
    }
}

// ---------------------------------------------------------------------------
// fused3: blocks 0-255 -> bind_p3 (writes cat cols 256-319),
//         blocks 256-767 -> scan_pass3 (writes cat cols 0-255)
// ---------------------------------------------------------------------------
__global__ __launch_bounds__(256) void fused3(
    const float* __restrict__ gi, const float* __restrict__ h_prev,
    const float* __restrict__ vkq, const float* __restrict__ Sstart,
    const float* __restrict__ op_decay, const float* __restrict__ o_intra,
    __hip_bfloat16* __restrict__ cat)
{
    __shared__ float B1[64 * LST];
    __shared__ float B2[64 * LST];
    __shared__ float l2d[64];
    const int bid = blockIdx.x;
    if (bid < 256) bind_p3_body(bid, vkq, Sstart, op_decay, o_intra, cat, B1, B2, l2d);
    else           scan_pass3_body(bid - 256, gi, h_prev, cat);
}

// ---------------------------------------------------------------------------
// In-place LayerNorm over last dim (512).
// ---------------------------------------------------------------------------
__global__ __launch_bounds__(256) void ln_kernel(
    float* __restrict__ y, const float* __restrict__ lng, const float* __restrict__ lnb)
{
    const int row = blockIdx.x;
    float* yr = y + (size_t)row * DD;
    const int tid = threadIdx.x;
    float2 v2 = *(float2*)&yr[tid * 2];
    float s = v2.x + v2.y;
    float s2 = v2.x * v2.x + v2.y * v2.y;
    #pragma unroll
    for (int off = 32; off > 0; off >>= 1) {
        s  += __shfl_down(s, off);
        s2 += __shfl_down(s2, off);
    }
    __shared__ float ps[4], ps2[4];
    int lane = tid & 63, wid = tid >> 6;
    if (lane == 0) { ps[wid] = s; ps2[wid] = s2; }
    __syncthreads();
    float tot  = ps[0] + ps[1] + ps[2] + ps[3];
    float tot2 = ps2[0] + ps2[1] + ps2[2] + ps2[3];
    float mu = tot * (1.f / 512.f);
    float var = tot2 * (1.f / 512.f) - mu * mu;
    float rstd = rsqrtf(var + 1e-5f);
    int d0 = tid * 2;
    yr[d0]     = (v2.x - mu) * rstd * lng[d0]     + lnb[d0];
    yr[d0 + 1] = (v2.y - mu) * rstd * lng[d0 + 1] + lnb[d0 + 1];
}

// ---------------------------------------------------------------------------
extern "C" void kernel_launch(void* const* d_in, const int* in_sizes, int n_in,
                              void* d_out, int out_size, void* d_ws, size_t ws_size,
                              hipStream_t stream)
{
    const float* x       = (const float*)d_in[0];
    const float* gate_W  = (const float*)d_in[1];
    const float* gate_b  = (const float*)d_in[2];
    const float* in_W    = (const float*)d_in[3];
    const float* in_b    = (const float*)d_in[4];
    const float* out_W   = (const float*)d_in[5];
    const float* out_b   = (const float*)d_in[6];
    const float* opv_W   = (const float*)d_in[7];
    const float* opv_b   = (const float*)d_in[8];
    const float* opk_W   = (const float*)d_in[9];
    const float* opk_b   = (const float*)d_in[10];
    const float* opq_W   = (const float*)d_in[11];
    const float* opq_b   = (const float*)d_in[12];
    const float* op_dec  = (const float*)d_in[13];
    const float* opout_W = (const float*)d_in[14];
    const float* opout_b = (const float*)d_in[15];
    const float* ln_g    = (const float*)d_in[16];
    const float* ln_b    = (const float*)d_in[17];
    float* y = (float*)d_out;

    char* w = (char*)d_ws;
    auto alloc = [&](size_t bytes) { char* p = w; w += (bytes + 255) & ~(size_t)255; return p; };
    float* gi        = (float*)alloc((size_t)MM * 512 * 4);
    float* vkq       = (float*)alloc((size_t)MM * 256 * 4);
    float* o_intra   = (float*)alloc((size_t)MM * 64 * 4);
    float* ca_last   = (float*)alloc((size_t)BB * NC * SD * 4);
    float* wb_last   = (float*)alloc((size_t)BB * NC * SD * 4);
    float* h_prev    = (float*)alloc((size_t)BB * NC * SD * 4);
    float* dS        = (float*)alloc((size_t)BB * NCB * 4096 * 4);
    float* Sstart    = (float*)alloc((size_t)BB * NCB * 4096 * 4);
    float* bias_cat  = (float*)alloc(768 * 4);
    float* bias_comb = (float*)alloc(512 * 4);
    __hip_bfloat16* xb    = (__hip_bfloat16*)alloc((size_t)MM * 512 * 2);
    __hip_bfloat16* cat   = (__hip_bfloat16*)alloc((size_t)MM * KCAT * 2);
    __hip_bfloat16* Wcat  = (__hip_bfloat16*)alloc((size_t)768 * 512 * 2);
    __hip_bfloat16* Wcomb = (__hip_bfloat16*)alloc((size_t)512 * KCAT * 2);

    // 1: conversions (x + all weights)
    hipLaunchKernelGGL(conv_all, dim3(4096 + 2181), dim3(256), 0, stream,
                       x, gate_W, gate_b, in_W, in_b, opv_W, opk_W, opq_W,
                       opv_b, opk_b, opq_b, out_W, out_b, opout_W, opout_b,
                       xb, Wcat, Wcomb, bias_cat, bias_comb);
    // 2: fused projection: [gi | vkq] = xb @ Wcat^T + bias  (sigmoid on cols<256)
    hipLaunchKernelGGL(gemm_bf16, dim3(6, MM / 128), dim3(256), 0, stream,
                       xb, Wcat, bias_cat, (const float*)nullptr, gi, vkq,
                       MM, 768, 512, 512, 256);
    // 3: bind_p1 || scan_pass1
    hipLaunchKernelGGL(fused1, dim3(768), dim3(256), 0, stream,
                       gi, vkq, op_dec, ca_last, wb_last, o_intra, dS);
    // 4: bind_p2 || scan_pass2 (carry scans)
    hipLaunchKernelGGL(fused2, dim3(136), dim3(256), 0, stream,
                       dS, op_dec, Sstart, ca_last, wb_last, h_prev);
    // 5: bind_p3 || scan_pass3 -> cat[M][320] bf16
    hipLaunchKernelGGL(fused3, dim3(768), dim3(256), 0, stream,
                       gi, h_prev, vkq, Sstart, op_dec, o_intra, cat);
    // 6: y = x + cat @ Wcomb^T + bias_comb
    hipLaunchKernelGGL(gemm_bf16, dim3(4, MM / 128), dim3(256), 0, stream,
                       cat, Wcomb, bias_comb, x, y, (float*)nullptr,
                       MM, 512, KCAT, 512, 0);
    // 7: LayerNorm in place
    hipLaunchKernelGGL(ln_kernel, dim3(MM), dim3(256), 0, stream, y, ln_g, ln_b);
}

// Round 5
// 92.918 us; speedup vs baseline: 4.3797x; 1.3990x over previous
//
#include <hip/hip_runtime.h>
#include <hip/hip_bf16.h>
#include <hip/hip_fp16.h>
#include <math.h>

#define BB 8
#define TT 2048
#define DD 512
#define SD 256
#define OD 64
#define CHUNK 32
#define NC 64          // TT/CHUNK
#define CB 64          // binding-scan chunk
#define NCB 32         // TT/CB
#define MM (BB*TT)     // 16384
#define KCAT 320       // states(256) | obind(64)

typedef __attribute__((ext_vector_type(8))) short bf16x8_t;
typedef __attribute__((ext_vector_type(4))) float f32x4;

// async global->LDS, 16B per lane. LDS dest must be wave-uniform base (+lane*16 by HW).
__device__ __forceinline__ void gload_lds16(const void* gsrc, void* ldst) {
    __builtin_amdgcn_global_load_lds(
        (const __attribute__((address_space(1))) unsigned int*)gsrc,
        (__attribute__((address_space(3))) unsigned int*)ldst,
        16, 0, 0);
}

// load 4 consecutive __half as float4 (two 4B loads)
__device__ __forceinline__ float4 ldh4(const __half* p) {
    __half2 a = *(const __half2*)p;
    __half2 b = *(const __half2*)(p + 2);
    float2 fa = __half22float2(a), fb = __half22float2(b);
    return make_float4(fa.x, fa.y, fb.x, fb.y);
}

// ---------------------------------------------------------------------------
// conv_all: x->bf16 (blocks < 4096) and weight prep (remaining blocks).
// Wcat[768][512] = [gate|in|v|k|q|pad]^T bf16; Wcomb[512][320] = [out_W^T|opout_W^T];
// bias_cat[768]; bias_comb[512] = out_b + opout_b.
// ---------------------------------------------------------------------------
__global__ __launch_bounds__(256) void conv_all(
    const float* __restrict__ x,
    const float* __restrict__ gate_W, const float* __restrict__ gate_b,
    const float* __restrict__ in_W,   const float* __restrict__ in_b,
    const float* __restrict__ opv_W,  const float* __restrict__ opk_W,
    const float* __restrict__ opq_W,
    const float* __restrict__ opv_b,  const float* __restrict__ opk_b,
    const float* __restrict__ opq_b,
    const float* __restrict__ out_W,  const float* __restrict__ out_b,
    const float* __restrict__ opout_W, const float* __restrict__ opout_b,
    __hip_bfloat16* __restrict__ xb,
    __hip_bfloat16* __restrict__ Wcat,  __hip_bfloat16* __restrict__ Wcomb,
    float* __restrict__ bias_cat, float* __restrict__ bias_comb)
{
    const int bid = blockIdx.x;
    if (bid < 4096) {
        size_t i = ((size_t)bid * 256 + threadIdx.x) * 8;
        float4 v0 = *(const float4*)&x[i];
        float4 v1 = *(const float4*)&x[i + 4];
        alignas(16) __hip_bfloat16 h[8] = {
            __float2bfloat16(v0.x), __float2bfloat16(v0.y),
            __float2bfloat16(v0.z), __float2bfloat16(v0.w),
            __float2bfloat16(v1.x), __float2bfloat16(v1.y),
            __float2bfloat16(v1.z), __float2bfloat16(v1.w)};
        *(float4*)&xb[i] = *(float4*)h;
        return;
    }
    int idx = (bid - 4096) * 256 + threadIdx.x;
    if (idx < 393216) {                       // Wcat [768][512]
        int n = idx >> 9, k = idx & 511;
        float v;
        if (n < 256)       v = gate_W[k * 256 + n];
        else if (n < 512)  v = in_W[k * 256 + (n - 256)];
        else if (n < 704) {
            int h = (n - 512) >> 6, j = (n - 512) & 63;
            const float* W = (h == 0) ? opv_W : (h == 1) ? opk_W : opq_W;
            v = W[k * 64 + j];
        } else v = 0.f;
        Wcat[idx] = __float2bfloat16(v);
        return;
    }
    idx -= 393216;
    if (idx < 163840) {                       // Wcomb [512][320]
        int n = idx / KCAT, k = idx % KCAT;
        float v = (k < 256) ? out_W[k * 512 + n] : opout_W[(k - 256) * 512 + n];
        Wcomb[idx] = __float2bfloat16(v);
        return;
    }
    idx -= 163840;
    if (idx < 768) {
        float v;
        if (idx < 256)      v = gate_b[idx];
        else if (idx < 512) v = in_b[idx - 256];
        else if (idx < 704) {
            int h = (idx - 512) >> 6, j = (idx - 512) & 63;
            v = (h == 0) ? opv_b[j] : (h == 1) ? opk_b[j] : opq_b[j];
        } else v = 0.f;
        bias_cat[idx] = v;
        return;
    }
    idx -= 768;
    if (idx < 512) bias_comb[idx] = out_b[idx] + opout_b[idx];
}

// ---------------------------------------------------------------------------
// Projection GEMM: [gi | vkq](fp16) = xb @ Wcat^T + bias, sigmoid cols<sigCols.
// 128x128 tile, BK=32, global_load_lds(16B), double-buffered, granule XOR
// swizzle (pre-swizzled source + swizzled read, linear LDS dest).
// XCD-aware block swizzle: gridDim.x % 8 == 0, chunked per XCD.
// ---------------------------------------------------------------------------
__global__ __launch_bounds__(256) void gemm_bf16(
    const __hip_bfloat16* __restrict__ A,
    const __hip_bfloat16* __restrict__ Bt,
    const float* __restrict__ bias,
    __half* __restrict__ out0,
    __half* __restrict__ out1,               // cols >= n0, stride N-n0
    int M, int N, int K, int n0, int sigCols)
{
    constexpr int BM = 128, BK = 32;
    __shared__ alignas(16) __hip_bfloat16 As[2][BM * BK];
    __shared__ alignas(16) __hip_bfloat16 Bs[2][BM * BK];
    const int tid = threadIdx.x;
    const int lane = tid & 63, wid = tid >> 6;
    const int wr = wid >> 1, wc = wid & 1;
    const int nbn = N >> 7;
    const int chunk = gridDim.x >> 3;
    const int b = blockIdx.x;
    const int orig = (b & 7) * chunk + (b >> 3);     // XCD-contiguous chunks
    const int bm = (orig / nbn) * BM, bn = (orig % nbn) * BM;
    const int l15 = lane & 15, hgr = lane >> 4;

    const __hip_bfloat16* srcA[2];
    const __hip_bfloat16* srcB[2];
    int ldsOff[2];
    #pragma unroll
    for (int s = 0; s < 2; ++s) {
        int g = s * 256 + tid;
        int row = g >> 2, slot = g & 3;
        int sgc = slot ^ ((row >> 1) & 3);
        srcA[s] = A  + (size_t)(bm + row) * K + sgc * 8;
        srcB[s] = Bt + (size_t)(bn + row) * K + sgc * 8;
        ldsOff[s] = (s * 256 + (tid & ~63)) * 16;
    }
    int offA[4], offB[4];
    #pragma unroll
    for (int mi = 0; mi < 4; ++mi) {
        int r = wr * 64 + mi * 16 + l15;
        offA[mi] = r * 64 + (hgr ^ ((r >> 1) & 3)) * 16;
    }
    #pragma unroll
    for (int nj = 0; nj < 4; ++nj) {
        int r = wc * 64 + nj * 16 + l15;
        offB[nj] = r * 64 + (hgr ^ ((r >> 1) & 3)) * 16;
    }

    f32x4 acc[4][4] = {};
    const int nk = K / BK;

    #pragma unroll
    for (int s = 0; s < 2; ++s) gload_lds16(srcA[s], (char*)&As[0][0] + ldsOff[s]);
    #pragma unroll
    for (int s = 0; s < 2; ++s) gload_lds16(srcB[s], (char*)&Bs[0][0] + ldsOff[s]);
    __syncthreads();

    int cur = 0;
    for (int t = 0; t < nk; ++t) {
        if (t + 1 < nk) {
            int k0 = (t + 1) * BK;
            #pragma unroll
            for (int s = 0; s < 2; ++s) gload_lds16(srcA[s] + k0, (char*)&As[cur ^ 1][0] + ldsOff[s]);
            #pragma unroll
            for (int s = 0; s < 2; ++s) gload_lds16(srcB[s] + k0, (char*)&Bs[cur ^ 1][0] + ldsOff[s]);
        }
        bf16x8_t af[4], bfr[4];
        #pragma unroll
        for (int mi = 0; mi < 4; ++mi)
            af[mi] = *(const bf16x8_t*)((const char*)&As[cur][0] + offA[mi]);
        #pragma unroll
        for (int nj = 0; nj < 4; ++nj)
            bfr[nj] = *(const bf16x8_t*)((const char*)&Bs[cur][0] + offB[nj]);
        #pragma unroll
        for (int mi = 0; mi < 4; ++mi)
            #pragma unroll
            for (int nj = 0; nj < 4; ++nj)
                acc[mi][nj] = __builtin_amdgcn_mfma_f32_16x16x32_bf16(
                    af[mi], bfr[nj], acc[mi][nj], 0, 0, 0);
        __syncthreads();
        cur ^= 1;
    }

    const int n1 = N - n0;
    #pragma unroll
    for (int mi = 0; mi < 4; ++mi) {
        #pragma unroll
        for (int nj = 0; nj < 4; ++nj) {
            int col = bn + wc * 64 + nj * 16 + l15;
            int r0 = bm + wr * 64 + mi * 16 + hgr * 4;
            float bv = bias[col];
            #pragma unroll
            for (int e = 0; e < 4; ++e) {
                int row = r0 + e;
                float val = acc[mi][nj][e] + bv;
                if (col < n0) {
                    if (col < sigCols) val = 1.f / (1.f + expf(-val));
                    out0[(size_t)row * n0 + col] = __float2half(val);
                } else {
                    out1[(size_t)row * n1 + (col - n0)] = __float2half(val);
                }
            }
        }
    }
}

// ---------------------------------------------------------------------------
// Scan / bind device bodies. gi: [M][512] fp16 (g | in). vkq: [M][256] fp16.
// ---------------------------------------------------------------------------
__device__ void scan_pass1_body(int blk,
    const __half* __restrict__ gi,
    float* __restrict__ ca_last, float* __restrict__ wb_last)
{
    int idx = blk * 256 + threadIdx.x;        // 131072
    int sd = idx & 255;
    int c  = (idx >> 8) & 63;
    int b  = idx >> 14;
    size_t base = ((size_t)(b * TT + c * CHUNK)) * 512;
    float prod = 1.f, wb = 0.f;
    for (int i = 0; i < CHUNK; ++i) {
        size_t off = base + (size_t)i * 512;
        float g  = __half2float(gi[off + sd]);
        float il = __half2float(gi[off + 256 + sd]);
        float a = fmaxf(g, 1e-6f);
        prod *= a;
        wb += (1.f - g) * il / fmaxf(prod, 1e-8f);
    }
    int cidx = (b * NC + c) * SD + sd;
    ca_last[cidx] = prod;
    wb_last[cidx] = wb;
}

// writes states bf16 into cat[row][0..255], stride KCAT
__device__ void scan_pass3_body(int blk,
    const __half* __restrict__ gi, const float* __restrict__ h_prev,
    __hip_bfloat16* __restrict__ cat)
{
    int idx = blk * 256 + threadIdx.x;        // 131072
    int sd = idx & 255;
    int c  = (idx >> 8) & 63;
    int b  = idx >> 14;
    size_t base = ((size_t)(b * TT + c * CHUNK)) * 512;
    size_t obase = ((size_t)(b * TT + c * CHUNK)) * KCAT + sd;
    float h = h_prev[(b * NC + c) * SD + sd];
    float prod = 1.f, wb = 0.f;
    for (int i = 0; i < CHUNK; ++i) {
        size_t off = base + (size_t)i * 512;
        float g  = __half2float(gi[off + sd]);
        float il = __half2float(gi[off + 256 + sd]);
        float a = fmaxf(g, 1e-6f);
        prod *= a;
        wb += (1.f - g) * il / fmaxf(prod, 1e-8f);
        cat[obase + (size_t)i * KCAT] = __float2bfloat16(prod * (h + wb));
    }
}

#define LST 68
__device__ void bind_p1_body(int bc,
    const __half* __restrict__ vkq, const float* __restrict__ op_decay,
    float* __restrict__ o, float* __restrict__ dS,
    float* B1, float* B2, float* B3, float* l2d)
{
    const int b = bc >> 5, c = bc & 31;
    const size_t base = ((size_t)b * TT + (size_t)c * CB) * 256;
    const size_t obase = ((size_t)b * TT + (size_t)c * CB) * OD;
    const int tid = threadIdx.x;
    if (tid < 64) l2d[tid] = log2f(1.f / (1.f + expf(-op_decay[tid])));
    const int lr = tid >> 4, lc = (tid & 15) << 2;
    #pragma unroll
    for (int rr = 0; rr < 4; ++rr) {
        int t = lr + rr * 16;
        float4 qv = ldh4(&vkq[base + t * 256 + 128 + lc]);
        float4 kv = ldh4(&vkq[base + t * 256 + 64 + lc]);
        float q4[4] = {qv.x, qv.y, qv.z, qv.w};
        float k4[4] = {kv.x, kv.y, kv.z, kv.w};
        #pragma unroll
        for (int j = 0; j < 4; ++j) {
            B1[(lc + j) * LST + t] = q4[j];
            B2[(lc + j) * LST + t] = k4[j];
        }
    }
    __syncthreads();
    const int tx = tid & 15, ty = tid >> 4;
    {
        float a_acc[4][4] = {};
        for (int d = 0; d < 64; ++d) {
            float4 q4 = *(const float4*)&B1[d * LST + 4 * ty];
            float4 k4 = *(const float4*)&B2[d * LST + 4 * tx];
            float qr[4] = {q4.x, q4.y, q4.z, q4.w};
            float kr[4] = {k4.x, k4.y, k4.z, k4.w};
            #pragma unroll
            for (int r = 0; r < 4; ++r)
                #pragma unroll
                for (int s = 0; s < 4; ++s)
                    a_acc[r][s] = fmaf(qr[r], kr[s], a_acc[r][s]);
        }
        __syncthreads();
        #pragma unroll
        for (int s = 0; s < 4; ++s) {
            int ss = 4 * tx + s;
            float w[4];
            #pragma unroll
            for (int r = 0; r < 4; ++r)
                w[r] = (ss <= 4 * ty + r) ? a_acc[r][s] : 0.f;
            *(float4*)&B3[ss * LST + 4 * ty] = *(float4*)w;
        }
    }
    #pragma unroll
    for (int rr = 0; rr < 4; ++rr) {
        int m = lr + rr * 16;
        float4 vv = ldh4(&vkq[base + m * 256 + 0 + lc]);
        float4 kv = ldh4(&vkq[base + m * 256 + 64 + lc]);
        float v4[4] = {vv.x, vv.y, vv.z, vv.w};
        #pragma unroll
        for (int j = 0; j < 4; ++j)
            v4[j] *= exp2f(-(float)m * l2d[lc + j]);
        *(float4*)&B1[m * LST + lc] = *(float4*)v4;
        float k4[4] = {kv.x, kv.y, kv.z, kv.w};
        *(float4*)&B2[m * LST + lc] = *(float4*)k4;
    }
    __syncthreads();
    {
        float p[4][4] = {};
        for (int s = 0; s < 64; ++s) {
            float4 a4 = *(const float4*)&B3[s * LST + 4 * ty];
            float4 v4 = *(const float4*)&B1[s * LST + 4 * tx];
            float ar[4] = {a4.x, a4.y, a4.z, a4.w};
            float vr[4] = {v4.x, v4.y, v4.z, v4.w};
            #pragma unroll
            for (int r = 0; r < 4; ++r)
                #pragma unroll
                for (int i2 = 0; i2 < 4; ++i2)
                    p[r][i2] = fmaf(ar[r], vr[i2], p[r][i2]);
        }
        #pragma unroll
        for (int r = 0; r < 4; ++r) {
            int t = 4 * ty + r;
            float w[4];
            #pragma unroll
            for (int i2 = 0; i2 < 4; ++i2)
                w[i2] = exp2f((float)t * l2d[4 * tx + i2]) * p[r][i2];
            *(float4*)&o[obase + t * OD + 4 * tx] = *(float4*)w;
        }
    }
    {
        float sacc[4][4] = {};
        for (int m = 0; m < 64; ++m) {
            float4 v4 = *(const float4*)&B1[m * LST + 4 * ty];
            float4 k4 = *(const float4*)&B2[m * LST + 4 * tx];
            float vr[4] = {v4.x, v4.y, v4.z, v4.w};
            float kr[4] = {k4.x, k4.y, k4.z, k4.w};
            #pragma unroll
            for (int r = 0; r < 4; ++r)
                #pragma unroll
                for (int j = 0; j < 4; ++j)
                    sacc[r][j] = fmaf(vr[r], kr[j], sacc[r][j]);
        }
        float* dSb = dS + (size_t)bc * 4096;
        #pragma unroll
        for (int r = 0; r < 4; ++r) {
            int i = 4 * ty + r;
            float scale = exp2f(63.f * l2d[i]);
            float w[4];
            #pragma unroll
            for (int j2 = 0; j2 < 4; ++j2)
                w[j2] = scale * sacc[r][j2];
            *(float4*)&dSb[i * 64 + 4 * tx] = *(float4*)w;
        }
    }
}

// o_final(bf16 into cat[row][256+i]) = o_intra + dec^(l+1) * (Q @ Sstart^T)
__device__ void bind_p3_body(int bc,
    const __half* __restrict__ vkq, const float* __restrict__ Sstart,
    const float* __restrict__ op_decay, const float* __restrict__ o,
    __hip_bfloat16* __restrict__ cat,
    float* B1, float* B2, float* l2d)
{
    const int b = bc >> 5, c = bc & 31;
    const size_t base = ((size_t)b * TT + (size_t)c * CB) * 256;
    const size_t obase = ((size_t)b * TT + (size_t)c * CB) * OD;
    const size_t cbase = ((size_t)b * TT + (size_t)c * CB) * KCAT + 256;
    const int tid = threadIdx.x;
    if (tid < 64) l2d[tid] = log2f(1.f / (1.f + expf(-op_decay[tid])));
    const int lr = tid >> 4, lc = (tid & 15) << 2;
    const float* Sb = Sstart + (size_t)bc * 4096;
    #pragma unroll
    for (int rr = 0; rr < 4; ++rr) {
        int t = lr + rr * 16;
        float4 qv = ldh4(&vkq[base + t * 256 + 128 + lc]);
        float4 sv = *(const float4*)&Sb[t * 64 + lc];
        float q4[4] = {qv.x, qv.y, qv.z, qv.w};
        float s4[4] = {sv.x, sv.y, sv.z, sv.w};
        #pragma unroll
        for (int j = 0; j < 4; ++j) {
            B1[(lc + j) * LST + t] = q4[j];
            B2[(lc + j) * LST + t] = s4[j];
        }
    }
    __syncthreads();
    const int tx = tid & 15, ty = tid >> 4;
    float acc[4][4] = {};
    for (int j = 0; j < 64; ++j) {
        float4 q4 = *(const float4*)&B1[j * LST + 4 * ty];
        float4 s4 = *(const float4*)&B2[j * LST + 4 * tx];
        float qr[4] = {q4.x, q4.y, q4.z, q4.w};
        float sr[4] = {s4.x, s4.y, s4.z, s4.w};
        #pragma unroll
        for (int r = 0; r < 4; ++r)
            #pragma unroll
            for (int i2 = 0; i2 < 4; ++i2)
                acc[r][i2] = fmaf(qr[r], sr[i2], acc[r][i2]);
    }
    #pragma unroll
    for (int r = 0; r < 4; ++r) {
        int l = 4 * ty + r;
        alignas(8) __hip_bfloat16 w[4];
        #pragma unroll
        for (int i2 = 0; i2 < 4; ++i2) {
            int i = 4 * tx + i2;
            float val = o[obase + l * OD + i] + exp2f((float)(l + 1) * l2d[i]) * acc[r][i2];
            w[i2] = __float2bfloat16(val);
        }
        *(float2*)&cat[cbase + l * KCAT + 4 * tx] = *(float2*)w;
    }
}

// fused1: blocks 0-255 -> bind_p1, blocks 256-767 -> scan_pass1
__global__ __launch_bounds__(256) void fused1(
    const __half* __restrict__ gi, const __half* __restrict__ vkq,
    const float* __restrict__ op_decay,
    float* __restrict__ ca_last, float* __restrict__ wb_last,
    float* __restrict__ o_intra, float* __restrict__ dS)
{
    __shared__ float B1[64 * LST];
    __shared__ float B2[64 * LST];
    __shared__ float B3[64 * LST];
    __shared__ float l2d[64];
    const int bid = blockIdx.x;
    if (bid < 256) bind_p1_body(bid, vkq, op_decay, o_intra, dS, B1, B2, B3, l2d);
    else           scan_pass1_body(bid - 256, gi, ca_last, wb_last);
}

// fused2: blocks 0-127 -> bind_p2 carry scan; blocks 128-135 -> scan_pass2
__global__ __launch_bounds__(256) void fused2(
    const float* __restrict__ dS, const float* __restrict__ op_decay,
    float* __restrict__ Sstart,
    const float* __restrict__ ca_last, const float* __restrict__ wb_last,
    float* __restrict__ h_prev)
{
    const int bid = blockIdx.x;
    if (bid < 128) {
        int idx = bid * 256 + threadIdx.x;   // 32768
        int j = idx & 63, i = (idx >> 6) & 63, b = idx >> 12;
        float dec = 1.f / (1.f + expf(-op_decay[i]));
        float d64 = exp2f(64.f * log2f(dec));
        float S = 0.f;
        for (int c = 0; c < NCB; ++c) {
            size_t o = (((size_t)b * NCB + c) * 4096) + i * 64 + j;
            Sstart[o] = S;
            S = d64 * S + dS[o];
        }
    } else {
        int idx = (bid - 128) * 256 + threadIdx.x;   // 2048
        int sd = idx & 255;
        int b  = idx >> 8;
        float h = 0.f;
        for (int c = 0; c < NC; ++c) {
            int o = (b * NC + c) * SD + sd;
            h_prev[o] = h;
            h = ca_last[o] * (h + wb_last[o]);
        }
    }
}

// fused3: blocks 0-255 -> bind_p3 (cat cols 256-319), 256-767 -> scan_pass3 (cols 0-255)
__global__ __launch_bounds__(256) void fused3(
    const __half* __restrict__ gi, const float* __restrict__ h_prev,
    const __half* __restrict__ vkq, const float* __restrict__ Sstart,
    const float* __restrict__ op_decay, const float* __restrict__ o_intra,
    __hip_bfloat16* __restrict__ cat)
{
    __shared__ float B1[64 * LST];
    __shared__ float B2[64 * LST];
    __shared__ float l2d[64];
    const int bid = blockIdx.x;
    if (bid < 256) bind_p3_body(bid, vkq, Sstart, op_decay, o_intra, cat, B1, B2, l2d);
    else           scan_pass3_body(bid - 256, gi, h_prev, cat);
}

// ---------------------------------------------------------------------------
// Fused output GEMM + residual + LayerNorm.
// y = LN(x + cat @ Wcomb^T + bias_comb) * ln_g + ln_b
// BM=32, BN=512 (full rows per block), BK=32, 512 threads (8 waves, 1x8),
// wave tile 32x64, double-buffered global_load_lds with granule swizzle.
// ---------------------------------------------------------------------------
__global__ __launch_bounds__(512) void outgemm_ln(
    const __hip_bfloat16* __restrict__ cat,    // [M][320]
    const __hip_bfloat16* __restrict__ Wcomb,  // [512][320]
    const float* __restrict__ bias_comb,
    const float* __restrict__ x,               // [M][512]
    const float* __restrict__ lng, const float* __restrict__ lnb,
    float* __restrict__ y)
{
    constexpr int BM = 32, BK = 32, NN = 512;
    __shared__ alignas(16) __hip_bfloat16 As[2][BM * BK];     // 2x2KB
    __shared__ alignas(16) __hip_bfloat16 Bs[2][NN * BK];     // 2x32KB
    __shared__ float psum[8][BM], psum2[8][BM], mvmu[BM], mvrs[BM];
    const int tid = threadIdx.x;
    const int lane = tid & 63, wid = tid >> 6;
    const int l15 = lane & 15, hgr = lane >> 4;
    const int bm = blockIdx.x * BM;

    // A staging (waves 0-1 only): granule gg = wid*64+lane, row=gg>>2, slot swz
    const __hip_bfloat16* srcA = cat;
    int ldsOffA = 0;
    {
        int gg = (wid & 1) * 64 + lane;
        int row = gg >> 2, sl = (gg & 3) ^ ((row >> 1) & 3);
        srcA = cat + (size_t)(bm + row) * KCAT + sl * 8;
        ldsOffA = (wid & 1) * 1024;
    }
    // B staging: 4 calls per wave
    const __hip_bfloat16* srcB[4];
    int ldsOffB[4];
    #pragma unroll
    for (int c = 0; c < 4; ++c) {
        int gg = (wid * 4 + c) * 64 + lane;
        int row = gg >> 2, sl = (gg & 3) ^ ((row >> 1) & 3);
        srcB[c] = Wcomb + (size_t)row * KCAT + sl * 8;
        ldsOffB[c] = (wid * 4 + c) * 1024;
    }
    int offA[2], offB[4];
    #pragma unroll
    for (int mi = 0; mi < 2; ++mi) {
        int r = mi * 16 + l15;
        offA[mi] = r * 64 + (hgr ^ ((r >> 1) & 3)) * 16;
    }
    #pragma unroll
    for (int nj = 0; nj < 4; ++nj) {
        int n = wid * 64 + nj * 16 + l15;
        offB[nj] = n * 64 + (hgr ^ ((n >> 1) & 3)) * 16;
    }

    f32x4 acc[2][4] = {};
    constexpr int nk = KCAT / BK;   // 10

    if (wid < 2) gload_lds16(srcA, (char*)&As[0][0] + ldsOffA);
    #pragma unroll
    for (int c = 0; c < 4; ++c) gload_lds16(srcB[c], (char*)&Bs[0][0] + ldsOffB[c]);
    __syncthreads();

    int cur = 0;
    for (int t = 0; t < nk; ++t) {
        if (t + 1 < nk) {
            int k0 = (t + 1) * BK;
            if (wid < 2) gload_lds16(srcA + k0, (char*)&As[cur ^ 1][0] + ldsOffA);
            #pragma unroll
            for (int c = 0; c < 4; ++c)
                gload_lds16(srcB[c] + k0, (char*)&Bs[cur ^ 1][0] + ldsOffB[c]);
        }
        bf16x8_t af[2], bfr[4];
        #pragma unroll
        for (int mi = 0; mi < 2; ++mi)
            af[mi] = *(const bf16x8_t*)((const char*)&As[cur][0] + offA[mi]);
        #pragma unroll
        for (int nj = 0; nj < 4; ++nj)
            bfr[nj] = *(const bf16x8_t*)((const char*)&Bs[cur][0] + offB[nj]);
        #pragma unroll
        for (int mi = 0; mi < 2; ++mi)
            #pragma unroll
            for (int nj = 0; nj < 4; ++nj)
                acc[mi][nj] = __builtin_amdgcn_mfma_f32_16x16x32_bf16(
                    af[mi], bfr[nj], acc[mi][nj], 0, 0, 0);
        __syncthreads();
        cur ^= 1;
    }

    // epilogue: + bias + x residual
    #pragma unroll
    for (int nj = 0; nj < 4; ++nj) {
        int col = wid * 64 + nj * 16 + l15;
        float bc_ = bias_comb[col];
        #pragma unroll
        for (int mi = 0; mi < 2; ++mi) {
            int r0 = bm + mi * 16 + hgr * 4;
            #pragma unroll
            for (int e = 0; e < 4; ++e)
                acc[mi][nj][e] += bc_ + x[(size_t)(r0 + e) * DD + col];
        }
    }
    // per-row sums over this wave's 64 cols
    float s[8], s2[8];
    #pragma unroll
    for (int mi = 0; mi < 2; ++mi)
        #pragma unroll
        for (int e = 0; e < 4; ++e) {
            float a = 0.f, b2 = 0.f;
            #pragma unroll
            for (int nj = 0; nj < 4; ++nj) {
                float v = acc[mi][nj][e];
                a += v; b2 += v * v;
            }
            s[mi * 4 + e] = a; s2[mi * 4 + e] = b2;
        }
    #pragma unroll
    for (int off = 1; off <= 8; off <<= 1)
        #pragma unroll
        for (int i = 0; i < 8; ++i) {
            s[i]  += __shfl_xor(s[i], off);
            s2[i] += __shfl_xor(s2[i], off);
        }
    if (l15 == 0) {
        #pragma unroll
        for (int mi = 0; mi < 2; ++mi)
            #pragma unroll
            for (int e = 0; e < 4; ++e) {
                int lr = mi * 16 + hgr * 4 + e;
                psum[wid][lr]  = s[mi * 4 + e];
                psum2[wid][lr] = s2[mi * 4 + e];
            }
    }
    __syncthreads();
    if (tid < BM) {
        float tot = 0.f, tot2 = 0.f;
        #pragma unroll
        for (int w2 = 0; w2 < 8; ++w2) { tot += psum[w2][tid]; tot2 += psum2[w2][tid]; }
        float mu = tot * (1.f / 512.f);
        float var = tot2 * (1.f / 512.f) - mu * mu;
        mvmu[tid] = mu;
        mvrs[tid] = rsqrtf(var + 1e-5f);
    }
    __syncthreads();
    #pragma unroll
    for (int nj = 0; nj < 4; ++nj) {
        int col = wid * 64 + nj * 16 + l15;
        float g = lng[col], bb = lnb[col];
        #pragma unroll
        for (int mi = 0; mi < 2; ++mi) {
            #pragma unroll
            for (int e = 0; e < 4; ++e) {
                int lr = mi * 16 + hgr * 4 + e;
                y[(size_t)(bm + lr) * DD + col] =
                    (acc[mi][nj][e] - mvmu[lr]) * mvrs[lr] * g + bb;
            }
        }
    }
}

// ---------------------------------------------------------------------------
extern "C" void kernel_launch(void* const* d_in, const int* in_sizes, int n_in,
                              void* d_out, int out_size, void* d_ws, size_t ws_size,
                              hipStream_t stream)
{
    const float* x       = (const float*)d_in[0];
    const float* gate_W  = (const float*)d_in[1];
    const float* gate_b  = (const float*)d_in[2];
    const float* in_W    = (const float*)d_in[3];
    const float* in_b    = (const float*)d_in[4];
    const float* out_W   = (const float*)d_in[5];
    const float* out_b   = (const float*)d_in[6];
    const float* opv_W   = (const float*)d_in[7];
    const float* opv_b   = (const float*)d_in[8];
    const float* opk_W   = (const float*)d_in[9];
    const float* opk_b   = (const float*)d_in[10];
    const float* opq_W   = (const float*)d_in[11];
    const float* opq_b   = (const float*)d_in[12];
    const float* op_dec  = (const float*)d_in[13];
    const float* opout_W = (const float*)d_in[14];
    const float* opout_b = (const float*)d_in[15];
    const float* ln_g    = (const float*)d_in[16];
    const float* ln_b    = (const float*)d_in[17];
    float* y = (float*)d_out;

    char* w = (char*)d_ws;
    auto alloc = [&](size_t bytes) { char* p = w; w += (bytes + 255) & ~(size_t)255; return p; };
    __half* gi       = (__half*)alloc((size_t)MM * 512 * 2);
    __half* vkq      = (__half*)alloc((size_t)MM * 256 * 2);
    float* o_intra   = (float*)alloc((size_t)MM * 64 * 4);
    float* ca_last   = (float*)alloc((size_t)BB * NC * SD * 4);
    float* wb_last   = (float*)alloc((size_t)BB * NC * SD * 4);
    float* h_prev    = (float*)alloc((size_t)BB * NC * SD * 4);
    float* dS        = (float*)alloc((size_t)BB * NCB * 4096 * 4);
    float* Sstart    = (float*)alloc((size_t)BB * NCB * 4096 * 4);
    float* bias_cat  = (float*)alloc(768 * 4);
    float* bias_comb = (float*)alloc(512 * 4);
    __hip_bfloat16* xb    = (__hip_bfloat16*)alloc((size_t)MM * 512 * 2);
    __hip_bfloat16* cat   = (__hip_bfloat16*)alloc((size_t)MM * KCAT * 2);
    __hip_bfloat16* Wcat  = (__hip_bfloat16*)alloc((size_t)768 * 512 * 2);
    __hip_bfloat16* Wcomb = (__hip_bfloat16*)alloc((size_t)512 * KCAT * 2);

    // 1: conversions
    hipLaunchKernelGGL(conv_all, dim3(4096 + 2181), dim3(256), 0, stream,
                       x, gate_W, gate_b, in_W, in_b, opv_W, opk_W, opq_W,
                       opv_b, opk_b, opq_b, out_W, out_b, opout_W, opout_b,
                       xb, Wcat, Wcomb, bias_cat, bias_comb);
    // 2: fused projection (fp16 outputs, XCD-swizzled grid 768 = 8*96)
    hipLaunchKernelGGL(gemm_bf16, dim3(6 * (MM / 128)), dim3(256), 0, stream,
                       xb, Wcat, bias_cat, gi, vkq,
                       MM, 768, 512, 512, 256);
    // 3: bind_p1 || scan_pass1
    hipLaunchKernelGGL(fused1, dim3(768), dim3(256), 0, stream,
                       gi, vkq, op_dec, ca_last, wb_last, o_intra, dS);
    // 4: carry scans
    hipLaunchKernelGGL(fused2, dim3(136), dim3(256), 0, stream,
                       dS, op_dec, Sstart, ca_last, wb_last, h_prev);
    // 5: bind_p3 || scan_pass3 -> cat[M][320] bf16
    hipLaunchKernelGGL(fused3, dim3(768), dim3(256), 0, stream,
                       gi, h_prev, vkq, Sstart, op_dec, o_intra, cat);
    // 6: y = LN(x + cat @ Wcomb^T + bias_comb)
    hipLaunchKernelGGL(outgemm_ln, dim3(MM / 32), dim3(512), 0, stream,
                       cat, Wcomb, bias_comb, x, ln_g, ln_b, y);
}

// Round 6
// 89.641 us; speedup vs baseline: 4.5398x; 1.0366x over previous
//
#include <hip/hip_runtime.h>
#include <hip/hip_bf16.h>
#include <hip/hip_fp16.h>
#include <math.h>

#define BB 8
#define TT 2048
#define DD 512
#define SD 256
#define OD 64
#define CHUNK 32
#define NC 64          // TT/CHUNK
#define CB 64          // binding-scan chunk
#define NCB 32         // TT/CB
#define MM (BB*TT)     // 16384
#define KCAT 320       // states(256) | obind(64)

typedef __attribute__((ext_vector_type(8))) short bf16x8_t;
typedef __attribute__((ext_vector_type(4))) float f32x4;

// async global->LDS, 16B per lane. LDS dest must be wave-uniform base (+lane*16 by HW).
__device__ __forceinline__ void gload_lds16(const void* gsrc, void* ldst) {
    __builtin_amdgcn_global_load_lds(
        (const __attribute__((address_space(1))) unsigned int*)gsrc,
        (__attribute__((address_space(3))) unsigned int*)ldst,
        16, 0, 0);
}

// load 4 consecutive __half as float4 (two 4B loads)
__device__ __forceinline__ float4 ldh4(const __half* p) {
    __half2 a = *(const __half2*)p;
    __half2 b = *(const __half2*)(p + 2);
    float2 fa = __half22float2(a), fb = __half22float2(b);
    return make_float4(fa.x, fa.y, fb.x, fb.y);
}

// ---------------------------------------------------------------------------
// conv_w: weight prep only (x is consumed fp32 directly by the proj GEMM now).
// Wcat[768][512] = [gate|in|v|k|q|pad]^T bf16; Wcomb[512][320] = [out_W^T|opout_W^T];
// bias_cat[768]; bias_comb[512] = out_b + opout_b.
// ---------------------------------------------------------------------------
__global__ __launch_bounds__(256) void conv_w(
    const float* __restrict__ gate_W, const float* __restrict__ gate_b,
    const float* __restrict__ in_W,   const float* __restrict__ in_b,
    const float* __restrict__ opv_W,  const float* __restrict__ opk_W,
    const float* __restrict__ opq_W,
    const float* __restrict__ opv_b,  const float* __restrict__ opk_b,
    const float* __restrict__ opq_b,
    const float* __restrict__ out_W,  const float* __restrict__ out_b,
    const float* __restrict__ opout_W, const float* __restrict__ opout_b,
    __hip_bfloat16* __restrict__ Wcat,  __hip_bfloat16* __restrict__ Wcomb,
    float* __restrict__ bias_cat, float* __restrict__ bias_comb)
{
    int idx = blockIdx.x * 256 + threadIdx.x;
    if (idx < 393216) {                       // Wcat [768][512]
        int n = idx >> 9, k = idx & 511;
        float v;
        if (n < 256)       v = gate_W[k * 256 + n];
        else if (n < 512)  v = in_W[k * 256 + (n - 256)];
        else if (n < 704) {
            int h = (n - 512) >> 6, j = (n - 512) & 63;
            const float* W = (h == 0) ? opv_W : (h == 1) ? opk_W : opq_W;
            v = W[k * 64 + j];
        } else v = 0.f;
        Wcat[idx] = __float2bfloat16(v);
        return;
    }
    idx -= 393216;
    if (idx < 163840) {                       // Wcomb [512][320]
        int n = idx / KCAT, k = idx % KCAT;
        float v = (k < 256) ? out_W[k * 512 + n] : opout_W[(k - 256) * 512 + n];
        Wcomb[idx] = __float2bfloat16(v);
        return;
    }
    idx -= 163840;
    if (idx < 768) {
        float v;
        if (idx < 256)      v = gate_b[idx];
        else if (idx < 512) v = in_b[idx - 256];
        else if (idx < 704) {
            int h = (idx - 512) >> 6, j = (idx - 512) & 63;
            v = (h == 0) ? opv_b[j] : (h == 1) ? opk_b[j] : opq_b[j];
        } else v = 0.f;
        bias_cat[idx] = v;
        return;
    }
    idx -= 768;
    if (idx < 512) bias_comb[idx] = out_b[idx] + opout_b[idx];
}

// ---------------------------------------------------------------------------
// Projection GEMM: [gi | vkq](fp16) = x(fp32) @ Wcat^T + bias, sigmoid<sigCols.
// A: fp32 reg-staged (issue-early loads, in-reg bf16 cvt, swizzled ds_write).
// B: global_load_lds(16B) with pre-swizzled source, linear LDS dest.
// 128x128 tile, BK=32, double-buffered, 4 waves, 16 MFMA/k-step.
// XCD-aware block swizzle: gridDim.x % 8 == 0, chunked per XCD.
// ---------------------------------------------------------------------------
__global__ __launch_bounds__(256) void gemm_proj(
    const float* __restrict__ A,             // x [M][K] fp32
    const __hip_bfloat16* __restrict__ Bt,   // Wcat [N][K]
    const float* __restrict__ bias,
    __half* __restrict__ out0,
    __half* __restrict__ out1,               // cols >= n0, stride N-n0
    int M, int N, int K, int n0, int sigCols)
{
    constexpr int BM = 128, BK = 32;
    __shared__ alignas(16) __hip_bfloat16 As[2][BM * BK];
    __shared__ alignas(16) __hip_bfloat16 Bs[2][BM * BK];
    const int tid = threadIdx.x;
    const int lane = tid & 63, wid = tid >> 6;
    const int wr = wid >> 1, wc = wid & 1;
    const int nbn = N >> 7;
    const int chunk = gridDim.x >> 3;
    const int b = blockIdx.x;
    const int orig = (b & 7) * chunk + (b >> 3);     // XCD-contiguous chunks
    const int bm = (orig / nbn) * BM, bn = (orig % nbn) * BM;
    const int l15 = lane & 15, hgr = lane >> 4;

    // A staging (reg): granule g = s*256+tid; row=g>>2, slot=g&3 (8 k-elems)
    const float* srcA[2];
    int wOffA[2];                              // swizzled LDS byte offsets
    const __hip_bfloat16* srcB[2];
    int ldsOffB[2];
    #pragma unroll
    for (int s = 0; s < 2; ++s) {
        int g = s * 256 + tid;
        int row = g >> 2, slot = g & 3;
        int sw = slot ^ ((row >> 1) & 3);
        srcA[s] = A + (size_t)(bm + row) * K + slot * 8;
        wOffA[s] = row * 64 + sw * 16;
        srcB[s] = Bt + (size_t)(bn + row) * K + sw * 8;   // pre-swizzled source
        ldsOffB[s] = (s * 256 + (tid & ~63)) * 16;        // linear, wave-uniform
    }
    int offA[4], offB[4];
    #pragma unroll
    for (int mi = 0; mi < 4; ++mi) {
        int r = wr * 64 + mi * 16 + l15;
        offA[mi] = r * 64 + (hgr ^ ((r >> 1) & 3)) * 16;
    }
    #pragma unroll
    for (int nj = 0; nj < 4; ++nj) {
        int r = wc * 64 + nj * 16 + l15;
        offB[nj] = r * 64 + (hgr ^ ((r >> 1) & 3)) * 16;
    }

    f32x4 acc[4][4] = {};
    const int nk = K / BK;
    float4 a4[2][2];

    // prologue: stage k-step 0
    #pragma unroll
    for (int s = 0; s < 2; ++s) {
        a4[s][0] = *(const float4*)(srcA[s]);
        a4[s][1] = *(const float4*)(srcA[s] + 4);
    }
    #pragma unroll
    for (int s = 0; s < 2; ++s) gload_lds16(srcB[s], (char*)&Bs[0][0] + ldsOffB[s]);
    #pragma unroll
    for (int s = 0; s < 2; ++s) {
        alignas(16) __hip_bfloat16 h[8] = {
            __float2bfloat16(a4[s][0].x), __float2bfloat16(a4[s][0].y),
            __float2bfloat16(a4[s][0].z), __float2bfloat16(a4[s][0].w),
            __float2bfloat16(a4[s][1].x), __float2bfloat16(a4[s][1].y),
            __float2bfloat16(a4[s][1].z), __float2bfloat16(a4[s][1].w)};
        *(float4*)((char*)&As[0][0] + wOffA[s]) = *(float4*)h;
    }
    __syncthreads();

    int cur = 0;
    for (int t = 0; t < nk; ++t) {
        const bool more = (t + 1 < nk);
        if (more) {
            int k0 = (t + 1) * BK;
            #pragma unroll
            for (int s = 0; s < 2; ++s) {                  // issue-early A loads
                a4[s][0] = *(const float4*)(srcA[s] + k0);
                a4[s][1] = *(const float4*)(srcA[s] + k0 + 4);
            }
            #pragma unroll
            for (int s = 0; s < 2; ++s)
                gload_lds16(srcB[s] + k0, (char*)&Bs[cur ^ 1][0] + ldsOffB[s]);
        }
        bf16x8_t af[4], bfr[4];
        #pragma unroll
        for (int mi = 0; mi < 4; ++mi)
            af[mi] = *(const bf16x8_t*)((const char*)&As[cur][0] + offA[mi]);
        #pragma unroll
        for (int nj = 0; nj < 4; ++nj)
            bfr[nj] = *(const bf16x8_t*)((const char*)&Bs[cur][0] + offB[nj]);
        #pragma unroll
        for (int mi = 0; mi < 4; ++mi)
            #pragma unroll
            for (int nj = 0; nj < 4; ++nj)
                acc[mi][nj] = __builtin_amdgcn_mfma_f32_16x16x32_bf16(
                    af[mi], bfr[nj], acc[mi][nj], 0, 0, 0);
        if (more) {                                        // write-late A stage
            #pragma unroll
            for (int s = 0; s < 2; ++s) {
                alignas(16) __hip_bfloat16 h[8] = {
                    __float2bfloat16(a4[s][0].x), __float2bfloat16(a4[s][0].y),
                    __float2bfloat16(a4[s][0].z), __float2bfloat16(a4[s][0].w),
                    __float2bfloat16(a4[s][1].x), __float2bfloat16(a4[s][1].y),
                    __float2bfloat16(a4[s][1].z), __float2bfloat16(a4[s][1].w)};
                *(float4*)((char*)&As[cur ^ 1][0] + wOffA[s]) = *(float4*)h;
            }
        }
        __syncthreads();
        cur ^= 1;
    }

    const int n1 = N - n0;
    #pragma unroll
    for (int mi = 0; mi < 4; ++mi) {
        #pragma unroll
        for (int nj = 0; nj < 4; ++nj) {
            int col = bn + wc * 64 + nj * 16 + l15;
            int r0 = bm + wr * 64 + mi * 16 + hgr * 4;
            float bv = bias[col];
            #pragma unroll
            for (int e = 0; e < 4; ++e) {
                int row = r0 + e;
                float val = acc[mi][nj][e] + bv;
                if (col < n0) {
                    if (col < sigCols) val = 1.f / (1.f + expf(-val));
                    out0[(size_t)row * n0 + col] = __float2half(val);
                } else {
                    out1[(size_t)row * n1 + (col - n0)] = __float2half(val);
                }
            }
        }
    }
}

// ---------------------------------------------------------------------------
// Scan / bind device bodies. gi: [M][512] fp16 (g | in). vkq: [M][256] fp16.
// ---------------------------------------------------------------------------
__device__ void scan_pass1_body(int blk,
    const __half* __restrict__ gi,
    float* __restrict__ ca_last, float* __restrict__ wb_last)
{
    int idx = blk * 256 + threadIdx.x;        // 131072
    int sd = idx & 255;
    int c  = (idx >> 8) & 63;
    int b  = idx >> 14;
    size_t base = ((size_t)(b * TT + c * CHUNK)) * 512;
    float prod = 1.f, wb = 0.f;
    for (int i = 0; i < CHUNK; ++i) {
        size_t off = base + (size_t)i * 512;
        float g  = __half2float(gi[off + sd]);
        float il = __half2float(gi[off + 256 + sd]);
        float a = fmaxf(g, 1e-6f);
        prod *= a;
        wb += (1.f - g) * il / fmaxf(prod, 1e-8f);
    }
    int cidx = (b * NC + c) * SD + sd;
    ca_last[cidx] = prod;
    wb_last[cidx] = wb;
}

// writes states bf16 into cat[row][0..255], stride KCAT
__device__ void scan_pass3_body(int blk,
    const __half* __restrict__ gi, const float* __restrict__ h_prev,
    __hip_bfloat16* __restrict__ cat)
{
    int idx = blk * 256 + threadIdx.x;        // 131072
    int sd = idx & 255;
    int c  = (idx >> 8) & 63;
    int b  = idx >> 14;
    size_t base = ((size_t)(b * TT + c * CHUNK)) * 512;
    size_t obase = ((size_t)(b * TT + c * CHUNK)) * KCAT + sd;
    float h = h_prev[(b * NC + c) * SD + sd];
    float prod = 1.f, wb = 0.f;
    for (int i = 0; i < CHUNK; ++i) {
        size_t off = base + (size_t)i * 512;
        float g  = __half2float(gi[off + sd]);
        float il = __half2float(gi[off + 256 + sd]);
        float a = fmaxf(g, 1e-6f);
        prod *= a;
        wb += (1.f - g) * il / fmaxf(prod, 1e-8f);
        cat[obase + (size_t)i * KCAT] = __float2bfloat16(prod * (h + wb));
    }
}

#define LST 68
__device__ void bind_p1_body(int bc,
    const __half* __restrict__ vkq, const float* __restrict__ op_decay,
    float* __restrict__ o, float* __restrict__ dS,
    float* B1, float* B2, float* B3, float* l2d)
{
    const int b = bc >> 5, c = bc & 31;
    const size_t base = ((size_t)b * TT + (size_t)c * CB) * 256;
    const size_t obase = ((size_t)b * TT + (size_t)c * CB) * OD;
    const int tid = threadIdx.x;
    if (tid < 64) l2d[tid] = log2f(1.f / (1.f + expf(-op_decay[tid])));
    const int lr = tid >> 4, lc = (tid & 15) << 2;
    #pragma unroll
    for (int rr = 0; rr < 4; ++rr) {
        int t = lr + rr * 16;
        float4 qv = ldh4(&vkq[base + t * 256 + 128 + lc]);
        float4 kv = ldh4(&vkq[base + t * 256 + 64 + lc]);
        float q4[4] = {qv.x, qv.y, qv.z, qv.w};
        float k4[4] = {kv.x, kv.y, kv.z, kv.w};
        #pragma unroll
        for (int j = 0; j < 4; ++j) {
            B1[(lc + j) * LST + t] = q4[j];
            B2[(lc + j) * LST + t] = k4[j];
        }
    }
    __syncthreads();
    const int tx = tid & 15, ty = tid >> 4;
    {
        float a_acc[4][4] = {};
        for (int d = 0; d < 64; ++d) {
            float4 q4 = *(const float4*)&B1[d * LST + 4 * ty];
            float4 k4 = *(const float4*)&B2[d * LST + 4 * tx];
            float qr[4] = {q4.x, q4.y, q4.z, q4.w};
            float kr[4] = {k4.x, k4.y, k4.z, k4.w};
            #pragma unroll
            for (int r = 0; r < 4; ++r)
                #pragma unroll
                for (int s = 0; s < 4; ++s)
                    a_acc[r][s] = fmaf(qr[r], kr[s], a_acc[r][s]);
        }
        __syncthreads();
        #pragma unroll
        for (int s = 0; s < 4; ++s) {
            int ss = 4 * tx + s;
            float w[4];
            #pragma unroll
            for (int r = 0; r < 4; ++r)
                w[r] = (ss <= 4 * ty + r) ? a_acc[r][s] : 0.f;
            *(float4*)&B3[ss * LST + 4 * ty] = *(float4*)w;
        }
    }
    #pragma unroll
    for (int rr = 0; rr < 4; ++rr) {
        int m = lr + rr * 16;
        float4 vv = ldh4(&vkq[base + m * 256 + 0 + lc]);
        float4 kv = ldh4(&vkq[base + m * 256 + 64 + lc]);
        float v4[4] = {vv.x, vv.y, vv.z, vv.w};
        #pragma unroll
        for (int j = 0; j < 4; ++j)
            v4[j] *= exp2f(-(float)m * l2d[lc + j]);
        *(float4*)&B1[m * LST + lc] = *(float4*)v4;
        float k4[4] = {kv.x, kv.y, kv.z, kv.w};
        *(float4*)&B2[m * LST + lc] = *(float4*)k4;
    }
    __syncthreads();
    {
        float p[4][4] = {};
        for (int s = 0; s < 64; ++s) {
            float4 a4 = *(const float4*)&B3[s * LST + 4 * ty];
            float4 v4 = *(const float4*)&B1[s * LST + 4 * tx];
            float ar[4] = {a4.x, a4.y, a4.z, a4.w};
            float vr[4] = {v4.x, v4.y, v4.z, v4.w};
            #pragma unroll
            for (int r = 0; r < 4; ++r)
                #pragma unroll
                for (int i2 = 0; i2 < 4; ++i2)
                    p[r][i2] = fmaf(ar[r], vr[i2], p[r][i2]);
        }
        #pragma unroll
        for (int r = 0; r < 4; ++r) {
            int t = 4 * ty + r;
            float w[4];
            #pragma unroll
            for (int i2 = 0; i2 < 4; ++i2)
                w[i2] = exp2f((float)t * l2d[4 * tx + i2]) * p[r][i2];
            *(float4*)&o[obase + t * OD + 4 * tx] = *(float4*)w;
        }
    }
    {
        float sacc[4][4] = {};
        for (int m = 0; m < 64; ++m) {
            float4 v4 = *(const float4*)&B1[m * LST + 4 * ty];
            float4 k4 = *(const float4*)&B2[m * LST + 4 * tx];
            float vr[4] = {v4.x, v4.y, v4.z, v4.w};
            float kr[4] = {k4.x, k4.y, k4.z, k4.w};
            #pragma unroll
            for (int r = 0; r < 4; ++r)
                #pragma unroll
                for (int j = 0; j < 4; ++j)
                    sacc[r][j] = fmaf(vr[r], kr[j], sacc[r][j]);
        }
        float* dSb = dS + (size_t)bc * 4096;
        #pragma unroll
        for (int r = 0; r < 4; ++r) {
            int i = 4 * ty + r;
            float scale = exp2f(63.f * l2d[i]);
            float w[4];
            #pragma unroll
            for (int j2 = 0; j2 < 4; ++j2)
                w[j2] = scale * sacc[r][j2];
            *(float4*)&dSb[i * 64 + 4 * tx] = *(float4*)w;
        }
    }
}

// o_final(bf16 into cat[row][256+i]) = o_intra + dec^(l+1) * (Q @ Sstart^T)
__device__ void bind_p3_body(int bc,
    const __half* __restrict__ vkq, const float* __restrict__ Sstart,
    const float* __restrict__ op_decay, const float* __restrict__ o,
    __hip_bfloat16* __restrict__ cat,
    float* B1, float* B2, float* l2d)
{
    const int b = bc >> 5, c = bc & 31;
    const size_t base = ((size_t)b * TT + (size_t)c * CB) * 256;
    const size_t obase = ((size_t)b * TT + (size_t)c * CB) * OD;
    const size_t cbase = ((size_t)b * TT + (size_t)c * CB) * KCAT + 256;
    const int tid = threadIdx.x;
    if (tid < 64) l2d[tid] = log2f(1.f / (1.f + expf(-op_decay[tid])));
    const int lr = tid >> 4, lc = (tid & 15) << 2;
    const float* Sb = Sstart + (size_t)bc * 4096;
    #pragma unroll
    for (int rr = 0; rr < 4; ++rr) {
        int t = lr + rr * 16;
        float4 qv = ldh4(&vkq[base + t * 256 + 128 + lc]);
        float4 sv = *(const float4*)&Sb[t * 64 + lc];
        float q4[4] = {qv.x, qv.y, qv.z, qv.w};
        float s4[4] = {sv.x, sv.y, sv.z, sv.w};
        #pragma unroll
        for (int j = 0; j < 4; ++j) {
            B1[(lc + j) * LST + t] = q4[j];
            B2[(lc + j) * LST + t] = s4[j];
        }
    }
    __syncthreads();
    const int tx = tid & 15, ty = tid >> 4;
    float acc[4][4] = {};
    for (int j = 0; j < 64; ++j) {
        float4 q4 = *(const float4*)&B1[j * LST + 4 * ty];
        float4 s4 = *(const float4*)&B2[j * LST + 4 * tx];
        float qr[4] = {q4.x, q4.y, q4.z, q4.w};
        float sr[4] = {s4.x, s4.y, s4.z, s4.w};
        #pragma unroll
        for (int r = 0; r < 4; ++r)
            #pragma unroll
            for (int i2 = 0; i2 < 4; ++i2)
                acc[r][i2] = fmaf(qr[r], sr[i2], acc[r][i2]);
    }
    #pragma unroll
    for (int r = 0; r < 4; ++r) {
        int l = 4 * ty + r;
        alignas(8) __hip_bfloat16 w[4];
        #pragma unroll
        for (int i2 = 0; i2 < 4; ++i2) {
            int i = 4 * tx + i2;
            float val = o[obase + l * OD + i] + exp2f((float)(l + 1) * l2d[i]) * acc[r][i2];
            w[i2] = __float2bfloat16(val);
        }
        *(float2*)&cat[cbase + l * KCAT + 4 * tx] = *(float2*)w;
    }
}

// fused1: blocks 0-255 -> bind_p1, blocks 256-767 -> scan_pass1
__global__ __launch_bounds__(256) void fused1(
    const __half* __restrict__ gi, const __half* __restrict__ vkq,
    const float* __restrict__ op_decay,
    float* __restrict__ ca_last, float* __restrict__ wb_last,
    float* __restrict__ o_intra, float* __restrict__ dS)
{
    __shared__ float B1[64 * LST];
    __shared__ float B2[64 * LST];
    __shared__ float B3[64 * LST];
    __shared__ float l2d[64];
    const int bid = blockIdx.x;
    if (bid < 256) bind_p1_body(bid, vkq, op_decay, o_intra, dS, B1, B2, B3, l2d);
    else           scan_pass1_body(bid - 256, gi, ca_last, wb_last);
}

// fused2: blocks 0-127 -> bind_p2 carry scan; blocks 128-135 -> scan_pass2
__global__ __launch_bounds__(256) void fused2(
    const float* __restrict__ dS, const float* __restrict__ op_decay,
    float* __restrict__ Sstart,
    const float* __restrict__ ca_last, const float* __restrict__ wb_last,
    float* __restrict__ h_prev)
{
    const int bid = blockIdx.x;
    if (bid < 128) {
        int idx = bid * 256 + threadIdx.x;   // 32768
        int j = idx & 63, i = (idx >> 6) & 63, b = idx >> 12;
        float dec = 1.f / (1.f + expf(-op_decay[i]));
        float d64 = exp2f(64.f * log2f(dec));
        float S = 0.f;
        for (int c = 0; c < NCB; ++c) {
            size_t o = (((size_t)b * NCB + c) * 4096) + i * 64 + j;
            Sstart[o] = S;
            S = d64 * S + dS[o];
        }
    } else {
        int idx = (bid - 128) * 256 + threadIdx.x;   // 2048
        int sd = idx & 255;
        int b  = idx >> 8;
        float h = 0.f;
        for (int c = 0; c < NC; ++c) {
            int o = (b * NC + c) * SD + sd;
            h_prev[o] = h;
            h = ca_last[o] * (h + wb_last[o]);
        }
    }
}

// fused3: blocks 0-255 -> bind_p3 (cat cols 256-319), 256-767 -> scan_pass3 (cols 0-255)
__global__ __launch_bounds__(256) void fused3(
    const __half* __restrict__ gi, const float* __restrict__ h_prev,
    const __half* __restrict__ vkq, const float* __restrict__ Sstart,
    const float* __restrict__ op_decay, const float* __restrict__ o_intra,
    __hip_bfloat16* __restrict__ cat)
{
    __shared__ float B1[64 * LST];
    __shared__ float B2[64 * LST];
    __shared__ float l2d[64];
    const int bid = blockIdx.x;
    if (bid < 256) bind_p3_body(bid, vkq, Sstart, op_decay, o_intra, cat, B1, B2, l2d);
    else           scan_pass3_body(bid - 256, gi, h_prev, cat);
}

// ---------------------------------------------------------------------------
// Fused output GEMM + residual + LayerNorm.
// y = LN(x + cat @ Wcomb^T + bias_comb) * ln_g + ln_b
// BM=32, BN=512 (full rows per block), BK=32, 512 threads (8 waves, 1x8),
// wave tile 32x64, double-buffered global_load_lds with granule swizzle.
// ---------------------------------------------------------------------------
__global__ __launch_bounds__(512) void outgemm_ln(
    const __hip_bfloat16* __restrict__ cat,    // [M][320]
    const __hip_bfloat16* __restrict__ Wcomb,  // [512][320]
    const float* __restrict__ bias_comb,
    const float* __restrict__ x,               // [M][512]
    const float* __restrict__ lng, const float* __restrict__ lnb,
    float* __restrict__ y)
{
    constexpr int BM = 32, BK = 32, NN = 512;
    __shared__ alignas(16) __hip_bfloat16 As[2][BM * BK];     // 2x2KB
    __shared__ alignas(16) __hip_bfloat16 Bs[2][NN * BK];     // 2x32KB
    __shared__ float psum[8][BM], psum2[8][BM], mvmu[BM], mvrs[BM];
    const int tid = threadIdx.x;
    const int lane = tid & 63, wid = tid >> 6;
    const int l15 = lane & 15, hgr = lane >> 4;
    const int bm = blockIdx.x * BM;

    // A staging (waves 0-1 only)
    const __hip_bfloat16* srcA = cat;
    int ldsOffA = 0;
    {
        int gg = (wid & 1) * 64 + lane;
        int row = gg >> 2, sl = (gg & 3) ^ ((row >> 1) & 3);
        srcA = cat + (size_t)(bm + row) * KCAT + sl * 8;
        ldsOffA = (wid & 1) * 1024;
    }
    // B staging: 4 calls per wave
    const __hip_bfloat16* srcB[4];
    int ldsOffB[4];
    #pragma unroll
    for (int c = 0; c < 4; ++c) {
        int gg = (wid * 4 + c) * 64 + lane;
        int row = gg >> 2, sl = (gg & 3) ^ ((row >> 1) & 3);
        srcB[c] = Wcomb + (size_t)row * KCAT + sl * 8;
        ldsOffB[c] = (wid * 4 + c) * 1024;
    }
    int offA[2], offB[4];
    #pragma unroll
    for (int mi = 0; mi < 2; ++mi) {
        int r = mi * 16 + l15;
        offA[mi] = r * 64 + (hgr ^ ((r >> 1) & 3)) * 16;
    }
    #pragma unroll
    for (int nj = 0; nj < 4; ++nj) {
        int n = wid * 64 + nj * 16 + l15;
        offB[nj] = n * 64 + (hgr ^ ((n >> 1) & 3)) * 16;
    }

    f32x4 acc[2][4] = {};
    constexpr int nk = KCAT / BK;   // 10

    if (wid < 2) gload_lds16(srcA, (char*)&As[0][0] + ldsOffA);
    #pragma unroll
    for (int c = 0; c < 4; ++c) gload_lds16(srcB[c], (char*)&Bs[0][0] + ldsOffB[c]);
    __syncthreads();

    int cur = 0;
    for (int t = 0; t < nk; ++t) {
        if (t + 1 < nk) {
            int k0 = (t + 1) * BK;
            if (wid < 2) gload_lds16(srcA + k0, (char*)&As[cur ^ 1][0] + ldsOffA);
            #pragma unroll
            for (int c = 0; c < 4; ++c)
                gload_lds16(srcB[c] + k0, (char*)&Bs[cur ^ 1][0] + ldsOffB[c]);
        }
        bf16x8_t af[2], bfr[4];
        #pragma unroll
        for (int mi = 0; mi < 2; ++mi)
            af[mi] = *(const bf16x8_t*)((const char*)&As[cur][0] + offA[mi]);
        #pragma unroll
        for (int nj = 0; nj < 4; ++nj)
            bfr[nj] = *(const bf16x8_t*)((const char*)&Bs[cur][0] + offB[nj]);
        #pragma unroll
        for (int mi = 0; mi < 2; ++mi)
            #pragma unroll
            for (int nj = 0; nj < 4; ++nj)
                acc[mi][nj] = __builtin_amdgcn_mfma_f32_16x16x32_bf16(
                    af[mi], bfr[nj], acc[mi][nj], 0, 0, 0);
        __syncthreads();
        cur ^= 1;
    }

    // epilogue: + bias + x residual
    #pragma unroll
    for (int nj = 0; nj < 4; ++nj) {
        int col = wid * 64 + nj * 16 + l15;
        float bc_ = bias_comb[col];
        #pragma unroll
        for (int mi = 0; mi < 2; ++mi) {
            int r0 = bm + mi * 16 + hgr * 4;
            #pragma unroll
            for (int e = 0; e < 4; ++e)
                acc[mi][nj][e] += bc_ + x[(size_t)(r0 + e) * DD + col];
        }
    }
    // per-row sums over this wave's 64 cols
    float s[8], s2[8];
    #pragma unroll
    for (int mi = 0; mi < 2; ++mi)
        #pragma unroll
        for (int e = 0; e < 4; ++e) {
            float a = 0.f, b2 = 0.f;
            #pragma unroll
            for (int nj = 0; nj < 4; ++nj) {
                float v = acc[mi][nj][e];
                a += v; b2 += v * v;
            }
            s[mi * 4 + e] = a; s2[mi * 4 + e] = b2;
        }
    #pragma unroll
    for (int off = 1; off <= 8; off <<= 1)
        #pragma unroll
        for (int i = 0; i < 8; ++i) {
            s[i]  += __shfl_xor(s[i], off);
            s2[i] += __shfl_xor(s2[i], off);
        }
    if (l15 == 0) {
        #pragma unroll
        for (int mi = 0; mi < 2; ++mi)
            #pragma unroll
            for (int e = 0; e < 4; ++e) {
                int lr = mi * 16 + hgr * 4 + e;
                psum[wid][lr]  = s[mi * 4 + e];
                psum2[wid][lr] = s2[mi * 4 + e];
            }
    }
    __syncthreads();
    if (tid < BM) {
        float tot = 0.f, tot2 = 0.f;
        #pragma unroll
        for (int w2 = 0; w2 < 8; ++w2) { tot += psum[w2][tid]; tot2 += psum2[w2][tid]; }
        float mu = tot * (1.f / 512.f);
        float var = tot2 * (1.f / 512.f) - mu * mu;
        mvmu[tid] = mu;
        mvrs[tid] = rsqrtf(var + 1e-5f);
    }
    __syncthreads();
    #pragma unroll
    for (int nj = 0; nj < 4; ++nj) {
        int col = wid * 64 + nj * 16 + l15;
        float g = lng[col], bb = lnb[col];
        #pragma unroll
        for (int mi = 0; mi < 2; ++mi) {
            #pragma unroll
            for (int e = 0; e < 4; ++e) {
                int lr = mi * 16 + hgr * 4 + e;
                y[(size_t)(bm + lr) * DD + col] =
                    (acc[mi][nj][e] - mvmu[lr]) * mvrs[lr] * g + bb;
            }
        }
    }
}

// ---------------------------------------------------------------------------
extern "C" void kernel_launch(void* const* d_in, const int* in_sizes, int n_in,
                              void* d_out, int out_size, void* d_ws, size_t ws_size,
                              hipStream_t stream)
{
    const float* x       = (const float*)d_in[0];
    const float* gate_W  = (const float*)d_in[1];
    const float* gate_b  = (const float*)d_in[2];
    const float* in_W    = (const float*)d_in[3];
    const float* in_b    = (const float*)d_in[4];
    const float* out_W   = (const float*)d_in[5];
    const float* out_b   = (const float*)d_in[6];
    const float* opv_W   = (const float*)d_in[7];
    const float* opv_b   = (const float*)d_in[8];
    const float* opk_W   = (const float*)d_in[9];
    const float* opk_b   = (const float*)d_in[10];
    const float* opq_W   = (const float*)d_in[11];
    const float* opq_b   = (const float*)d_in[12];
    const float* op_dec  = (const float*)d_in[13];
    const float* opout_W = (const float*)d_in[14];
    const float* opout_b = (const float*)d_in[15];
    const float* ln_g    = (const float*)d_in[16];
    const float* ln_b    = (const float*)d_in[17];
    float* y = (float*)d_out;

    char* w = (char*)d_ws;
    auto alloc = [&](size_t bytes) { char* p = w; w += (bytes + 255) & ~(size_t)255; return p; };
    __half* gi       = (__half*)alloc((size_t)MM * 512 * 2);
    __half* vkq      = (__half*)alloc((size_t)MM * 256 * 2);
    float* o_intra   = (float*)alloc((size_t)MM * 64 * 4);
    float* ca_last   = (float*)alloc((size_t)BB * NC * SD * 4);
    float* wb_last   = (float*)alloc((size_t)BB * NC * SD * 4);
    float* h_prev    = (float*)alloc((size_t)BB * NC * SD * 4);
    float* dS        = (float*)alloc((size_t)BB * NCB * 4096 * 4);
    float* Sstart    = (float*)alloc((size_t)BB * NCB * 4096 * 4);
    float* bias_cat  = (float*)alloc(768 * 4);
    float* bias_comb = (float*)alloc(512 * 4);
    __hip_bfloat16* cat   = (__hip_bfloat16*)alloc((size_t)MM * KCAT * 2);
    __hip_bfloat16* Wcat  = (__hip_bfloat16*)alloc((size_t)768 * 512 * 2);
    __hip_bfloat16* Wcomb = (__hip_bfloat16*)alloc((size_t)512 * KCAT * 2);

    // 1: weight prep (tiny)
    hipLaunchKernelGGL(conv_w, dim3((393216 + 163840 + 768 + 512 + 255) / 256), dim3(256), 0, stream,
                       gate_W, gate_b, in_W, in_b, opv_W, opk_W, opq_W,
                       opv_b, opk_b, opq_b, out_W, out_b, opout_W, opout_b,
                       Wcat, Wcomb, bias_cat, bias_comb);
    // 2: fused projection from fp32 x (fp16 outputs, XCD-swizzled grid 768 = 8*96)
    hipLaunchKernelGGL(gemm_proj, dim3(6 * (MM / 128)), dim3(256), 0, stream,
                       x, Wcat, bias_cat, gi, vkq,
                       MM, 768, 512, 512, 256);
    // 3: bind_p1 || scan_pass1
    hipLaunchKernelGGL(fused1, dim3(768), dim3(256), 0, stream,
                       gi, vkq, op_dec, ca_last, wb_last, o_intra, dS);
    // 4: carry scans
    hipLaunchKernelGGL(fused2, dim3(136), dim3(256), 0, stream,
                       dS, op_dec, Sstart, ca_last, wb_last, h_prev);
    // 5: bind_p3 || scan_pass3 -> cat[M][320] bf16
    hipLaunchKernelGGL(fused3, dim3(768), dim3(256), 0, stream,
                       gi, h_prev, vkq, Sstart, op_dec, o_intra, cat);
    // 6: y = LN(x + cat @ Wcomb^T + bias_comb)
    hipLaunchKernelGGL(outgemm_ln, dim3(MM / 32), dim3(512), 0, stream,
                       cat, Wcomb, bias_comb, x, ln_g, ln_b, y);
}

// Round 7
// 87.775 us; speedup vs baseline: 4.6364x; 1.0213x over previous
//
#include <hip/hip_runtime.h>
#include <hip/hip_bf16.h>
#include <hip/hip_fp16.h>
#include <math.h>

#define BB 8
#define TT 2048
#define DD 512
#define SD 256
#define OD 64
#define CHUNK 32
#define NC 64          // TT/CHUNK
#define CB 64          // binding-scan chunk
#define NCB 32         // TT/CB
#define MM (BB*TT)     // 16384
#define KCAT 320       // states(256) | obind(64)

typedef __attribute__((ext_vector_type(8))) short bf16x8_t;
typedef __attribute__((ext_vector_type(4))) float f32x4;

// async global->LDS, 16B per lane. LDS dest must be wave-uniform base (+lane*16 by HW).
__device__ __forceinline__ void gload_lds16(const void* gsrc, void* ldst) {
    __builtin_amdgcn_global_load_lds(
        (const __attribute__((address_space(1))) unsigned int*)gsrc,
        (__attribute__((address_space(3))) unsigned int*)ldst,
        16, 0, 0);
}

// load 4 consecutive __half as float4 (two 4B loads)
__device__ __forceinline__ float4 ldh4(const __half* p) {
    __half2 a = *(const __half2*)p;
    __half2 b = *(const __half2*)(p + 2);
    float2 fa = __half22float2(a), fb = __half22float2(b);
    return make_float4(fa.x, fa.y, fb.x, fb.y);
}

// ---------------------------------------------------------------------------
// conv_w: weight prep only.
// Wcat[768][512] = [gate|in|v|k|q|pad]^T bf16; Wcomb[512][320] = [out_W^T|opout_W^T];
// bias_cat[768]; bias_comb[512] = out_b + opout_b.
// ---------------------------------------------------------------------------
__global__ __launch_bounds__(256) void conv_w(
    const float* __restrict__ gate_W, const float* __restrict__ gate_b,
    const float* __restrict__ in_W,   const float* __restrict__ in_b,
    const float* __restrict__ opv_W,  const float* __restrict__ opk_W,
    const float* __restrict__ opq_W,
    const float* __restrict__ opv_b,  const float* __restrict__ opk_b,
    const float* __restrict__ opq_b,
    const float* __restrict__ out_W,  const float* __restrict__ out_b,
    const float* __restrict__ opout_W, const float* __restrict__ opout_b,
    __hip_bfloat16* __restrict__ Wcat,  __hip_bfloat16* __restrict__ Wcomb,
    float* __restrict__ bias_cat, float* __restrict__ bias_comb)
{
    int idx = blockIdx.x * 256 + threadIdx.x;
    if (idx < 393216) {                       // Wcat [768][512]
        int n = idx >> 9, k = idx & 511;
        float v;
        if (n < 256)       v = gate_W[k * 256 + n];
        else if (n < 512)  v = in_W[k * 256 + (n - 256)];
        else if (n < 704) {
            int h = (n - 512) >> 6, j = (n - 512) & 63;
            const float* W = (h == 0) ? opv_W : (h == 1) ? opk_W : opq_W;
            v = W[k * 64 + j];
        } else v = 0.f;
        Wcat[idx] = __float2bfloat16(v);
        return;
    }
    idx -= 393216;
    if (idx < 163840) {                       // Wcomb [512][320]
        int n = idx / KCAT, k = idx % KCAT;
        float v = (k < 256) ? out_W[k * 512 + n] : opout_W[(k - 256) * 512 + n];
        Wcomb[idx] = __float2bfloat16(v);
        return;
    }
    idx -= 163840;
    if (idx < 768) {
        float v;
        if (idx < 256)      v = gate_b[idx];
        else if (idx < 512) v = in_b[idx - 256];
        else if (idx < 704) {
            int h = (idx - 512) >> 6, j = (idx - 512) & 63;
            v = (h == 0) ? opv_b[j] : (h == 1) ? opk_b[j] : opq_b[j];
        } else v = 0.f;
        bias_cat[idx] = v;
        return;
    }
    idx -= 768;
    if (idx < 512) bias_comb[idx] = out_b[idx] + opout_b[idx];
}

// ---------------------------------------------------------------------------
// Projection GEMM: [gi | vkq](fp16) = x(fp32) @ Wcat^T + bias, sigmoid<sigCols.
// 128x128 tile, BK=32, 512 threads / 8 waves (2x4), wave tile 64x32.
// A: fp32 reg-staged (1 granule/thread, in-reg bf16 cvt, swizzled ds_write).
// B: global_load_lds(16B), pre-swizzled source, linear LDS dest.
// Grid 768 = 3 blocks/CU x 8 waves = 24 waves/CU. XCD-chunked block swizzle.
// ---------------------------------------------------------------------------
__global__ __launch_bounds__(512, 6) void gemm_proj(
    const float* __restrict__ A,             // x [M][K] fp32
    const __hip_bfloat16* __restrict__ Bt,   // Wcat [N][K]
    const float* __restrict__ bias,
    __half* __restrict__ out0,
    __half* __restrict__ out1,               // cols >= n0, stride N-n0
    int M, int N, int K, int n0, int sigCols)
{
    constexpr int BM = 128, BK = 32;
    __shared__ alignas(16) __hip_bfloat16 As[2][BM * BK];   // 8KB each
    __shared__ alignas(16) __hip_bfloat16 Bs[2][BM * BK];
    const int tid = threadIdx.x;
    const int lane = tid & 63, wid = tid >> 6;
    const int wr = wid >> 2, wc = wid & 3;           // 2x4 wave grid, 64x32 tiles
    const int nbn = N >> 7;
    const int chunk = gridDim.x >> 3;
    const int b = blockIdx.x;
    const int orig = (b & 7) * chunk + (b >> 3);     // XCD-contiguous chunks
    const int bm = (orig / nbn) * BM, bn = (orig % nbn) * BM;
    const int l15 = lane & 15, hgr = lane >> 4;

    // staging: granule g = tid (512 granules = 128 rows x 4 slots)
    const int grow = tid >> 2, gslot = tid & 3;
    const int gsw = gslot ^ ((grow >> 1) & 3);
    const float* srcA = A + (size_t)(bm + grow) * K + gslot * 8;
    const int wOffA = grow * 64 + gsw * 16;                  // swizzled LDS bytes
    const __hip_bfloat16* srcB = Bt + (size_t)(bn + grow) * K + gsw * 8;  // pre-swz src
    const int ldsOffB = (tid & ~63) * 16;                    // linear, wave-uniform

    int offA[4], offB[2];
    #pragma unroll
    for (int mi = 0; mi < 4; ++mi) {
        int r = wr * 64 + mi * 16 + l15;
        offA[mi] = r * 64 + (hgr ^ ((r >> 1) & 3)) * 16;
    }
    #pragma unroll
    for (int nj = 0; nj < 2; ++nj) {
        int r = wc * 32 + nj * 16 + l15;
        offB[nj] = r * 64 + (hgr ^ ((r >> 1) & 3)) * 16;
    }

    f32x4 acc[4][2] = {};
    const int nk = K / BK;
    float4 a4lo, a4hi;

    // prologue: stage k-step 0
    a4lo = *(const float4*)(srcA);
    a4hi = *(const float4*)(srcA + 4);
    gload_lds16(srcB, (char*)&Bs[0][0] + ldsOffB);
    {
        alignas(16) __hip_bfloat16 h[8] = {
            __float2bfloat16(a4lo.x), __float2bfloat16(a4lo.y),
            __float2bfloat16(a4lo.z), __float2bfloat16(a4lo.w),
            __float2bfloat16(a4hi.x), __float2bfloat16(a4hi.y),
            __float2bfloat16(a4hi.z), __float2bfloat16(a4hi.w)};
        *(float4*)((char*)&As[0][0] + wOffA) = *(float4*)h;
    }
    __syncthreads();

    int cur = 0;
    for (int t = 0; t < nk; ++t) {
        const bool more = (t + 1 < nk);
        if (more) {
            int k0 = (t + 1) * BK;
            a4lo = *(const float4*)(srcA + k0);              // issue-early A loads
            a4hi = *(const float4*)(srcA + k0 + 4);
            gload_lds16(srcB + k0, (char*)&Bs[cur ^ 1][0] + ldsOffB);
        }
        bf16x8_t af[4], bfr[2];
        #pragma unroll
        for (int mi = 0; mi < 4; ++mi)
            af[mi] = *(const bf16x8_t*)((const char*)&As[cur][0] + offA[mi]);
        #pragma unroll
        for (int nj = 0; nj < 2; ++nj)
            bfr[nj] = *(const bf16x8_t*)((const char*)&Bs[cur][0] + offB[nj]);
        #pragma unroll
        for (int mi = 0; mi < 4; ++mi)
            #pragma unroll
            for (int nj = 0; nj < 2; ++nj)
                acc[mi][nj] = __builtin_amdgcn_mfma_f32_16x16x32_bf16(
                    af[mi], bfr[nj], acc[mi][nj], 0, 0, 0);
        if (more) {                                          // write-late A stage
            alignas(16) __hip_bfloat16 h[8] = {
                __float2bfloat16(a4lo.x), __float2bfloat16(a4lo.y),
                __float2bfloat16(a4lo.z), __float2bfloat16(a4lo.w),
                __float2bfloat16(a4hi.x), __float2bfloat16(a4hi.y),
                __float2bfloat16(a4hi.z), __float2bfloat16(a4hi.w)};
            *(float4*)((char*)&As[cur ^ 1][0] + wOffA) = *(float4*)h;
        }
        __syncthreads();
        cur ^= 1;
    }

    const int n1 = N - n0;
    #pragma unroll
    for (int mi = 0; mi < 4; ++mi) {
        #pragma unroll
        for (int nj = 0; nj < 2; ++nj) {
            int col = bn + wc * 32 + nj * 16 + l15;
            int r0 = bm + wr * 64 + mi * 16 + hgr * 4;
            float bv = bias[col];
            #pragma unroll
            for (int e = 0; e < 4; ++e) {
                int row = r0 + e;
                float val = acc[mi][nj][e] + bv;
                if (col < n0) {
                    if (col < sigCols) val = 1.f / (1.f + expf(-val));
                    out0[(size_t)row * n0 + col] = __float2half(val);
                } else {
                    out1[(size_t)row * n1 + (col - n0)] = __float2half(val);
                }
            }
        }
    }
}

// ---------------------------------------------------------------------------
// Scan / bind device bodies. gi: [M][512] fp16 (g | in). vkq: [M][256] fp16.
// ---------------------------------------------------------------------------
__device__ void scan_pass1_body(int blk,
    const __half* __restrict__ gi,
    float* __restrict__ ca_last, float* __restrict__ wb_last)
{
    int idx = blk * 256 + threadIdx.x;        // 131072
    int sd = idx & 255;
    int c  = (idx >> 8) & 63;
    int b  = idx >> 14;
    size_t base = ((size_t)(b * TT + c * CHUNK)) * 512;
    float prod = 1.f, wb = 0.f;
    for (int i = 0; i < CHUNK; ++i) {
        size_t off = base + (size_t)i * 512;
        float g  = __half2float(gi[off + sd]);
        float il = __half2float(gi[off + 256 + sd]);
        float a = fmaxf(g, 1e-6f);
        prod *= a;
        wb += (1.f - g) * il / fmaxf(prod, 1e-8f);
    }
    int cidx = (b * NC + c) * SD + sd;
    ca_last[cidx] = prod;
    wb_last[cidx] = wb;
}

// writes states bf16 into cat[row][0..255], stride KCAT
__device__ void scan_pass3_body(int blk,
    const __half* __restrict__ gi, const float* __restrict__ h_prev,
    __hip_bfloat16* __restrict__ cat)
{
    int idx = blk * 256 + threadIdx.x;        // 131072
    int sd = idx & 255;
    int c  = (idx >> 8) & 63;
    int b  = idx >> 14;
    size_t base = ((size_t)(b * TT + c * CHUNK)) * 512;
    size_t obase = ((size_t)(b * TT + c * CHUNK)) * KCAT + sd;
    float h = h_prev[(b * NC + c) * SD + sd];
    float prod = 1.f, wb = 0.f;
    for (int i = 0; i < CHUNK; ++i) {
        size_t off = base + (size_t)i * 512;
        float g  = __half2float(gi[off + sd]);
        float il = __half2float(gi[off + 256 + sd]);
        float a = fmaxf(g, 1e-6f);
        prod *= a;
        wb += (1.f - g) * il / fmaxf(prod, 1e-8f);
        cat[obase + (size_t)i * KCAT] = __float2bfloat16(prod * (h + wb));
    }
}

#define LST 68
__device__ void bind_p1_body(int bc,
    const __half* __restrict__ vkq, const float* __restrict__ op_decay,
    float* __restrict__ o, float* __restrict__ dS,
    float* B1, float* B2, float* B3, float* l2d)
{
    const int b = bc >> 5, c = bc & 31;
    const size_t base = ((size_t)b * TT + (size_t)c * CB) * 256;
    const size_t obase = ((size_t)b * TT + (size_t)c * CB) * OD;
    const int tid = threadIdx.x;
    if (tid < 64) l2d[tid] = log2f(1.f / (1.f + expf(-op_decay[tid])));
    const int lr = tid >> 4, lc = (tid & 15) << 2;
    #pragma unroll
    for (int rr = 0; rr < 4; ++rr) {
        int t = lr + rr * 16;
        float4 qv = ldh4(&vkq[base + t * 256 + 128 + lc]);
        float4 kv = ldh4(&vkq[base + t * 256 + 64 + lc]);
        float q4[4] = {qv.x, qv.y, qv.z, qv.w};
        float k4[4] = {kv.x, kv.y, kv.z, kv.w};
        #pragma unroll
        for (int j = 0; j < 4; ++j) {
            B1[(lc + j) * LST + t] = q4[j];
            B2[(lc + j) * LST + t] = k4[j];
        }
    }
    __syncthreads();
    const int tx = tid & 15, ty = tid >> 4;
    {
        float a_acc[4][4] = {};
        for (int d = 0; d < 64; ++d) {
            float4 q4 = *(const float4*)&B1[d * LST + 4 * ty];
            float4 k4 = *(const float4*)&B2[d * LST + 4 * tx];
            float qr[4] = {q4.x, q4.y, q4.z, q4.w};
            float kr[4] = {k4.x, k4.y, k4.z, k4.w};
            #pragma unroll
            for (int r = 0; r < 4; ++r)
                #pragma unroll
                for (int s = 0; s < 4; ++s)
                    a_acc[r][s] = fmaf(qr[r], kr[s], a_acc[r][s]);
        }
        __syncthreads();
        #pragma unroll
        for (int s = 0; s < 4; ++s) {
            int ss = 4 * tx + s;
            float w[4];
            #pragma unroll
            for (int r = 0; r < 4; ++r)
                w[r] = (ss <= 4 * ty + r) ? a_acc[r][s] : 0.f;
            *(float4*)&B3[ss * LST + 4 * ty] = *(float4*)w;
        }
    }
    #pragma unroll
    for (int rr = 0; rr < 4; ++rr) {
        int m = lr + rr * 16;
        float4 vv = ldh4(&vkq[base + m * 256 + 0 + lc]);
        float4 kv = ldh4(&vkq[base + m * 256 + 64 + lc]);
        float v4[4] = {vv.x, vv.y, vv.z, vv.w};
        #pragma unroll
        for (int j = 0; j < 4; ++j)
            v4[j] *= exp2f(-(float)m * l2d[lc + j]);
        *(float4*)&B1[m * LST + lc] = *(float4*)v4;
        float k4[4] = {kv.x, kv.y, kv.z, kv.w};
        *(float4*)&B2[m * LST + lc] = *(float4*)k4;
    }
    __syncthreads();
    {
        float p[4][4] = {};
        for (int s = 0; s < 64; ++s) {
            float4 a4 = *(const float4*)&B3[s * LST + 4 * ty];
            float4 v4 = *(const float4*)&B1[s * LST + 4 * tx];
            float ar[4] = {a4.x, a4.y, a4.z, a4.w};
            float vr[4] = {v4.x, v4.y, v4.z, v4.w};
            #pragma unroll
            for (int r = 0; r < 4; ++r)
                #pragma unroll
                for (int i2 = 0; i2 < 4; ++i2)
                    p[r][i2] = fmaf(ar[r], vr[i2], p[r][i2]);
        }
        #pragma unroll
        for (int r = 0; r < 4; ++r) {
            int t = 4 * ty + r;
            float w[4];
            #pragma unroll
            for (int i2 = 0; i2 < 4; ++i2)
                w[i2] = exp2f((float)t * l2d[4 * tx + i2]) * p[r][i2];
            *(float4*)&o[obase + t * OD + 4 * tx] = *(float4*)w;
        }
    }
    {
        float sacc[4][4] = {};
        for (int m = 0; m < 64; ++m) {
            float4 v4 = *(const float4*)&B1[m * LST + 4 * ty];
            float4 k4 = *(const float4*)&B2[m * LST + 4 * tx];
            float vr[4] = {v4.x, v4.y, v4.z, v4.w};
            float kr[4] = {k4.x, k4.y, k4.z, k4.w};
            #pragma unroll
            for (int r = 0; r < 4; ++r)
                #pragma unroll
                for (int j = 0; j < 4; ++j)
                    sacc[r][j] = fmaf(vr[r], kr[j], sacc[r][j]);
        }
        float* dSb = dS + (size_t)bc * 4096;
        #pragma unroll
        for (int r = 0; r < 4; ++r) {
            int i = 4 * ty + r;
            float scale = exp2f(63.f * l2d[i]);
            float w[4];
            #pragma unroll
            for (int j2 = 0; j2 < 4; ++j2)
                w[j2] = scale * sacc[r][j2];
            *(float4*)&dSb[i * 64 + 4 * tx] = *(float4*)w;
        }
    }
}

// o_final(bf16 into cat[row][256+i]) = o_intra + dec^(l+1) * (Q @ Sstart^T)
__device__ void bind_p3_body(int bc,
    const __half* __restrict__ vkq, const float* __restrict__ Sstart,
    const float* __restrict__ op_decay, const float* __restrict__ o,
    __hip_bfloat16* __restrict__ cat,
    float* B1, float* B2, float* l2d)
{
    const int b = bc >> 5, c = bc & 31;
    const size_t base = ((size_t)b * TT + (size_t)c * CB) * 256;
    const size_t obase = ((size_t)b * TT + (size_t)c * CB) * OD;
    const size_t cbase = ((size_t)b * TT + (size_t)c * CB) * KCAT + 256;
    const int tid = threadIdx.x;
    if (tid < 64) l2d[tid] = log2f(1.f / (1.f + expf(-op_decay[tid])));
    const int lr = tid >> 4, lc = (tid & 15) << 2;
    const float* Sb = Sstart + (size_t)bc * 4096;
    #pragma unroll
    for (int rr = 0; rr < 4; ++rr) {
        int t = lr + rr * 16;
        float4 qv = ldh4(&vkq[base + t * 256 + 128 + lc]);
        float4 sv = *(const float4*)&Sb[t * 64 + lc];
        float q4[4] = {qv.x, qv.y, qv.z, qv.w};
        float s4[4] = {sv.x, sv.y, sv.z, sv.w};
        #pragma unroll
        for (int j = 0; j < 4; ++j) {
            B1[(lc + j) * LST + t] = q4[j];
            B2[(lc + j) * LST + t] = s4[j];
        }
    }
    __syncthreads();
    const int tx = tid & 15, ty = tid >> 4;
    float acc[4][4] = {};
    for (int j = 0; j < 64; ++j) {
        float4 q4 = *(const float4*)&B1[j * LST + 4 * ty];
        float4 s4 = *(const float4*)&B2[j * LST + 4 * tx];
        float qr[4] = {q4.x, q4.y, q4.z, q4.w};
        float sr[4] = {s4.x, s4.y, s4.z, s4.w};
        #pragma unroll
        for (int r = 0; r < 4; ++r)
            #pragma unroll
            for (int i2 = 0; i2 < 4; ++i2)
                acc[r][i2] = fmaf(qr[r], sr[i2], acc[r][i2]);
    }
    #pragma unroll
    for (int r = 0; r < 4; ++r) {
        int l = 4 * ty + r;
        alignas(8) __hip_bfloat16 w[4];
        #pragma unroll
        for (int i2 = 0; i2 < 4; ++i2) {
            int i = 4 * tx + i2;
            float val = o[obase + l * OD + i] + exp2f((float)(l + 1) * l2d[i]) * acc[r][i2];
            w[i2] = __float2bfloat16(val);
        }
        *(float2*)&cat[cbase + l * KCAT + 4 * tx] = *(float2*)w;
    }
}

// fused1: blocks 0-255 -> bind_p1, blocks 256-767 -> scan_pass1
__global__ __launch_bounds__(256) void fused1(
    const __half* __restrict__ gi, const __half* __restrict__ vkq,
    const float* __restrict__ op_decay,
    float* __restrict__ ca_last, float* __restrict__ wb_last,
    float* __restrict__ o_intra, float* __restrict__ dS)
{
    __shared__ float B1[64 * LST];
    __shared__ float B2[64 * LST];
    __shared__ float B3[64 * LST];
    __shared__ float l2d[64];
    const int bid = blockIdx.x;
    if (bid < 256) bind_p1_body(bid, vkq, op_decay, o_intra, dS, B1, B2, B3, l2d);
    else           scan_pass1_body(bid - 256, gi, ca_last, wb_last);
}

// fused2: blocks 0-127 -> bind_p2 carry scan; blocks 128-135 -> scan_pass2
__global__ __launch_bounds__(256) void fused2(
    const float* __restrict__ dS, const float* __restrict__ op_decay,
    float* __restrict__ Sstart,
    const float* __restrict__ ca_last, const float* __restrict__ wb_last,
    float* __restrict__ h_prev)
{
    const int bid = blockIdx.x;
    if (bid < 128) {
        int idx = bid * 256 + threadIdx.x;   // 32768
        int j = idx & 63, i = (idx >> 6) & 63, b = idx >> 12;
        float dec = 1.f / (1.f + expf(-op_decay[i]));
        float d64 = exp2f(64.f * log2f(dec));
        float S = 0.f;
        for (int c = 0; c < NCB; ++c) {
            size_t o = (((size_t)b * NCB + c) * 4096) + i * 64 + j;
            Sstart[o] = S;
            S = d64 * S + dS[o];
        }
    } else {
        int idx = (bid - 128) * 256 + threadIdx.x;   // 2048
        int sd = idx & 255;
        int b  = idx >> 8;
        float h = 0.f;
        for (int c = 0; c < NC; ++c) {
            int o = (b * NC + c) * SD + sd;
            h_prev[o] = h;
            h = ca_last[o] * (h + wb_last[o]);
        }
    }
}

// fused3: blocks 0-255 -> bind_p3 (cat cols 256-319), 256-767 -> scan_pass3 (cols 0-255)
__global__ __launch_bounds__(256) void fused3(
    const __half* __restrict__ gi, const float* __restrict__ h_prev,
    const __half* __restrict__ vkq, const float* __restrict__ Sstart,
    const float* __restrict__ op_decay, const float* __restrict__ o_intra,
    __hip_bfloat16* __restrict__ cat)
{
    __shared__ float B1[64 * LST];
    __shared__ float B2[64 * LST];
    __shared__ float l2d[64];
    const int bid = blockIdx.x;
    if (bid < 256) bind_p3_body(bid, vkq, Sstart, op_decay, o_intra, cat, B1, B2, l2d);
    else           scan_pass3_body(bid - 256, gi, h_prev, cat);
}

// ---------------------------------------------------------------------------
// Fused output GEMM + residual + LayerNorm.
// y = LN(x + cat @ Wcomb^T + bias_comb) * ln_g + ln_b
// BM=32, BN=512 (full rows per block), BK=32, 512 threads (8 waves, 1x8),
// wave tile 32x64, double-buffered global_load_lds with granule swizzle.
// ---------------------------------------------------------------------------
__global__ __launch_bounds__(512) void outgemm_ln(
    const __hip_bfloat16* __restrict__ cat,    // [M][320]
    const __hip_bfloat16* __restrict__ Wcomb,  // [512][320]
    const float* __restrict__ bias_comb,
    const float* __restrict__ x,               // [M][512]
    const float* __restrict__ lng, const float* __restrict__ lnb,
    float* __restrict__ y)
{
    constexpr int BM = 32, BK = 32, NN = 512;
    __shared__ alignas(16) __hip_bfloat16 As[2][BM * BK];     // 2x2KB
    __shared__ alignas(16) __hip_bfloat16 Bs[2][NN * BK];     // 2x32KB
    __shared__ float psum[8][BM], psum2[8][BM], mvmu[BM], mvrs[BM];
    const int tid = threadIdx.x;
    const int lane = tid & 63, wid = tid >> 6;
    const int l15 = lane & 15, hgr = lane >> 4;
    const int bm = blockIdx.x * BM;

    // A staging (waves 0-1 only)
    const __hip_bfloat16* srcA = cat;
    int ldsOffA = 0;
    {
        int gg = (wid & 1) * 64 + lane;
        int row = gg >> 2, sl = (gg & 3) ^ ((row >> 1) & 3);
        srcA = cat + (size_t)(bm + row) * KCAT + sl * 8;
        ldsOffA = (wid & 1) * 1024;
    }
    // B staging: 4 calls per wave
    const __hip_bfloat16* srcB[4];
    int ldsOffB[4];
    #pragma unroll
    for (int c = 0; c < 4; ++c) {
        int gg = (wid * 4 + c) * 64 + lane;
        int row = gg >> 2, sl = (gg & 3) ^ ((row >> 1) & 3);
        srcB[c] = Wcomb + (size_t)row * KCAT + sl * 8;
        ldsOffB[c] = (wid * 4 + c) * 1024;
    }
    int offA[2], offB[4];
    #pragma unroll
    for (int mi = 0; mi < 2; ++mi) {
        int r = mi * 16 + l15;
        offA[mi] = r * 64 + (hgr ^ ((r >> 1) & 3)) * 16;
    }
    #pragma unroll
    for (int nj = 0; nj < 4; ++nj) {
        int n = wid * 64 + nj * 16 + l15;
        offB[nj] = n * 64 + (hgr ^ ((n >> 1) & 3)) * 16;
    }

    f32x4 acc[2][4] = {};
    constexpr int nk = KCAT / BK;   // 10

    if (wid < 2) gload_lds16(srcA, (char*)&As[0][0] + ldsOffA);
    #pragma unroll
    for (int c = 0; c < 4; ++c) gload_lds16(srcB[c], (char*)&Bs[0][0] + ldsOffB[c]);
    __syncthreads();

    int cur = 0;
    for (int t = 0; t < nk; ++t) {
        if (t + 1 < nk) {
            int k0 = (t + 1) * BK;
            if (wid < 2) gload_lds16(srcA + k0, (char*)&As[cur ^ 1][0] + ldsOffA);
            #pragma unroll
            for (int c = 0; c < 4; ++c)
                gload_lds16(srcB[c] + k0, (char*)&Bs[cur ^ 1][0] + ldsOffB[c]);
        }
        bf16x8_t af[2], bfr[4];
        #pragma unroll
        for (int mi = 0; mi < 2; ++mi)
            af[mi] = *(const bf16x8_t*)((const char*)&As[cur][0] + offA[mi]);
        #pragma unroll
        for (int nj = 0; nj < 4; ++nj)
            bfr[nj] = *(const bf16x8_t*)((const char*)&Bs[cur][0] + offB[nj]);
        #pragma unroll
        for (int mi = 0; mi < 2; ++mi)
            #pragma unroll
            for (int nj = 0; nj < 4; ++nj)
                acc[mi][nj] = __builtin_amdgcn_mfma_f32_16x16x32_bf16(
                    af[mi], bfr[nj], acc[mi][nj], 0, 0, 0);
        __syncthreads();
        cur ^= 1;
    }

    // epilogue: + bias + x residual
    #pragma unroll
    for (int nj = 0; nj < 4; ++nj) {
        int col = wid * 64 + nj * 16 + l15;
        float bc_ = bias_comb[col];
        #pragma unroll
        for (int mi = 0; mi < 2; ++mi) {
            int r0 = bm + mi * 16 + hgr * 4;
            #pragma unroll
            for (int e = 0; e < 4; ++e)
                acc[mi][nj][e] += bc_ + x[(size_t)(r0 + e) * DD + col];
        }
    }
    // per-row sums over this wave's 64 cols
    float s[8], s2[8];
    #pragma unroll
    for (int mi = 0; mi < 2; ++mi)
        #pragma unroll
        for (int e = 0; e < 4; ++e) {
            float a = 0.f, b2 = 0.f;
            #pragma unroll
            for (int nj = 0; nj < 4; ++nj) {
                float v = acc[mi][nj][e];
                a += v; b2 += v * v;
            }
            s[mi * 4 + e] = a; s2[mi * 4 + e] = b2;
        }
    #pragma unroll
    for (int off = 1; off <= 8; off <<= 1)
        #pragma unroll
        for (int i = 0; i < 8; ++i) {
            s[i]  += __shfl_xor(s[i], off);
            s2[i] += __shfl_xor(s2[i], off);
        }
    if (l15 == 0) {
        #pragma unroll
        for (int mi = 0; mi < 2; ++mi)
            #pragma unroll
            for (int e = 0; e < 4; ++e) {
                int lr = mi * 16 + hgr * 4 + e;
                psum[wid][lr]  = s[mi * 4 + e];
                psum2[wid][lr] = s2[mi * 4 + e];
            }
    }
    __syncthreads();
    if (tid < BM) {
        float tot = 0.f, tot2 = 0.f;
        #pragma unroll
        for (int w2 = 0; w2 < 8; ++w2) { tot += psum[w2][tid]; tot2 += psum2[w2][tid]; }
        float mu = tot * (1.f / 512.f);
        float var = tot2 * (1.f / 512.f) - mu * mu;
        mvmu[tid] = mu;
        mvrs[tid] = rsqrtf(var + 1e-5f);
    }
    __syncthreads();
    #pragma unroll
    for (int nj = 0; nj < 4; ++nj) {
        int col = wid * 64 + nj * 16 + l15;
        float g = lng[col], bb = lnb[col];
        #pragma unroll
        for (int mi = 0; mi < 2; ++mi) {
            #pragma unroll
            for (int e = 0; e < 4; ++e) {
                int lr = mi * 16 + hgr * 4 + e;
                y[(size_t)(bm + lr) * DD + col] =
                    (acc[mi][nj][e] - mvmu[lr]) * mvrs[lr] * g + bb;
            }
        }
    }
}

// ---------------------------------------------------------------------------
extern "C" void kernel_launch(void* const* d_in, const int* in_sizes, int n_in,
                              void* d_out, int out_size, void* d_ws, size_t ws_size,
                              hipStream_t stream)
{
    const float* x       = (const float*)d_in[0];
    const float* gate_W  = (const float*)d_in[1];
    const float* gate_b  = (const float*)d_in[2];
    const float* in_W    = (const float*)d_in[3];
    const float* in_b    = (const float*)d_in[4];
    const float* out_W   = (const float*)d_in[5];
    const float* out_b   = (const float*)d_in[6];
    const float* opv_W   = (const float*)d_in[7];
    const float* opv_b   = (const float*)d_in[8];
    const float* opk_W   = (const float*)d_in[9];
    const float* opk_b   = (const float*)d_in[10];
    const float* opq_W   = (const float*)d_in[11];
    const float* opq_b   = (const float*)d_in[12];
    const float* op_dec  = (const float*)d_in[13];
    const float* opout_W = (const float*)d_in[14];
    const float* opout_b = (const float*)d_in[15];
    const float* ln_g    = (const float*)d_in[16];
    const float* ln_b    = (const float*)d_in[17];
    float* y = (float*)d_out;

    char* w = (char*)d_ws;
    auto alloc = [&](size_t bytes) { char* p = w; w += (bytes + 255) & ~(size_t)255; return p; };
    __half* gi       = (__half*)alloc((size_t)MM * 512 * 2);
    __half* vkq      = (__half*)alloc((size_t)MM * 256 * 2);
    float* o_intra   = (float*)alloc((size_t)MM * 64 * 4);
    float* ca_last   = (float*)alloc((size_t)BB * NC * SD * 4);
    float* wb_last   = (float*)alloc((size_t)BB * NC * SD * 4);
    float* h_prev    = (float*)alloc((size_t)BB * NC * SD * 4);
    float* dS        = (float*)alloc((size_t)BB * NCB * 4096 * 4);
    float* Sstart    = (float*)alloc((size_t)BB * NCB * 4096 * 4);
    float* bias_cat  = (float*)alloc(768 * 4);
    float* bias_comb = (float*)alloc(512 * 4);
    __hip_bfloat16* cat   = (__hip_bfloat16*)alloc((size_t)MM * KCAT * 2);
    __hip_bfloat16* Wcat  = (__hip_bfloat16*)alloc((size_t)768 * 512 * 2);
    __hip_bfloat16* Wcomb = (__hip_bfloat16*)alloc((size_t)512 * KCAT * 2);

    // 1: weight prep (tiny)
    hipLaunchKernelGGL(conv_w, dim3((393216 + 163840 + 768 + 512 + 255) / 256), dim3(256), 0, stream,
                       gate_W, gate_b, in_W, in_b, opv_W, opk_W, opq_W,
                       opv_b, opk_b, opq_b, out_W, out_b, opout_W, opout_b,
                       Wcat, Wcomb, bias_cat, bias_comb);
    // 2: fused projection from fp32 x (fp16 outputs, XCD-swizzled grid 768 = 8*96)
    hipLaunchKernelGGL(gemm_proj, dim3(6 * (MM / 128)), dim3(512), 0, stream,
                       x, Wcat, bias_cat, gi, vkq,
                       MM, 768, 512, 512, 256);
    // 3: bind_p1 || scan_pass1
    hipLaunchKernelGGL(fused1, dim3(768), dim3(256), 0, stream,
                       gi, vkq, op_dec, ca_last, wb_last, o_intra, dS);
    // 4: carry scans
    hipLaunchKernelGGL(fused2, dim3(136), dim3(256), 0, stream,
                       dS, op_dec, Sstart, ca_last, wb_last, h_prev);
    // 5: bind_p3 || scan_pass3 -> cat[M][320] bf16
    hipLaunchKernelGGL(fused3, dim3(768), dim3(256), 0, stream,
                       gi, h_prev, vkq, Sstart, op_dec, o_intra, cat);
    // 6: y = LN(x + cat @ Wcomb^T + bias_comb)
    hipLaunchKernelGGL(outgemm_ln, dim3(MM / 32), dim3(512), 0, stream,
                       cat, Wcomb, bias_comb, x, ln_g, ln_b, y);
}

// Round 8
// 87.363 us; speedup vs baseline: 4.6582x; 1.0047x over previous
//
#include <hip/hip_runtime.h>
#include <hip/hip_bf16.h>
#include <hip/hip_fp16.h>
#include <math.h>

#define BB 8
#define TT 2048
#define DD 512
#define SD 256
#define OD 64
#define CHUNK 32
#define NC 64          // TT/CHUNK
#define CB 64          // binding-scan chunk
#define NCB 32         // TT/CB
#define MM (BB*TT)     // 16384
#define KCAT 320       // states(256) | obind(64)

typedef __attribute__((ext_vector_type(8))) short bf16x8_t;
typedef __attribute__((ext_vector_type(4))) float f32x4;

// async global->LDS, 16B per lane. LDS dest must be wave-uniform base (+lane*16 by HW).
__device__ __forceinline__ void gload_lds16(const void* gsrc, void* ldst) {
    __builtin_amdgcn_global_load_lds(
        (const __attribute__((address_space(1))) unsigned int*)gsrc,
        (__attribute__((address_space(3))) unsigned int*)ldst,
        16, 0, 0);
}

// load 4 consecutive __half as float4 (two 4B loads)
__device__ __forceinline__ float4 ldh4(const __half* p) {
    __half2 a = *(const __half2*)p;
    __half2 b = *(const __half2*)(p + 2);
    float2 fa = __half22float2(a), fb = __half22float2(b);
    return make_float4(fa.x, fa.y, fb.x, fb.y);
}

// ---------------------------------------------------------------------------
// conv_w: weight prep only.
// Wcat[768][512] = [gate|in|v|k|q|pad]^T bf16; Wcomb[512][320] = [out_W^T|opout_W^T];
// bias_cat[768]; bias_comb[512] = out_b + opout_b.
// ---------------------------------------------------------------------------
__global__ __launch_bounds__(256) void conv_w(
    const float* __restrict__ gate_W, const float* __restrict__ gate_b,
    const float* __restrict__ in_W,   const float* __restrict__ in_b,
    const float* __restrict__ opv_W,  const float* __restrict__ opk_W,
    const float* __restrict__ opq_W,
    const float* __restrict__ opv_b,  const float* __restrict__ opk_b,
    const float* __restrict__ opq_b,
    const float* __restrict__ out_W,  const float* __restrict__ out_b,
    const float* __restrict__ opout_W, const float* __restrict__ opout_b,
    __hip_bfloat16* __restrict__ Wcat,  __hip_bfloat16* __restrict__ Wcomb,
    float* __restrict__ bias_cat, float* __restrict__ bias_comb)
{
    int idx = blockIdx.x * 256 + threadIdx.x;
    if (idx < 393216) {                       // Wcat [768][512]
        int n = idx >> 9, k = idx & 511;
        float v;
        if (n < 256)       v = gate_W[k * 256 + n];
        else if (n < 512)  v = in_W[k * 256 + (n - 256)];
        else if (n < 704) {
            int h = (n - 512) >> 6, j = (n - 512) & 63;
            const float* W = (h == 0) ? opv_W : (h == 1) ? opk_W : opq_W;
            v = W[k * 64 + j];
        } else v = 0.f;
        Wcat[idx] = __float2bfloat16(v);
        return;
    }
    idx -= 393216;
    if (idx < 163840) {                       // Wcomb [512][320]
        int n = idx / KCAT, k = idx % KCAT;
        float v = (k < 256) ? out_W[k * 512 + n] : opout_W[(k - 256) * 512 + n];
        Wcomb[idx] = __float2bfloat16(v);
        return;
    }
    idx -= 163840;
    if (idx < 768) {
        float v;
        if (idx < 256)      v = gate_b[idx];
        else if (idx < 512) v = in_b[idx - 256];
        else if (idx < 704) {
            int h = (idx - 512) >> 6, j = (idx - 512) & 63;
            v = (h == 0) ? opv_b[j] : (h == 1) ? opk_b[j] : opq_b[j];
        } else v = 0.f;
        bias_cat[idx] = v;
        return;
    }
    idx -= 768;
    if (idx < 512) bias_comb[idx] = out_b[idx] + opout_b[idx];
}

// ---------------------------------------------------------------------------
// Projection GEMM: [gi | vkq](fp16) = x(fp32) @ Wcat^T + bias, sigmoid<sigCols.
// 128x128 tile, BK=32, 512 threads / 8 waves (2x4), wave tile 64x32.
// DEPTH-2 PIPELINE (T3/T4): 3 LDS buffers, raw s_barrier + counted vmcnt(3)
// so the 3 newest loads (step t+2) stay in flight across the barrier.
// A: fp32 reg-staged (issue-early, in-reg bf16 cvt, swizzled ds_write).
// B: global_load_lds(16B), pre-swizzled source, linear LDS dest.
// Grid 768 = 3 blocks/CU (48KB LDS). XCD-chunked block swizzle.
// ---------------------------------------------------------------------------
__global__ __launch_bounds__(512, 6) void gemm_proj(
    const float* __restrict__ A,             // x [M][K] fp32
    const __hip_bfloat16* __restrict__ Bt,   // Wcat [N][K]
    const float* __restrict__ bias,
    __half* __restrict__ out0,
    __half* __restrict__ out1,               // cols >= n0, stride N-n0
    int M, int N, int K, int n0, int sigCols)
{
    constexpr int BM = 128, BK = 32;
    __shared__ alignas(16) __hip_bfloat16 Abuf[3][BM * BK];   // 3x8KB
    __shared__ alignas(16) __hip_bfloat16 Bbuf[3][BM * BK];   // 3x8KB
    const int tid = threadIdx.x;
    const int lane = tid & 63, wid = tid >> 6;
    const int wr = wid >> 2, wc = wid & 3;           // 2x4 wave grid, 64x32 tiles
    const int nbn = N >> 7;
    const int chunk = gridDim.x >> 3;
    const int b = blockIdx.x;
    const int orig = (b & 7) * chunk + (b >> 3);     // XCD-contiguous chunks
    const int bm = (orig / nbn) * BM, bn = (orig % nbn) * BM;
    const int l15 = lane & 15, hgr = lane >> 4;

    // staging: granule g = tid (512 granules = 128 rows x 4 slots)
    const int grow = tid >> 2, gslot = tid & 3;
    const int gsw = gslot ^ ((grow >> 1) & 3);
    const float* srcA = A + (size_t)(bm + grow) * K + gslot * 8;
    const int wOffA = grow * 64 + gsw * 16;                  // swizzled LDS bytes
    const __hip_bfloat16* srcB = Bt + (size_t)(bn + grow) * K + gsw * 8;  // pre-swz src
    const int ldsOffB = (tid & ~63) * 16;                    // linear, wave-uniform

    int offA[4], offB[2];
    #pragma unroll
    for (int mi = 0; mi < 4; ++mi) {
        int r = wr * 64 + mi * 16 + l15;
        offA[mi] = r * 64 + (hgr ^ ((r >> 1) & 3)) * 16;
    }
    #pragma unroll
    for (int nj = 0; nj < 2; ++nj) {
        int r = wc * 32 + nj * 16 + l15;
        offB[nj] = r * 64 + (hgr ^ ((r >> 1) & 3)) * 16;
    }

    f32x4 acc[4][2] = {};
    const int nk = K / BK;    // 16
    float4 pA0, pA1, qA0, qA1;   // two reg sets (even steps / odd steps)

#define WRITE_A(IDX, R0, R1) do { \
        alignas(16) __hip_bfloat16 h_[8] = { \
            __float2bfloat16((R0).x), __float2bfloat16((R0).y), \
            __float2bfloat16((R0).z), __float2bfloat16((R0).w), \
            __float2bfloat16((R1).x), __float2bfloat16((R1).y), \
            __float2bfloat16((R1).z), __float2bfloat16((R1).w)}; \
        *(float4*)((char*)&Abuf[(IDX)][0] + wOffA) = *(float4*)h_; \
    } while (0)

#define FRAG_MFMA(T) do { \
        const char* ab_ = (const char*)&Abuf[(T) % 3][0]; \
        const char* bb_ = (const char*)&Bbuf[(T) % 3][0]; \
        bf16x8_t af_[4], bf_[2]; \
        _Pragma("unroll") \
        for (int mi = 0; mi < 4; ++mi) af_[mi] = *(const bf16x8_t*)(ab_ + offA[mi]); \
        _Pragma("unroll") \
        for (int nj = 0; nj < 2; ++nj) bf_[nj] = *(const bf16x8_t*)(bb_ + offB[nj]); \
        _Pragma("unroll") \
        for (int mi = 0; mi < 4; ++mi) \
            _Pragma("unroll") \
            for (int nj = 0; nj < 2; ++nj) \
                acc[mi][nj] = __builtin_amdgcn_mfma_f32_16x16x32_bf16( \
                    af_[mi], bf_[nj], acc[mi][nj], 0, 0, 0); \
    } while (0)

    // body for step T: issue loads for T+2 into (I0,I1); compute T; write A(T+1) from (W0,W1)
#define GEMM_STEP(T, I0, I1, W0, W1) do { \
        int k2_ = ((T) + 2) * BK; \
        I0 = *(const float4*)(srcA + k2_); \
        I1 = *(const float4*)(srcA + k2_ + 4); \
        gload_lds16(srcB + k2_, (char*)&Bbuf[((T) + 2) % 3][0] + ldsOffB); \
        FRAG_MFMA(T); \
        WRITE_A(((T) + 1) % 3, W0, W1); \
        asm volatile("s_waitcnt vmcnt(3) lgkmcnt(0)" ::: "memory"); \
        __builtin_amdgcn_sched_barrier(0); \
        __builtin_amdgcn_s_barrier(); \
        __builtin_amdgcn_sched_barrier(0); \
    } while (0)

    // prologue: issue steps 0 and 1
    pA0 = *(const float4*)(srcA);
    pA1 = *(const float4*)(srcA + 4);
    gload_lds16(srcB, (char*)&Bbuf[0][0] + ldsOffB);
    qA0 = *(const float4*)(srcA + BK);
    qA1 = *(const float4*)(srcA + BK + 4);
    gload_lds16(srcB + BK, (char*)&Bbuf[1][0] + ldsOffB);
    asm volatile("s_waitcnt vmcnt(3)" ::: "memory");   // step-0 loads done
    WRITE_A(0, pA0, pA1);
    asm volatile("s_waitcnt lgkmcnt(0)" ::: "memory");
    __builtin_amdgcn_sched_barrier(0);
    __builtin_amdgcn_s_barrier();
    __builtin_amdgcn_sched_barrier(0);

    // main pipelined loop: steps 0..nk-3 (nk=16 -> t=0..13, 7 pairs)
    for (int tt = 0; tt + 3 < nk; tt += 2) {
        GEMM_STEP(tt,     pA0, pA1, qA0, qA1);   // even: issue->p, write q=A(t+1)
        GEMM_STEP(tt + 1, qA0, qA1, pA0, pA1);   // odd:  issue->q, write p=A(t+2)
    }
    // peeled step nk-2: no new issues; write A(nk-1) from q-set
    FRAG_MFMA(nk - 2);
    WRITE_A((nk - 1) % 3, qA0, qA1);
    __syncthreads();
    // peeled step nk-1
    FRAG_MFMA(nk - 1);

#undef GEMM_STEP
#undef FRAG_MFMA
#undef WRITE_A

    const int n1 = N - n0;
    #pragma unroll
    for (int mi = 0; mi < 4; ++mi) {
        #pragma unroll
        for (int nj = 0; nj < 2; ++nj) {
            int col = bn + wc * 32 + nj * 16 + l15;
            int r0 = bm + wr * 64 + mi * 16 + hgr * 4;
            float bv = bias[col];
            #pragma unroll
            for (int e = 0; e < 4; ++e) {
                int row = r0 + e;
                float val = acc[mi][nj][e] + bv;
                if (col < n0) {
                    if (col < sigCols) val = 1.f / (1.f + expf(-val));
                    out0[(size_t)row * n0 + col] = __float2half(val);
                } else {
                    out1[(size_t)row * n1 + (col - n0)] = __float2half(val);
                }
            }
        }
    }
}

// ---------------------------------------------------------------------------
// Scan / bind device bodies. gi: [M][512] fp16 (g | in). vkq: [M][256] fp16.
// ---------------------------------------------------------------------------
__device__ void scan_pass1_body(int blk,
    const __half* __restrict__ gi,
    float* __restrict__ ca_last, float* __restrict__ wb_last)
{
    int idx = blk * 256 + threadIdx.x;        // 131072
    int sd = idx & 255;
    int c  = (idx >> 8) & 63;
    int b  = idx >> 14;
    size_t base = ((size_t)(b * TT + c * CHUNK)) * 512;
    float prod = 1.f, wb = 0.f;
    for (int i = 0; i < CHUNK; ++i) {
        size_t off = base + (size_t)i * 512;
        float g  = __half2float(gi[off + sd]);
        float il = __half2float(gi[off + 256 + sd]);
        float a = fmaxf(g, 1e-6f);
        prod *= a;
        wb += (1.f - g) * il / fmaxf(prod, 1e-8f);
    }
    int cidx = (b * NC + c) * SD + sd;
    ca_last[cidx] = prod;
    wb_last[cidx] = wb;
}

// writes states bf16 into cat[row][0..255], stride KCAT
__device__ void scan_pass3_body(int blk,
    const __half* __restrict__ gi, const float* __restrict__ h_prev,
    __hip_bfloat16* __restrict__ cat)
{
    int idx = blk * 256 + threadIdx.x;        // 131072
    int sd = idx & 255;
    int c  = (idx >> 8) & 63;
    int b  = idx >> 14;
    size_t base = ((size_t)(b * TT + c * CHUNK)) * 512;
    size_t obase = ((size_t)(b * TT + c * CHUNK)) * KCAT + sd;
    float h = h_prev[(b * NC + c) * SD + sd];
    float prod = 1.f, wb = 0.f;
    for (int i = 0; i < CHUNK; ++i) {
        size_t off = base + (size_t)i * 512;
        float g  = __half2float(gi[off + sd]);
        float il = __half2float(gi[off + 256 + sd]);
        float a = fmaxf(g, 1e-6f);
        prod *= a;
        wb += (1.f - g) * il / fmaxf(prod, 1e-8f);
        cat[obase + (size_t)i * KCAT] = __float2bfloat16(prod * (h + wb));
    }
}

#define LST 68
__device__ void bind_p1_body(int bc,
    const __half* __restrict__ vkq, const float* __restrict__ op_decay,
    float* __restrict__ o, float* __restrict__ dS,
    float* B1, float* B2, float* B3, float* l2d)
{
    const int b = bc >> 5, c = bc & 31;
    const size_t base = ((size_t)b * TT + (size_t)c * CB) * 256;
    const size_t obase = ((size_t)b * TT + (size_t)c * CB) * OD;
    const int tid = threadIdx.x;
    if (tid < 64) l2d[tid] = log2f(1.f / (1.f + expf(-op_decay[tid])));
    const int lr = tid >> 4, lc = (tid & 15) << 2;
    #pragma unroll
    for (int rr = 0; rr < 4; ++rr) {
        int t = lr + rr * 16;
        float4 qv = ldh4(&vkq[base + t * 256 + 128 + lc]);
        float4 kv = ldh4(&vkq[base + t * 256 + 64 + lc]);
        float q4[4] = {qv.x, qv.y, qv.z, qv.w};
        float k4[4] = {kv.x, kv.y, kv.z, kv.w};
        #pragma unroll
        for (int j = 0; j < 4; ++j) {
            B1[(lc + j) * LST + t] = q4[j];
            B2[(lc + j) * LST + t] = k4[j];
        }
    }
    __syncthreads();
    const int tx = tid & 15, ty = tid >> 4;
    {
        float a_acc[4][4] = {};
        for (int d = 0; d < 64; ++d) {
            float4 q4 = *(const float4*)&B1[d * LST + 4 * ty];
            float4 k4 = *(const float4*)&B2[d * LST + 4 * tx];
            float qr[4] = {q4.x, q4.y, q4.z, q4.w};
            float kr[4] = {k4.x, k4.y, k4.z, k4.w};
            #pragma unroll
            for (int r = 0; r < 4; ++r)
                #pragma unroll
                for (int s = 0; s < 4; ++s)
                    a_acc[r][s] = fmaf(qr[r], kr[s], a_acc[r][s]);
        }
        __syncthreads();
        #pragma unroll
        for (int s = 0; s < 4; ++s) {
            int ss = 4 * tx + s;
            float w[4];
            #pragma unroll
            for (int r = 0; r < 4; ++r)
                w[r] = (ss <= 4 * ty + r) ? a_acc[r][s] : 0.f;
            *(float4*)&B3[ss * LST + 4 * ty] = *(float4*)w;
        }
    }
    #pragma unroll
    for (int rr = 0; rr < 4; ++rr) {
        int m = lr + rr * 16;
        float4 vv = ldh4(&vkq[base + m * 256 + 0 + lc]);
        float4 kv = ldh4(&vkq[base + m * 256 + 64 + lc]);
        float v4[4] = {vv.x, vv.y, vv.z, vv.w};
        #pragma unroll
        for (int j = 0; j < 4; ++j)
            v4[j] *= exp2f(-(float)m * l2d[lc + j]);
        *(float4*)&B1[m * LST + lc] = *(float4*)v4;
        float k4[4] = {kv.x, kv.y, kv.z, kv.w};
        *(float4*)&B2[m * LST + lc] = *(float4*)k4;
    }
    __syncthreads();
    {
        float p[4][4] = {};
        for (int s = 0; s < 64; ++s) {
            float4 a4 = *(const float4*)&B3[s * LST + 4 * ty];
            float4 v4 = *(const float4*)&B1[s * LST + 4 * tx];
            float ar[4] = {a4.x, a4.y, a4.z, a4.w};
            float vr[4] = {v4.x, v4.y, v4.z, v4.w};
            #pragma unroll
            for (int r = 0; r < 4; ++r)
                #pragma unroll
                for (int i2 = 0; i2 < 4; ++i2)
                    p[r][i2] = fmaf(ar[r], vr[i2], p[r][i2]);
        }
        #pragma unroll
        for (int r = 0; r < 4; ++r) {
            int t = 4 * ty + r;
            float w[4];
            #pragma unroll
            for (int i2 = 0; i2 < 4; ++i2)
                w[i2] = exp2f((float)t * l2d[4 * tx + i2]) * p[r][i2];
            *(float4*)&o[obase + t * OD + 4 * tx] = *(float4*)w;
        }
    }
    {
        float sacc[4][4] = {};
        for (int m = 0; m < 64; ++m) {
            float4 v4 = *(const float4*)&B1[m * LST + 4 * ty];
            float4 k4 = *(const float4*)&B2[m * LST + 4 * tx];
            float vr[4] = {v4.x, v4.y, v4.z, v4.w};
            float kr[4] = {k4.x, k4.y, k4.z, k4.w};
            #pragma unroll
            for (int r = 0; r < 4; ++r)
                #pragma unroll
                for (int j = 0; j < 4; ++j)
                    sacc[r][j] = fmaf(vr[r], kr[j], sacc[r][j]);
        }
        float* dSb = dS + (size_t)bc * 4096;
        #pragma unroll
        for (int r = 0; r < 4; ++r) {
            int i = 4 * ty + r;
            float scale = exp2f(63.f * l2d[i]);
            float w[4];
            #pragma unroll
            for (int j2 = 0; j2 < 4; ++j2)
                w[j2] = scale * sacc[r][j2];
            *(float4*)&dSb[i * 64 + 4 * tx] = *(float4*)w;
        }
    }
}

// o_final(bf16 into cat[row][256+i]) = o_intra + dec^(l+1) * (Q @ Sstart^T)
__device__ void bind_p3_body(int bc,
    const __half* __restrict__ vkq, const float* __restrict__ Sstart,
    const float* __restrict__ op_decay, const float* __restrict__ o,
    __hip_bfloat16* __restrict__ cat,
    float* B1, float* B2, float* l2d)
{
    const int b = bc >> 5, c = bc & 31;
    const size_t base = ((size_t)b * TT + (size_t)c * CB) * 256;
    const size_t obase = ((size_t)b * TT + (size_t)c * CB) * OD;
    const size_t cbase = ((size_t)b * TT + (size_t)c * CB) * KCAT + 256;
    const int tid = threadIdx.x;
    if (tid < 64) l2d[tid] = log2f(1.f / (1.f + expf(-op_decay[tid])));
    const int lr = tid >> 4, lc = (tid & 15) << 2;
    const float* Sb = Sstart + (size_t)bc * 4096;
    #pragma unroll
    for (int rr = 0; rr < 4; ++rr) {
        int t = lr + rr * 16;
        float4 qv = ldh4(&vkq[base + t * 256 + 128 + lc]);
        float4 sv = *(const float4*)&Sb[t * 64 + lc];
        float q4[4] = {qv.x, qv.y, qv.z, qv.w};
        float s4[4] = {sv.x, sv.y, sv.z, sv.w};
        #pragma unroll
        for (int j = 0; j < 4; ++j) {
            B1[(lc + j) * LST + t] = q4[j];
            B2[(lc + j) * LST + t] = s4[j];
        }
    }
    __syncthreads();
    const int tx = tid & 15, ty = tid >> 4;
    float acc[4][4] = {};
    for (int j = 0; j < 64; ++j) {
        float4 q4 = *(const float4*)&B1[j * LST + 4 * ty];
        float4 s4 = *(const float4*)&B2[j * LST + 4 * tx];
        float qr[4] = {q4.x, q4.y, q4.z, q4.w};
        float sr[4] = {s4.x, s4.y, s4.z, s4.w};
        #pragma unroll
        for (int r = 0; r < 4; ++r)
            #pragma unroll
            for (int i2 = 0; i2 < 4; ++i2)
                acc[r][i2] = fmaf(qr[r], sr[i2], acc[r][i2]);
    }
    #pragma unroll
    for (int r = 0; r < 4; ++r) {
        int l = 4 * ty + r;
        alignas(8) __hip_bfloat16 w[4];
        #pragma unroll
        for (int i2 = 0; i2 < 4; ++i2) {
            int i = 4 * tx + i2;
            float val = o[obase + l * OD + i] + exp2f((float)(l + 1) * l2d[i]) * acc[r][i2];
            w[i2] = __float2bfloat16(val);
        }
        *(float2*)&cat[cbase + l * KCAT + 4 * tx] = *(float2*)w;
    }
}

// fused1: blocks 0-255 -> bind_p1, blocks 256-767 -> scan_pass1
__global__ __launch_bounds__(256) void fused1(
    const __half* __restrict__ gi, const __half* __restrict__ vkq,
    const float* __restrict__ op_decay,
    float* __restrict__ ca_last, float* __restrict__ wb_last,
    float* __restrict__ o_intra, float* __restrict__ dS)
{
    __shared__ float B1[64 * LST];
    __shared__ float B2[64 * LST];
    __shared__ float B3[64 * LST];
    __shared__ float l2d[64];
    const int bid = blockIdx.x;
    if (bid < 256) bind_p1_body(bid, vkq, op_decay, o_intra, dS, B1, B2, B3, l2d);
    else           scan_pass1_body(bid - 256, gi, ca_last, wb_last);
}

// fused2: blocks 0-127 -> bind_p2 carry scan; blocks 128-135 -> scan_pass2
__global__ __launch_bounds__(256) void fused2(
    const float* __restrict__ dS, const float* __restrict__ op_decay,
    float* __restrict__ Sstart,
    const float* __restrict__ ca_last, const float* __restrict__ wb_last,
    float* __restrict__ h_prev)
{
    const int bid = blockIdx.x;
    if (bid < 128) {
        int idx = bid * 256 + threadIdx.x;   // 32768
        int j = idx & 63, i = (idx >> 6) & 63, b = idx >> 12;
        float dec = 1.f / (1.f + expf(-op_decay[i]));
        float d64 = exp2f(64.f * log2f(dec));
        float S = 0.f;
        for (int c = 0; c < NCB; ++c) {
            size_t o = (((size_t)b * NCB + c) * 4096) + i * 64 + j;
            Sstart[o] = S;
            S = d64 * S + dS[o];
        }
    } else {
        int idx = (bid - 128) * 256 + threadIdx.x;   // 2048
        int sd = idx & 255;
        int b  = idx >> 8;
        float h = 0.f;
        for (int c = 0; c < NC; ++c) {
            int o = (b * NC + c) * SD + sd;
            h_prev[o] = h;
            h = ca_last[o] * (h + wb_last[o]);
        }
    }
}

// fused3: blocks 0-255 -> bind_p3 (cat cols 256-319), 256-767 -> scan_pass3 (cols 0-255)
__global__ __launch_bounds__(256) void fused3(
    const __half* __restrict__ gi, const float* __restrict__ h_prev,
    const __half* __restrict__ vkq, const float* __restrict__ Sstart,
    const float* __restrict__ op_decay, const float* __restrict__ o_intra,
    __hip_bfloat16* __restrict__ cat)
{
    __shared__ float B1[64 * LST];
    __shared__ float B2[64 * LST];
    __shared__ float l2d[64];
    const int bid = blockIdx.x;
    if (bid < 256) bind_p3_body(bid, vkq, Sstart, op_decay, o_intra, cat, B1, B2, l2d);
    else           scan_pass3_body(bid - 256, gi, h_prev, cat);
}

// ---------------------------------------------------------------------------
// Fused output GEMM + residual + LayerNorm.
// y = LN(x + cat @ Wcomb^T + bias_comb) * ln_g + ln_b
// BM=32, BN=512 (full rows per block), BK=32, 512 threads (8 waves, 1x8),
// wave tile 32x64, double-buffered global_load_lds with granule swizzle.
// ---------------------------------------------------------------------------
__global__ __launch_bounds__(512) void outgemm_ln(
    const __hip_bfloat16* __restrict__ cat,    // [M][320]
    const __hip_bfloat16* __restrict__ Wcomb,  // [512][320]
    const float* __restrict__ bias_comb,
    const float* __restrict__ x,               // [M][512]
    const float* __restrict__ lng, const float* __restrict__ lnb,
    float* __restrict__ y)
{
    constexpr int BM = 32, BK = 32, NN = 512;
    __shared__ alignas(16) __hip_bfloat16 As[2][BM * BK];     // 2x2KB
    __shared__ alignas(16) __hip_bfloat16 Bs[2][NN * BK];     // 2x32KB
    __shared__ float psum[8][BM], psum2[8][BM], mvmu[BM], mvrs[BM];
    const int tid = threadIdx.x;
    const int lane = tid & 63, wid = tid >> 6;
    const int l15 = lane & 15, hgr = lane >> 4;
    const int bm = blockIdx.x * BM;

    // A staging (waves 0-1 only)
    const __hip_bfloat16* srcA = cat;
    int ldsOffA = 0;
    {
        int gg = (wid & 1) * 64 + lane;
        int row = gg >> 2, sl = (gg & 3) ^ ((row >> 1) & 3);
        srcA = cat + (size_t)(bm + row) * KCAT + sl * 8;
        ldsOffA = (wid & 1) * 1024;
    }
    // B staging: 4 calls per wave
    const __hip_bfloat16* srcB[4];
    int ldsOffB[4];
    #pragma unroll
    for (int c = 0; c < 4; ++c) {
        int gg = (wid * 4 + c) * 64 + lane;
        int row = gg >> 2, sl = (gg & 3) ^ ((row >> 1) & 3);
        srcB[c] = Wcomb + (size_t)row * KCAT + sl * 8;
        ldsOffB[c] = (wid * 4 + c) * 1024;
    }
    int offA[2], offB[4];
    #pragma unroll
    for (int mi = 0; mi < 2; ++mi) {
        int r = mi * 16 + l15;
        offA[mi] = r * 64 + (hgr ^ ((r >> 1) & 3)) * 16;
    }
    #pragma unroll
    for (int nj = 0; nj < 4; ++nj) {
        int n = wid * 64 + nj * 16 + l15;
        offB[nj] = n * 64 + (hgr ^ ((n >> 1) & 3)) * 16;
    }

    f32x4 acc[2][4] = {};
    constexpr int nk = KCAT / BK;   // 10

    if (wid < 2) gload_lds16(srcA, (char*)&As[0][0] + ldsOffA);
    #pragma unroll
    for (int c = 0; c < 4; ++c) gload_lds16(srcB[c], (char*)&Bs[0][0] + ldsOffB[c]);
    __syncthreads();

    int cur = 0;
    for (int t = 0; t < nk; ++t) {
        if (t + 1 < nk) {
            int k0 = (t + 1) * BK;
            if (wid < 2) gload_lds16(srcA + k0, (char*)&As[cur ^ 1][0] + ldsOffA);
            #pragma unroll
            for (int c = 0; c < 4; ++c)
                gload_lds16(srcB[c] + k0, (char*)&Bs[cur ^ 1][0] + ldsOffB[c]);
        }
        bf16x8_t af[2], bfr[4];
        #pragma unroll
        for (int mi = 0; mi < 2; ++mi)
            af[mi] = *(const bf16x8_t*)((const char*)&As[cur][0] + offA[mi]);
        #pragma unroll
        for (int nj = 0; nj < 4; ++nj)
            bfr[nj] = *(const bf16x8_t*)((const char*)&Bs[cur][0] + offB[nj]);
        #pragma unroll
        for (int mi = 0; mi < 2; ++mi)
            #pragma unroll
            for (int nj = 0; nj < 4; ++nj)
                acc[mi][nj] = __builtin_amdgcn_mfma_f32_16x16x32_bf16(
                    af[mi], bfr[nj], acc[mi][nj], 0, 0, 0);
        __syncthreads();
        cur ^= 1;
    }

    // epilogue: + bias + x residual
    #pragma unroll
    for (int nj = 0; nj < 4; ++nj) {
        int col = wid * 64 + nj * 16 + l15;
        float bc_ = bias_comb[col];
        #pragma unroll
        for (int mi = 0; mi < 2; ++mi) {
            int r0 = bm + mi * 16 + hgr * 4;
            #pragma unroll
            for (int e = 0; e < 4; ++e)
                acc[mi][nj][e] += bc_ + x[(size_t)(r0 + e) * DD + col];
        }
    }
    // per-row sums over this wave's 64 cols
    float s[8], s2[8];
    #pragma unroll
    for (int mi = 0; mi < 2; ++mi)
        #pragma unroll
        for (int e = 0; e < 4; ++e) {
            float a = 0.f, b2 = 0.f;
            #pragma unroll
            for (int nj = 0; nj < 4; ++nj) {
                float v = acc[mi][nj][e];
                a += v; b2 += v * v;
            }
            s[mi * 4 + e] = a; s2[mi * 4 + e] = b2;
        }
    #pragma unroll
    for (int off = 1; off <= 8; off <<= 1)
        #pragma unroll
        for (int i = 0; i < 8; ++i) {
            s[i]  += __shfl_xor(s[i], off);
            s2[i] += __shfl_xor(s2[i], off);
        }
    if (l15 == 0) {
        #pragma unroll
        for (int mi = 0; mi < 2; ++mi)
            #pragma unroll
            for (int e = 0; e < 4; ++e) {
                int lr = mi * 16 + hgr * 4 + e;
                psum[wid][lr]  = s[mi * 4 + e];
                psum2[wid][lr] = s2[mi * 4 + e];
            }
    }
    __syncthreads();
    if (tid < BM) {
        float tot = 0.f, tot2 = 0.f;
        #pragma unroll
        for (int w2 = 0; w2 < 8; ++w2) { tot += psum[w2][tid]; tot2 += psum2[w2][tid]; }
        float mu = tot * (1.f / 512.f);
        float var = tot2 * (1.f / 512.f) - mu * mu;
        mvmu[tid] = mu;
        mvrs[tid] = rsqrtf(var + 1e-5f);
    }
    __syncthreads();
    #pragma unroll
    for (int nj = 0; nj < 4; ++nj) {
        int col = wid * 64 + nj * 16 + l15;
        float g = lng[col], bb = lnb[col];
        #pragma unroll
        for (int mi = 0; mi < 2; ++mi) {
            #pragma unroll
            for (int e = 0; e < 4; ++e) {
                int lr = mi * 16 + hgr * 4 + e;
                y[(size_t)(bm + lr) * DD + col] =
                    (acc[mi][nj][e] - mvmu[lr]) * mvrs[lr] * g + bb;
            }
        }
    }
}

// ---------------------------------------------------------------------------
extern "C" void kernel_launch(void* const* d_in, const int* in_sizes, int n_in,
                              void* d_out, int out_size, void* d_ws, size_t ws_size,
                              hipStream_t stream)
{
    const float* x       = (const float*)d_in[0];
    const float* gate_W  = (const float*)d_in[1];
    const float* gate_b  = (const float*)d_in[2];
    const float* in_W    = (const float*)d_in[3];
    const float* in_b    = (const float*)d_in[4];
    const float* out_W   = (const float*)d_in[5];
    const float* out_b   = (const float*)d_in[6];
    const float* opv_W   = (const float*)d_in[7];
    const float* opv_b   = (const float*)d_in[8];
    const float* opk_W   = (const float*)d_in[9];
    const float* opk_b   = (const float*)d_in[10];
    const float* opq_W   = (const float*)d_in[11];
    const float* opq_b   = (const float*)d_in[12];
    const float* op_dec  = (const float*)d_in[13];
    const float* opout_W = (const float*)d_in[14];
    const float* opout_b = (const float*)d_in[15];
    const float* ln_g    = (const float*)d_in[16];
    const float* ln_b    = (const float*)d_in[17];
    float* y = (float*)d_out;

    char* w = (char*)d_ws;
    auto alloc = [&](size_t bytes) { char* p = w; w += (bytes + 255) & ~(size_t)255; return p; };
    __half* gi       = (__half*)alloc((size_t)MM * 512 * 2);
    __half* vkq      = (__half*)alloc((size_t)MM * 256 * 2);
    float* o_intra   = (float*)alloc((size_t)MM * 64 * 4);
    float* ca_last   = (float*)alloc((size_t)BB * NC * SD * 4);
    float* wb_last   = (float*)alloc((size_t)BB * NC * SD * 4);
    float* h_prev    = (float*)alloc((size_t)BB * NC * SD * 4);
    float* dS        = (float*)alloc((size_t)BB * NCB * 4096 * 4);
    float* Sstart    = (float*)alloc((size_t)BB * NCB * 4096 * 4);
    float* bias_cat  = (float*)alloc(768 * 4);
    float* bias_comb = (float*)alloc(512 * 4);
    __hip_bfloat16* cat   = (__hip_bfloat16*)alloc((size_t)MM * KCAT * 2);
    __hip_bfloat16* Wcat  = (__hip_bfloat16*)alloc((size_t)768 * 512 * 2);
    __hip_bfloat16* Wcomb = (__hip_bfloat16*)alloc((size_t)512 * KCAT * 2);

    // 1: weight prep (tiny)
    hipLaunchKernelGGL(conv_w, dim3((393216 + 163840 + 768 + 512 + 255) / 256), dim3(256), 0, stream,
                       gate_W, gate_b, in_W, in_b, opv_W, opk_W, opq_W,
                       opv_b, opk_b, opq_b, out_W, out_b, opout_W, opout_b,
                       Wcat, Wcomb, bias_cat, bias_comb);
    // 2: fused projection from fp32 x (fp16 outputs, XCD-swizzled grid 768 = 8*96)
    hipLaunchKernelGGL(gemm_proj, dim3(6 * (MM / 128)), dim3(512), 0, stream,
                       x, Wcat, bias_cat, gi, vkq,
                       MM, 768, 512, 512, 256);
    // 3: bind_p1 || scan_pass1
    hipLaunchKernelGGL(fused1, dim3(768), dim3(256), 0, stream,
                       gi, vkq, op_dec, ca_last, wb_last, o_intra, dS);
    // 4: carry scans
    hipLaunchKernelGGL(fused2, dim3(136), dim3(256), 0, stream,
                       dS, op_dec, Sstart, ca_last, wb_last, h_prev);
    // 5: bind_p3 || scan_pass3 -> cat[M][320] bf16
    hipLaunchKernelGGL(fused3, dim3(768), dim3(256), 0, stream,
                       gi, h_prev, vkq, Sstart, op_dec, o_intra, cat);
    // 6: y = LN(x + cat @ Wcomb^T + bias_comb)
    hipLaunchKernelGGL(outgemm_ln, dim3(MM / 32), dim3(512), 0, stream,
                       cat, Wcomb, bias_comb, x, ln_g, ln_b, y);
}